// Round 10
// baseline (1945.422 us; speedup 1.0000x reference)
//
#include <hip/hip_runtime.h>
#include <hip/hip_bf16.h>
#include <math.h>

#define B_    32
#define SEQ_  672
#define CVAR_ 21
#define PRED_ 336
#define D_    512
#define H_    8
#define DFF_  2048
#define NL_   2
#define R_    14
#define T_    6
#define N_    84
#define BC_   672           // B_*CVAR_
#define M_    (BC_*N_)      // 56448 tokens
#define KHEAD_ (D_*N_)      // 43008
#define SK_   16            // head split-K
#define PM_   768           // head M padded to 6*128
#define PN_   384           // head N padded to 3*128
#define QKVN_ 1536          // fused qkv width

typedef __attribute__((ext_vector_type(8))) short bh8;
typedef __attribute__((ext_vector_type(4))) float f32x4;

__device__ __forceinline__ unsigned short f2b(float x){
  union { float f; unsigned int u; } v; v.f = x;
  unsigned int r = v.u + 0x7FFFu + ((v.u >> 16) & 1u);   // RNE
  return (unsigned short)(r >> 16);
}
__device__ __forceinline__ float b2f(unsigned short h){
  union { unsigned int u; float f; } v; v.u = ((unsigned int)h) << 16;
  return v.f;
}
__device__ __forceinline__ float wred_add(float v){
  #pragma unroll
  for (int o = 32; o; o >>= 1) v += __shfl_xor(v, o, 64);
  return v;
}
// async global->LDS, 16B per lane; lds base must be wave-uniform
__device__ __forceinline__ void stage16(const unsigned short* g, unsigned short* l){
  __builtin_amdgcn_global_load_lds(
      (const __attribute__((address_space(1))) unsigned int*)(const void*)g,
      (__attribute__((address_space(3))) unsigned int*)(void*)l, 16, 0, 0);
}

// ---------------- instance norm over time ----------------
__global__ void k_instnorm(const float* __restrict__ x, float* __restrict__ xc,
                           float* __restrict__ stats){
  int bc = blockIdx.x; int b = bc / CVAR_, c = bc % CVAR_;
  const float* xp = x + (size_t)b*SEQ_*CVAR_ + c;
  int tid = threadIdx.x;
  float s = 0.f, sq = 0.f;
  for (int l = tid; l < SEQ_; l += 256){ float v = xp[(size_t)l*CVAR_]; s += v; sq += v*v; }
  __shared__ float rs[4], rq[4];
  s = wred_add(s); sq = wred_add(sq);
  int w = tid >> 6, lane = tid & 63;
  if (lane == 0){ rs[w] = s; rq[w] = sq; }
  __syncthreads();
  if (tid == 0){
    float S = rs[0]+rs[1]+rs[2]+rs[3], Q = rq[0]+rq[1]+rq[2]+rq[3];
    float mean = S * (1.f/SEQ_);
    float var  = Q * (1.f/SEQ_) - mean*mean;
    float stdev = sqrtf(var + 1e-5f);
    stats[bc] = mean; stats[BC_ + bc] = stdev;
    rs[0] = mean; rq[0] = stdev;
  }
  __syncthreads();
  float mean = rs[0], inv = 1.f / rq[0];
  for (int l = tid; l < SEQ_; l += 256)
    xc[(size_t)bc*SEQ_ + l] = (xp[(size_t)l*CVAR_] - mean) * inv;
}

// ---------------- region router ----------------
__global__ void k_router(const float* __restrict__ xc,
                         const float* __restrict__ w1, const float* __restrict__ b1,
                         const float* __restrict__ w2, const float* __restrict__ b2,
                         int* __restrict__ pred){
  int t = blockIdx.x*256 + threadIdx.x;
  if (t >= BC_*R_) return;
  int bc = t / R_, r = t % R_;
  const float* xr = xc + (size_t)bc*SEQ_ + r*48;
  float xs[48];
  #pragma unroll
  for (int i = 0; i < 48; i++) xs[i] = xr[i];
  float hdn[64];
  #pragma unroll 4
  for (int h = 0; h < 64; h++){
    float a = b1[h];
    const float* wr = w1 + h*48;
    #pragma unroll
    for (int i = 0; i < 48; i++) a = fmaf(xs[i], wr[i], a);
    hdn[h] = fmaxf(a, 0.f);
  }
  float best = -1e30f; int be = 0;
  for (int e = 0; e < 4; e++){
    float lg = b2[e];
    const float* wr = w2 + e*64;
    #pragma unroll 8
    for (int h = 0; h < 64; h++) lg = fmaf(hdn[h], wr[h], lg);
    if (lg > best){ best = lg; be = e; }   // first max wins (strict >)
  }
  pred[t] = be;
}

// ---------------- positional encoding ----------------
__global__ void k_pe(float* __restrict__ pe){
  int i = blockIdx.x*256 + threadIdx.x;
  if (i >= N_*D_) return;
  int n = i / D_, d = i % D_;
  int ii = d >> 1;
  float freq = expf((float)(2*ii) * (-9.210340371976184f / (float)D_)); // -ln(10000)/D
  float a = (float)n * freq;
  pe[i] = (d & 1) ? cosf(a) : sinf(a);
}

// ---------------- fp32 -> bf16 convert (n4 = elems/4) ----------------
__global__ void k_cvt(const float* __restrict__ in, unsigned short* __restrict__ out, int n4){
  int i = blockIdx.x*256 + threadIdx.x;
  if (i >= n4) return;
  float4 v = ((const float4*)in)[i];
  ((ushort4*)out)[i] = make_ushort4(f2b(v.x), f2b(v.y), f2b(v.z), f2b(v.w));
}

// ---------------- fused qkv weight convert (concat rows) ----------------
__global__ void k_cvtqkv(const float* __restrict__ wq, const float* __restrict__ wk,
                         const float* __restrict__ wv, unsigned short* __restrict__ o){
  int i = blockIdx.x*256 + threadIdx.x;          // one per 4 elems
  const int per_l = QKVN_*D_/4;                  // 196608
  const int per_s = D_*D_/4;                     // 65536
  if (i >= NL_*per_l) return;
  int l = i / per_l;
  int rem = i - l*per_l;
  int sec = rem / per_s;
  int off = rem - sec*per_s;
  const float* src = (sec==0 ? wq : sec==1 ? wk : wv) + (size_t)l*D_*D_ + (size_t)off*4;
  float4 v = *(const float4*)src;
  ((ushort4*)o)[i] = make_ushort4(f2b(v.x), f2b(v.y), f2b(v.z), f2b(v.w));
}

// ---------------- qkv bias concat ----------------
__global__ void k_catbias(const float* __restrict__ bq, const float* __restrict__ bk,
                          const float* __restrict__ bv, float* __restrict__ bqkv){
  int i = blockIdx.x*256 + threadIdx.x;
  if (i >= NL_*QKVN_) return;
  int l = i / QKVN_, r = i % QKVN_;
  float v = (r < 512) ? bq[l*512 + r] : (r < 1024) ? bk[l*512 + r - 512] : bv[l*512 + r - 1024];
  bqkv[i] = v;
}

// ------ expert weight transpose: W_e[d][q] -> wt[base_e + q*512 + d] ----------
// bases (floats): e0:0 (p=8), e1:4096 (16), e2:12288 (24), e3:24576 (48); total 49152
__global__ void k_transe(const float* __restrict__ w0, const float* __restrict__ w1,
                         const float* __restrict__ w2, const float* __restrict__ w3,
                         float* __restrict__ wt){
  int i = blockIdx.x*256 + threadIdx.x;
  if (i >= 49152) return;
  int e, base, p;
  if (i < 4096){ e = 0; base = 0; p = 8; }
  else if (i < 12288){ e = 1; base = 4096; p = 16; }
  else if (i < 24576){ e = 2; base = 12288; p = 24; }
  else { e = 3; base = 24576; p = 48; }
  int local = i - base;
  int q = local >> 9, d = local & 511;
  const float* W = (e==0) ? w0 : (e==1) ? w1 : (e==2) ? w2 : w3;
  wt[base + q*512 + d] = W[(size_t)d*p + q];
}

// ---------------- patch embedding + PE (coalesced transposed weights) ---------
__global__ void k_embed(const float* __restrict__ xc, const int* __restrict__ pred,
                        const float* __restrict__ wt, const float* __restrict__ pe,
                        float* __restrict__ z, unsigned short* __restrict__ zb, int bc0){
  int blk = blockIdx.x; int bcl = blk / R_, r = blk % R_;
  int bc = bc0 + bcl;
  __shared__ float xr[48];
  int tid = threadIdx.x;
  if (tid < 48) xr[tid] = xc[(size_t)bc*SEQ_ + r*48 + tid];
  __syncthreads();
  int e = pred[bc*R_ + r];
  int p    = (e==0) ? 8 : (e==1) ? 16 : (e==2) ? 24 : 48;
  int base = (e==0) ? 0 : (e==1) ? 4096 : (e==2) ? 12288 : 24576;
  int num = 48 / p, rep = 7 - num;
  const float* Wt = wt + base;
  int d0 = tid, d1 = tid + 256;
  float acc0[6], acc1[6];
  #pragma unroll
  for (int u = 0; u < 6; u++){ acc0[u] = 0.f; acc1[u] = 0.f; }
  #pragma unroll
  for (int u = 0; u < 6; u++){
    if (u < num){
      float s0 = 0.f, s1 = 0.f;
      const float* xu = xr + u*p;
      for (int q = 0; q < p; q++){
        float xv = xu[q];
        const float* wrow = Wt + q*512;
        s0 = fmaf(xv, wrow[d0], s0);
        s1 = fmaf(xv, wrow[d1], s1);
      }
      acc0[u] = s0; acc1[u] = s1;
    }
  }
  #pragma unroll
  for (int u = 0; u < 6; u++){
    if (u < num){
      #pragma unroll
      for (int t = 0; t < 6; t++){
        int ut = t / rep; if (ut > num-1) ut = num-1;
        if (ut == u){
          int n = r*T_ + t;
          size_t off = ((size_t)bcl*N_ + n)*D_;
          float v0 = acc0[u] + pe[n*D_ + d0];
          float v1 = acc1[u] + pe[n*D_ + d1];
          z[off + d0] = v0;  z[off + d1] = v1;
          zb[off + d0] = f2b(v0);  zb[off + d1] = f2b(v1);
        }
      }
    }
  }
}

// ---------------- bf16 MFMA GEMM: C[M,N] = act(A[M,K] * B[N,K]^T + bias) ------
// 128x128 tile, BK=32, 256 thr (4 waves, 2x2), 4x4 16x16x32 frags per wave.
// 3-deep LDS pipeline (2 tiles prefetched ahead): issue tile k+2, then
// s_waitcnt vmcnt(8) => tile k landed while k+1/k+2 stay in flight.
// M % 128 == 0, N % 128 == 0, K % 32 == 0, K >= 96.
template<bool GELU, bool OBF16>
__global__ __launch_bounds__(256) void k_mm(const unsigned short* __restrict__ A,
      const unsigned short* __restrict__ Bw, const float* __restrict__ bias,
      void* __restrict__ Cp, int M, int N, int K){
  __shared__ unsigned short As[3][128*32];
  __shared__ unsigned short Bs[3][128*32];
  int tid = threadIdx.x;
  int lane = tid & 63;
  int wave = tid >> 6;
  int wr = wave >> 1, wc = wave & 1;
  // bijective XCD swizzle (m204): contiguous wgid chunk per XCD
  int nx = N >> 7;
  int nwg = gridDim.x;
  int orig = blockIdx.x;
  int q = nwg >> 3, r8 = nwg & 7;
  int xcd = orig & 7, idx = orig >> 3;
  int wgid = (xcd < r8 ? xcd*(q+1) : r8*(q+1) + (xcd - r8)*q) + idx;
  int m0 = (wgid / nx) << 7;
  int n0 = (wgid % nx) << 7;
  // staging geometry (precomputed, reused each step)
  int eb0 = (tid & 192);                   // wave-uniform chunk base, group 0
  int e0 = eb0 + lane, e1 = eb0 + 256 + lane;
  int row0 = e0 >> 2, kc0 = (e0 & 3) << 3;
  int row1 = e1 >> 2, kc1 = (e1 & 3) << 3;
  const unsigned short* a0 = A  + (size_t)(m0+row0)*K + kc0;
  const unsigned short* a1 = A  + (size_t)(m0+row1)*K + kc1;
  const unsigned short* b0 = Bw + (size_t)(n0+row0)*K + kc0;
  const unsigned short* b1 = Bw + (size_t)(n0+row1)*K + kc1;
  f32x4 acc[4][4];
  #pragma unroll
  for (int m = 0; m < 4; m++)
    #pragma unroll
    for (int n = 0; n < 4; n++) acc[m][n] = (f32x4){0.f,0.f,0.f,0.f};

  const int nst = K >> 5;
  // prologue: stage tiles 0 and 1 (8 loads/wave in flight)
  stage16(a0, &As[0][eb0*8]);
  stage16(a1, &As[0][(eb0+256)*8]);
  stage16(b0, &Bs[0][eb0*8]);
  stage16(b1, &Bs[0][(eb0+256)*8]);
  stage16(a0 + 32, &As[1][eb0*8]);
  stage16(a1 + 32, &As[1][(eb0+256)*8]);
  stage16(b0 + 32, &Bs[1][eb0*8]);
  stage16(b1 + 32, &Bs[1][(eb0+256)*8]);
  int cur = 0;
  for (int s = 0; s < nst; s++){
    int pf = s + 2;
    if (pf < nst){
      int pb = cur >= 1 ? cur - 1 : 2;     // (cur+2)%3
      int ko = pf << 5;
      stage16(a0 + ko, &As[pb][eb0*8]);
      stage16(a1 + ko, &As[pb][(eb0+256)*8]);
      stage16(b0 + ko, &Bs[pb][eb0*8]);
      stage16(b1 + ko, &Bs[pb][(eb0+256)*8]);
      asm volatile("s_waitcnt vmcnt(8)" ::: "memory");
    } else if (s + 1 < nst){
      asm volatile("s_waitcnt vmcnt(4)" ::: "memory");
    } else {
      asm volatile("s_waitcnt vmcnt(0)" ::: "memory");
    }
    __builtin_amdgcn_s_barrier();
    __builtin_amdgcn_sched_barrier(0);
    bh8 fa[4], fb[4];
    #pragma unroll
    for (int m = 0; m < 4; m++)
      fa[m] = *(const bh8*)&As[cur][(wr*64 + m*16 + (lane & 15))*32 + (lane >> 4)*8];
    #pragma unroll
    for (int n = 0; n < 4; n++)
      fb[n] = *(const bh8*)&Bs[cur][(wc*64 + n*16 + (lane & 15))*32 + (lane >> 4)*8];
    #pragma unroll
    for (int m = 0; m < 4; m++)
      #pragma unroll
      for (int n = 0; n < 4; n++)
        acc[m][n] = __builtin_amdgcn_mfma_f32_16x16x32_bf16(fa[m], fb[n], acc[m][n], 0, 0, 0);
    __builtin_amdgcn_sched_barrier(0);
    __builtin_amdgcn_s_barrier();          // WAR: all reads of buf[cur] done
    cur = cur < 2 ? cur + 1 : 0;
  }
  int rbase = m0 + wr*64 + (lane >> 4)*4;
  int cbase = n0 + wc*64 + (lane & 15);
  #pragma unroll
  for (int n = 0; n < 4; n++){
    int col = cbase + n*16;
    float bs = bias[col];
    #pragma unroll
    for (int m = 0; m < 4; m++){
      int row = rbase + m*16;
      #pragma unroll
      for (int j = 0; j < 4; j++){
        float cv = acc[m][n][j] + bs;
        if (GELU) cv = 0.5f*cv*(1.f + erff(cv*0.70710678118654752f));
        if (OBF16) ((unsigned short*)Cp)[(size_t)(row+j)*N + col] = f2b(cv);
        else       ((float*)Cp)[(size_t)(row+j)*N + col] = cv;
      }
    }
  }
}

// ---------------- head GEMM, split-K partials (rows/cols clamped) -------------
__global__ __launch_bounds__(256) void k_mm_part(const unsigned short* __restrict__ A,
      const unsigned short* __restrict__ Bw, float* __restrict__ part, int kchunk){
  __shared__ unsigned short As[3][128*32];
  __shared__ unsigned short Bs[3][128*32];
  int tid = threadIdx.x;
  int lane = tid & 63, wave = tid >> 6;
  int wr = wave >> 1, wc = wave & 1;
  int m0 = blockIdx.y*128, n0 = blockIdx.x*128;
  int kb0 = blockIdx.z*kchunk;
  int eb0 = (tid & 192);
  int e0 = eb0 + lane, e1 = eb0 + 256 + lane;
  int row0 = e0 >> 2, kc0 = (e0 & 3) << 3;
  int row1 = e1 >> 2, kc1 = (e1 & 3) << 3;
  int ar0 = m0 + row0; if (ar0 >= BC_)  ar0 = BC_ - 1;
  int ar1 = m0 + row1; if (ar1 >= BC_)  ar1 = BC_ - 1;
  int br0 = n0 + row0; if (br0 >= PRED_) br0 = PRED_ - 1;
  int br1 = n0 + row1; if (br1 >= PRED_) br1 = PRED_ - 1;
  const unsigned short* a0 = A  + (size_t)ar0*KHEAD_ + kb0 + kc0;
  const unsigned short* a1 = A  + (size_t)ar1*KHEAD_ + kb0 + kc1;
  const unsigned short* b0 = Bw + (size_t)br0*KHEAD_ + kb0 + kc0;
  const unsigned short* b1 = Bw + (size_t)br1*KHEAD_ + kb0 + kc1;
  f32x4 acc[4][4];
  #pragma unroll
  for (int m = 0; m < 4; m++)
    #pragma unroll
    for (int n = 0; n < 4; n++) acc[m][n] = (f32x4){0.f,0.f,0.f,0.f};

  const int nst = kchunk >> 5;
  stage16(a0, &As[0][eb0*8]);
  stage16(a1, &As[0][(eb0+256)*8]);
  stage16(b0, &Bs[0][eb0*8]);
  stage16(b1, &Bs[0][(eb0+256)*8]);
  stage16(a0 + 32, &As[1][eb0*8]);
  stage16(a1 + 32, &As[1][(eb0+256)*8]);
  stage16(b0 + 32, &Bs[1][eb0*8]);
  stage16(b1 + 32, &Bs[1][(eb0+256)*8]);
  int cur = 0;
  for (int s = 0; s < nst; s++){
    int pf = s + 2;
    if (pf < nst){
      int pb = cur >= 1 ? cur - 1 : 2;
      int kk = pf << 5;
      stage16(a0 + kk, &As[pb][eb0*8]);
      stage16(a1 + kk, &As[pb][(eb0+256)*8]);
      stage16(b0 + kk, &Bs[pb][eb0*8]);
      stage16(b1 + kk, &Bs[pb][(eb0+256)*8]);
      asm volatile("s_waitcnt vmcnt(8)" ::: "memory");
    } else if (s + 1 < nst){
      asm volatile("s_waitcnt vmcnt(4)" ::: "memory");
    } else {
      asm volatile("s_waitcnt vmcnt(0)" ::: "memory");
    }
    __builtin_amdgcn_s_barrier();
    __builtin_amdgcn_sched_barrier(0);
    bh8 fa[4], fb[4];
    #pragma unroll
    for (int m = 0; m < 4; m++)
      fa[m] = *(const bh8*)&As[cur][(wr*64 + m*16 + (lane & 15))*32 + (lane >> 4)*8];
    #pragma unroll
    for (int n = 0; n < 4; n++)
      fb[n] = *(const bh8*)&Bs[cur][(wc*64 + n*16 + (lane & 15))*32 + (lane >> 4)*8];
    #pragma unroll
    for (int m = 0; m < 4; m++)
      #pragma unroll
      for (int n = 0; n < 4; n++)
        acc[m][n] = __builtin_amdgcn_mfma_f32_16x16x32_bf16(fa[m], fb[n], acc[m][n], 0, 0, 0);
    __builtin_amdgcn_sched_barrier(0);
    __builtin_amdgcn_s_barrier();
    cur = cur < 2 ? cur + 1 : 0;
  }
  float* po = part + (size_t)blockIdx.z*PM_*PN_;
  int rbase = m0 + wr*64 + (lane >> 4)*4;
  int cbase = n0 + wc*64 + (lane & 15);
  #pragma unroll
  for (int n = 0; n < 4; n++){
    int col = cbase + n*16;
    #pragma unroll
    for (int m = 0; m < 4; m++){
      int row = rbase + m*16;
      #pragma unroll
      for (int j = 0; j < 4; j++)
        po[(size_t)(row+j)*PN_ + col] = acc[m][n][j];
    }
  }
}

// ---------------- head reduce + bias ----------------
__global__ void k_headred(const float* __restrict__ part, const float* __restrict__ bias2,
                          float* __restrict__ dec){
  int i = blockIdx.x*256 + threadIdx.x;
  if (i >= BC_*PRED_) return;
  int bc = i / PRED_, pr = i % PRED_;
  float s = bias2[pr];
  #pragma unroll
  for (int sk = 0; sk < SK_; sk++)
    s += part[(size_t)sk*PM_*PN_ + (size_t)bc*PN_ + pr];
  dec[i] = s;
}

// -------- MFMA fused attention: block = (bc-local, head), 6 waves -------------
// Per wave: one 16-row tile of S (96x96 padded), in-register softmax, PV.
__global__ __launch_bounds__(384) void k_attn(const unsigned short* __restrict__ qkv,
                                              unsigned short* __restrict__ o){
  __shared__ unsigned short Qb[96][72];       // stride 144B: 2-way alias (free)
  __shared__ unsigned short Kb[96][72];
  __shared__ unsigned short Vt[64][104];      // V transposed; stride 208B
  __shared__ unsigned short Pb[6][16][104];
  int bh = blockIdx.x; int bcl = bh >> 3, h = bh & 7;
  int tid = threadIdx.x, lane = tid & 63, wv = tid >> 6;   // wv = row-tile 0..5
  size_t qb = (size_t)bcl*N_*QKVN_ + h*64;
  // stage Q,K ([96][64], pad rows zeroed)
  for (int g = tid; g < 1536; g += 384){
    int n = g >> 4, d4 = (g & 15) << 2;
    ushort4 qv = make_ushort4(0,0,0,0), kv = make_ushort4(0,0,0,0);
    if (n < N_){
      qv = *(const ushort4*)(qkv + qb + (size_t)n*QKVN_ + d4);
      kv = *(const ushort4*)(qkv + qb + 512 + (size_t)n*QKVN_ + d4);
    }
    *(ushort4*)&Qb[n][d4] = qv;
    *(ushort4*)&Kb[n][d4] = kv;
  }
  // stage V transposed: Vt[d][n]
  for (int g = tid; g < N_*16; g += 384){
    int n = g >> 4, d4 = (g & 15) << 2;
    ushort4 vv = *(const ushort4*)(qkv + qb + 1024 + (size_t)n*QKVN_ + d4);
    Vt[d4+0][n] = vv.x; Vt[d4+1][n] = vv.y; Vt[d4+2][n] = vv.z; Vt[d4+3][n] = vv.w;
  }
  for (int g = tid; g < 64*12; g += 384) Vt[g/12][N_ + g%12] = 0;
  __syncthreads();
  // S tile: rows [wv*16, wv*16+16), all 96 cols
  f32x4 acc[6];
  #pragma unroll
  for (int t = 0; t < 6; t++) acc[t] = (f32x4){0.f,0.f,0.f,0.f};
  #pragma unroll
  for (int ks = 0; ks < 2; ks++){
    bh8 qa = *(const bh8*)&Qb[wv*16 + (lane & 15)][ks*32 + (lane >> 4)*8];
    #pragma unroll
    for (int t = 0; t < 6; t++){
      bh8 kf = *(const bh8*)&Kb[t*16 + (lane & 15)][ks*32 + (lane >> 4)*8];
      acc[t] = __builtin_amdgcn_mfma_f32_16x16x32_bf16(qa, kf, acc[t], 0, 0, 0);
    }
  }
  // softmax over cols (mask cols >= 84); lane holds col t*16+(lane&15), rows (lane>>4)*4+j
  bool v5 = (lane & 15) < 4;
  #pragma unroll
  for (int j = 0; j < 4; j++){
    float m = -1e30f;
    #pragma unroll
    for (int t = 0; t < 6; t++){
      float s = acc[t][j] * 0.125f;
      if (t == 5 && !v5) s = -1e30f;
      acc[t][j] = s;
      m = fmaxf(m, s);
    }
    #pragma unroll
    for (int off = 1; off < 16; off <<= 1) m = fmaxf(m, __shfl_xor(m, off, 64));
    float sum = 0.f;
    #pragma unroll
    for (int t = 0; t < 6; t++){
      float p = __expf(acc[t][j] - m);
      acc[t][j] = p;
      sum += p;
    }
    #pragma unroll
    for (int off = 1; off < 16; off <<= 1) sum += __shfl_xor(sum, off, 64);
    float inv = 1.f / sum;
    int lr = (lane >> 4)*4 + j;
    #pragma unroll
    for (int t = 0; t < 6; t++)
      Pb[wv][lr][t*16 + (lane & 15)] = f2b(acc[t][j] * inv);
  }
  // PV: O[16][64] = P[16][96] * V[96][64]; each wave reads only its own Pb slice
  f32x4 accO[4];
  #pragma unroll
  for (int dt = 0; dt < 4; dt++) accO[dt] = (f32x4){0.f,0.f,0.f,0.f};
  #pragma unroll
  for (int ks = 0; ks < 3; ks++){
    bh8 pa = *(const bh8*)&Pb[wv][lane & 15][ks*32 + (lane >> 4)*8];
    #pragma unroll
    for (int dt = 0; dt < 4; dt++){
      bh8 vf = *(const bh8*)&Vt[dt*16 + (lane & 15)][ks*32 + (lane >> 4)*8];
      accO[dt] = __builtin_amdgcn_mfma_f32_16x16x32_bf16(pa, vf, accO[dt], 0, 0, 0);
    }
  }
  size_t ob = (size_t)bcl*N_*D_ + h*64;
  #pragma unroll
  for (int dt = 0; dt < 4; dt++)
    #pragma unroll
    for (int j = 0; j < 4; j++){
      int r = wv*16 + (lane >> 4)*4 + j;
      if (r < N_) o[ob + (size_t)r*D_ + dt*16 + (lane & 15)] = f2b(accO[dt][j]);
    }
}

// ---------- fused residual-add + LayerNorm (bf16 delta) + bf16 shadow ---------
__global__ __launch_bounds__(256) void k_addln(float* __restrict__ z,
                        const unsigned short* __restrict__ delta,
                        const float* __restrict__ g, const float* __restrict__ b,
                        unsigned short* __restrict__ zb, int ntok){
  int w = threadIdx.x >> 6, lane = threadIdx.x & 63;
  int tok = blockIdx.x*4 + w;
  if (tok >= ntok) return;
  float4* zp = (float4*)(z + (size_t)tok*D_);
  const ushort4* dp = (const ushort4*)(delta + (size_t)tok*D_);
  float4 a0 = zp[lane], a1 = zp[64+lane];
  ushort4 u0 = dp[lane], u1 = dp[64+lane];
  a0.x += b2f(u0.x); a0.y += b2f(u0.y); a0.z += b2f(u0.z); a0.w += b2f(u0.w);
  a1.x += b2f(u1.x); a1.y += b2f(u1.y); a1.z += b2f(u1.z); a1.w += b2f(u1.w);
  float s  = a0.x+a0.y+a0.z+a0.w + a1.x+a1.y+a1.z+a1.w;
  float sq = a0.x*a0.x+a0.y*a0.y+a0.z*a0.z+a0.w*a0.w
           + a1.x*a1.x+a1.y*a1.y+a1.z*a1.z+a1.w*a1.w;
  s = wred_add(s); sq = wred_add(sq);
  float mean = s * (1.f/D_);
  float var  = sq * (1.f/D_) - mean*mean;
  float rstd = rsqrtf(var + 1e-5f);
  const float4* g4 = (const float4*)g; const float4* b4 = (const float4*)b;
  float4 G0 = g4[lane], G1 = g4[64+lane], B0 = b4[lane], B1 = b4[64+lane];
  float4 o0, o1;
  o0.x = (a0.x-mean)*rstd*G0.x + B0.x; o0.y = (a0.y-mean)*rstd*G0.y + B0.y;
  o0.z = (a0.z-mean)*rstd*G0.z + B0.z; o0.w = (a0.w-mean)*rstd*G0.w + B0.w;
  o1.x = (a1.x-mean)*rstd*G1.x + B1.x; o1.y = (a1.y-mean)*rstd*G1.y + B1.y;
  o1.z = (a1.z-mean)*rstd*G1.z + B1.z; o1.w = (a1.w-mean)*rstd*G1.w + B1.w;
  zp[lane] = o0; zp[64+lane] = o1;
  unsigned short* zo = zb + (size_t)tok*D_;
  *(ushort4*)(zo + 4*lane)       = make_ushort4(f2b(o0.x), f2b(o0.y), f2b(o0.z), f2b(o0.w));
  *(ushort4*)(zo + 256 + 4*lane) = make_ushort4(f2b(o1.x), f2b(o1.y), f2b(o1.z), f2b(o1.w));
}

// ------ head_w transpose -> bf16 with BN-gamma fold: hwt[pr][n*512+d] ---------
__global__ void k_transw(const float* __restrict__ hw, const float* __restrict__ bng,
                         unsigned short* __restrict__ hwt){
  int dc = blockIdx.x, pr = blockIdx.y;
  int d0 = dc*64;
  __shared__ float tl[64*N_];
  const float* src = hw + (size_t)pr*KHEAD_ + (size_t)d0*N_;
  for (int i = threadIdx.x; i < 64*N_; i += 256) tl[i] = src[i];
  __syncthreads();
  const float sc = 0.9999950000374997f;   // 1/sqrt(1+1e-5)
  unsigned short* dst = hwt + (size_t)pr*KHEAD_;
  for (int i = threadIdx.x; i < 64*N_; i += 256){
    int n = i >> 6, dd = i & 63;
    dst[(size_t)n*D_ + d0 + dd] = f2b(tl[dd*N_ + n] * sc * bng[d0+dd]);
  }
}

// ------ bias2[pr] = head_b[pr] + sum_{d,n} bn_b[d]*head_w[pr][d*84+n] ---------
__global__ void k_bias2(const float* __restrict__ hw, const float* __restrict__ bnb,
                        const float* __restrict__ hb, float* __restrict__ bias2){
  int pr = blockIdx.x, tid = threadIdx.x;
  const float* src = hw + (size_t)pr*KHEAD_;
  float s = 0.f;
  for (int i = tid; i < KHEAD_; i += 256) s += src[i] * bnb[i / N_];
  __shared__ float rs[4];
  s = wred_add(s);
  int w = tid >> 6;
  if ((tid & 63) == 0) rs[w] = s;
  __syncthreads();
  if (tid == 0) bias2[pr] = hb[pr] + rs[0] + rs[1] + rs[2] + rs[3];
}

// ---------------- de-normalize + final transpose ----------------
__global__ void k_out(const float* __restrict__ dec, const float* __restrict__ stats,
                      float* __restrict__ out){
  int i = blockIdx.x*256 + threadIdx.x;
  if (i >= B_*PRED_*CVAR_) return;
  int c = i % CVAR_; int t = (i / CVAR_) % PRED_; int b = i / (CVAR_*PRED_);
  int bc = b*CVAR_ + c;
  out[i] = dec[(size_t)bc*PRED_ + t] * stats[BC_ + bc] + stats[bc];
}

extern "C" void kernel_launch(void* const* d_in, const int* in_sizes, int n_in,
                              void* d_out, int out_size, void* d_ws, size_t ws_size,
                              hipStream_t stream){
  const float* x_enc  = (const float*)d_in[0];
  const float* cls_w1 = (const float*)d_in[4];
  const float* cls_b1 = (const float*)d_in[5];
  const float* cls_w2 = (const float*)d_in[6];
  const float* cls_b2 = (const float*)d_in[7];
  const float* ew0 = (const float*)d_in[8];
  const float* ew1 = (const float*)d_in[9];
  const float* ew2 = (const float*)d_in[10];
  const float* ew3 = (const float*)d_in[11];
  const float* wq = (const float*)d_in[12]; const float* bq = (const float*)d_in[13];
  const float* wk = (const float*)d_in[14]; const float* bk = (const float*)d_in[15];
  const float* wv = (const float*)d_in[16]; const float* bv = (const float*)d_in[17];
  const float* wo = (const float*)d_in[18]; const float* bo = (const float*)d_in[19];
  const float* ln1_g = (const float*)d_in[20]; const float* ln1_b = (const float*)d_in[21];
  const float* ln2_g = (const float*)d_in[22]; const float* ln2_b = (const float*)d_in[23];
  const float* ff1_w = (const float*)d_in[24]; const float* ff1_b = (const float*)d_in[25];
  const float* ff2_w = (const float*)d_in[26]; const float* ff2_b = (const float*)d_in[27];
  const float* bn_g = (const float*)d_in[28]; const float* bn_b = (const float*)d_in[29];
  const float* head_w = (const float*)d_in[30]; const float* head_b = (const float*)d_in[31];
  float* out = (float*)d_out;

  // ---- workspace layout (256B-aligned regions) ----
  char* cur = (char*)d_ws;
  auto alloc = [&](size_t bytes)->char*{
    char* p = cur; cur += (bytes + 255) & ~(size_t)255; return p;
  };
  float* xc    = (float*)alloc(451584*4);
  float* stats = (float*)alloc(1344*4);
  int*   pred  = (int*)  alloc(9408*4);
  float* pe    = (float*)alloc(43008*4);
  float* ewt   = (float*)alloc(49152*4);
  unsigned short* wqkv_b = (unsigned short*)alloc((size_t)NL_*QKVN_*D_*2);
  float* bqkv  = (float*)alloc((size_t)NL_*QKVN_*4);
  unsigned short* wo_b  = (unsigned short*)alloc((size_t)NL_*D_*D_*2);
  unsigned short* ff1b  = (unsigned short*)alloc((size_t)NL_*DFF_*D_*2);
  unsigned short* ff2b  = (unsigned short*)alloc((size_t)NL_*D_*DFF_*2);
  unsigned short* hwt   = (unsigned short*)alloc((size_t)PRED_*KHEAD_*2);
  float* bias2 = (float*)alloc(PRED_*4);
  unsigned short* zfinal = (unsigned short*)alloc((size_t)M_*D_*2);
  char* E = cur;
  size_t E_avail = (ws_size > (size_t)(E - (char*)d_ws)) ? ws_size - (size_t)(E - (char*)d_ws) : 0;

  // chunk size: Cb in {672,224,96,32}; per-token scratch = 8192 B
  static const int cands[4] = {672, 224, 96, 32};
  int Cb = 32;
  for (int i = 0; i < 4; i++){
    size_t need = (size_t)8192 * cands[i] * N_;
    if (need <= E_avail){ Cb = cands[i]; break; }
  }
  const int nchunk = BC_ / Cb;
  const int Tc = Cb * N_;
  float*          z_c  = (float*)E;                                    // [Tc][512] f32
  unsigned short* zb_c = (unsigned short*)(E + (size_t)2048*Tc);       // [Tc][512] bf16
  unsigned short* r1   = (unsigned short*)(E + (size_t)3072*Tc);       // qkv [Tc][1536] / y1 [Tc][2048]
  unsigned short* abuf = (unsigned short*)(E + (size_t)6144*Tc);       // attn out [Tc][512]
  unsigned short* r2   = (unsigned short*)(E + (size_t)7168*Tc);       // delta [Tc][512] bf16
  // head-phase scratch (after encoder done)
  float* part = (float*)E;
  float* dec  = (float*)(E + (size_t)SK_*PM_*PN_*4);

  // ---- prologue ----
  k_instnorm<<<BC_, 256, 0, stream>>>(x_enc, xc, stats);
  k_router<<<(BC_*R_ + 255)/256, 256, 0, stream>>>(xc, cls_w1, cls_b1, cls_w2, cls_b2, pred);
  k_pe<<<(N_*D_ + 255)/256, 256, 0, stream>>>(pe);
  k_transe<<<192, 256, 0, stream>>>(ew0, ew1, ew2, ew3, ewt);
  int nqkvg = NL_*QKVN_*D_/4, nw4 = NL_*D_*D_/4, nff4 = NL_*DFF_*D_/4;
  k_cvtqkv<<<(nqkvg+255)/256, 256, 0, stream>>>(wq, wk, wv, wqkv_b);
  k_catbias<<<(NL_*QKVN_+255)/256, 256, 0, stream>>>(bq, bk, bv, bqkv);
  k_cvt<<<(nw4+255)/256, 256, 0, stream>>>(wo, wo_b, nw4);
  k_cvt<<<(nff4+255)/256, 256, 0, stream>>>(ff1_w, ff1b, nff4);
  k_cvt<<<(nff4+255)/256, 256, 0, stream>>>(ff2_w, ff2b, nff4);
  k_transw<<<dim3(8, PRED_), 256, 0, stream>>>(head_w, bn_g, hwt);
  k_bias2<<<PRED_, 256, 0, stream>>>(head_w, bn_b, head_b, bias2);

  // ---- encoder (chunked over bc; chunks fully independent) ----
  for (int ch = 0; ch < nchunk; ch++){
    int bc0 = ch*Cb;
    k_embed<<<Cb*R_, 256, 0, stream>>>(xc, pred, ewt, pe, z_c, zb_c, bc0);
    for (int l = 0; l < NL_; l++){
      k_mm<false,true><<<(QKVN_/128)*(Tc/128), 256, 0, stream>>>(
          zb_c, wqkv_b + (size_t)l*QKVN_*D_, bqkv + l*QKVN_, r1, Tc, QKVN_, D_);
      k_attn<<<Cb*H_, 384, 0, stream>>>(r1, abuf);
      k_mm<false,true><<<(D_/128)*(Tc/128), 256, 0, stream>>>(
          abuf, wo_b + (size_t)l*D_*D_, bo + l*D_, r2, Tc, D_, D_);
      k_addln<<<Tc/4, 256, 0, stream>>>(z_c, r2, ln1_g+l*D_, ln1_b+l*D_, zb_c, Tc);
      size_t foff = (size_t)l*DFF_*D_;
      k_mm<true,true><<<(DFF_/128)*(Tc/128), 256, 0, stream>>>(
          zb_c, ff1b+foff, ff1_b+l*DFF_, r1, Tc, DFF_, D_);
      k_mm<false,true><<<(D_/128)*(Tc/128), 256, 0, stream>>>(
          r1, ff2b+foff, ff2_b+l*D_, r2, Tc, D_, DFF_);
      unsigned short* zb_out = (l == NL_-1) ? (zfinal + (size_t)bc0*N_*D_) : zb_c;
      k_addln<<<Tc/4, 256, 0, stream>>>(z_c, r2, ln2_g+l*D_, ln2_b+l*D_, zb_out, Tc);
    }
  }

  // ---- head: dec = zfinal @ hwt^T (split-K) + bias2, then de-normalize ----
  k_mm_part<<<dim3(PN_/128, PM_/128, SK_), 256, 0, stream>>>(zfinal, hwt, part, KHEAD_/SK_);
  k_headred<<<(BC_*PRED_ + 255)/256, 256, 0, stream>>>(part, bias2, dec);
  k_out<<<(B_*PRED_*CVAR_ + 255)/256, 256, 0, stream>>>(dec, stats, out);
}

// Round 11
// 1769.463 us; speedup vs baseline: 1.0994x; 1.0994x over previous
//
#include <hip/hip_runtime.h>
#include <hip/hip_bf16.h>
#include <math.h>

#define B_    32
#define SEQ_  672
#define CVAR_ 21
#define PRED_ 336
#define D_    512
#define H_    8
#define DFF_  2048
#define NL_   2
#define R_    14
#define T_    6
#define N_    84
#define BC_   672           // B_*CVAR_
#define M_    (BC_*N_)      // 56448 tokens
#define KHEAD_ (D_*N_)      // 43008
#define SK_   16            // head split-K
#define PM_   768           // head M padded to 6*128
#define PN_   384           // head N padded to 3*128
#define QKVN_ 1536          // fused qkv width

typedef __attribute__((ext_vector_type(8))) short bh8;
typedef __attribute__((ext_vector_type(4))) float f32x4;

__device__ __forceinline__ unsigned short f2b(float x){
  union { float f; unsigned int u; } v; v.f = x;
  unsigned int r = v.u + 0x7FFFu + ((v.u >> 16) & 1u);   // RNE
  return (unsigned short)(r >> 16);
}
__device__ __forceinline__ float b2f(unsigned short h){
  union { unsigned int u; float f; } v; v.u = ((unsigned int)h) << 16;
  return v.f;
}
__device__ __forceinline__ float wred_add(float v){
  #pragma unroll
  for (int o = 32; o; o >>= 1) v += __shfl_xor(v, o, 64);
  return v;
}
// async global->LDS, 16B per lane; lds base must be wave-uniform
__device__ __forceinline__ void stage16(const unsigned short* g, unsigned short* l){
  __builtin_amdgcn_global_load_lds(
      (const __attribute__((address_space(1))) unsigned int*)(const void*)g,
      (__attribute__((address_space(3))) unsigned int*)(void*)l, 16, 0, 0);
}

// ---------------- instance norm over time ----------------
__global__ void k_instnorm(const float* __restrict__ x, float* __restrict__ xc,
                           float* __restrict__ stats){
  int bc = blockIdx.x; int b = bc / CVAR_, c = bc % CVAR_;
  const float* xp = x + (size_t)b*SEQ_*CVAR_ + c;
  int tid = threadIdx.x;
  float s = 0.f, sq = 0.f;
  for (int l = tid; l < SEQ_; l += 256){ float v = xp[(size_t)l*CVAR_]; s += v; sq += v*v; }
  __shared__ float rs[4], rq[4];
  s = wred_add(s); sq = wred_add(sq);
  int w = tid >> 6, lane = tid & 63;
  if (lane == 0){ rs[w] = s; rq[w] = sq; }
  __syncthreads();
  if (tid == 0){
    float S = rs[0]+rs[1]+rs[2]+rs[3], Q = rq[0]+rq[1]+rq[2]+rq[3];
    float mean = S * (1.f/SEQ_);
    float var  = Q * (1.f/SEQ_) - mean*mean;
    float stdev = sqrtf(var + 1e-5f);
    stats[bc] = mean; stats[BC_ + bc] = stdev;
    rs[0] = mean; rq[0] = stdev;
  }
  __syncthreads();
  float mean = rs[0], inv = 1.f / rq[0];
  for (int l = tid; l < SEQ_; l += 256)
    xc[(size_t)bc*SEQ_ + l] = (xp[(size_t)l*CVAR_] - mean) * inv;
}

// ---------------- region router ----------------
__global__ void k_router(const float* __restrict__ xc,
                         const float* __restrict__ w1, const float* __restrict__ b1,
                         const float* __restrict__ w2, const float* __restrict__ b2,
                         int* __restrict__ pred){
  int t = blockIdx.x*256 + threadIdx.x;
  if (t >= BC_*R_) return;
  int bc = t / R_, r = t % R_;
  const float* xr = xc + (size_t)bc*SEQ_ + r*48;
  float xs[48];
  #pragma unroll
  for (int i = 0; i < 48; i++) xs[i] = xr[i];
  float hdn[64];
  #pragma unroll 4
  for (int h = 0; h < 64; h++){
    float a = b1[h];
    const float* wr = w1 + h*48;
    #pragma unroll
    for (int i = 0; i < 48; i++) a = fmaf(xs[i], wr[i], a);
    hdn[h] = fmaxf(a, 0.f);
  }
  float best = -1e30f; int be = 0;
  for (int e = 0; e < 4; e++){
    float lg = b2[e];
    const float* wr = w2 + e*64;
    #pragma unroll 8
    for (int h = 0; h < 64; h++) lg = fmaf(hdn[h], wr[h], lg);
    if (lg > best){ best = lg; be = e; }   // first max wins (strict >)
  }
  pred[t] = be;
}

// ---------------- positional encoding ----------------
__global__ void k_pe(float* __restrict__ pe){
  int i = blockIdx.x*256 + threadIdx.x;
  if (i >= N_*D_) return;
  int n = i / D_, d = i % D_;
  int ii = d >> 1;
  float freq = expf((float)(2*ii) * (-9.210340371976184f / (float)D_)); // -ln(10000)/D
  float a = (float)n * freq;
  pe[i] = (d & 1) ? cosf(a) : sinf(a);
}

// ---------------- fp32 -> bf16 convert (n4 = elems/4) ----------------
__global__ void k_cvt(const float* __restrict__ in, unsigned short* __restrict__ out, int n4){
  int i = blockIdx.x*256 + threadIdx.x;
  if (i >= n4) return;
  float4 v = ((const float4*)in)[i];
  ((ushort4*)out)[i] = make_ushort4(f2b(v.x), f2b(v.y), f2b(v.z), f2b(v.w));
}

// ---------------- fused qkv weight convert (concat rows) ----------------
__global__ void k_cvtqkv(const float* __restrict__ wq, const float* __restrict__ wk,
                         const float* __restrict__ wv, unsigned short* __restrict__ o){
  int i = blockIdx.x*256 + threadIdx.x;          // one per 4 elems
  const int per_l = QKVN_*D_/4;                  // 196608
  const int per_s = D_*D_/4;                     // 65536
  if (i >= NL_*per_l) return;
  int l = i / per_l;
  int rem = i - l*per_l;
  int sec = rem / per_s;
  int off = rem - sec*per_s;
  const float* src = (sec==0 ? wq : sec==1 ? wk : wv) + (size_t)l*D_*D_ + (size_t)off*4;
  float4 v = *(const float4*)src;
  ((ushort4*)o)[i] = make_ushort4(f2b(v.x), f2b(v.y), f2b(v.z), f2b(v.w));
}

// ---------------- qkv bias concat ----------------
__global__ void k_catbias(const float* __restrict__ bq, const float* __restrict__ bk,
                          const float* __restrict__ bv, float* __restrict__ bqkv){
  int i = blockIdx.x*256 + threadIdx.x;
  if (i >= NL_*QKVN_) return;
  int l = i / QKVN_, r = i % QKVN_;
  float v = (r < 512) ? bq[l*512 + r] : (r < 1024) ? bk[l*512 + r - 512] : bv[l*512 + r - 1024];
  bqkv[i] = v;
}

// ------ expert weight transpose: W_e[d][q] -> wt[base_e + q*512 + d] ----------
__global__ void k_transe(const float* __restrict__ w0, const float* __restrict__ w1,
                         const float* __restrict__ w2, const float* __restrict__ w3,
                         float* __restrict__ wt){
  int i = blockIdx.x*256 + threadIdx.x;
  if (i >= 49152) return;
  int e, base, p;
  if (i < 4096){ e = 0; base = 0; p = 8; }
  else if (i < 12288){ e = 1; base = 4096; p = 16; }
  else if (i < 24576){ e = 2; base = 12288; p = 24; }
  else { e = 3; base = 24576; p = 48; }
  int local = i - base;
  int q = local >> 9, d = local & 511;
  const float* W = (e==0) ? w0 : (e==1) ? w1 : (e==2) ? w2 : w3;
  wt[base + q*512 + d] = W[(size_t)d*p + q];
}

// ---------------- patch embedding + PE (coalesced transposed weights) ---------
__global__ void k_embed(const float* __restrict__ xc, const int* __restrict__ pred,
                        const float* __restrict__ wt, const float* __restrict__ pe,
                        unsigned short* __restrict__ zb, int bc0){
  int blk = blockIdx.x; int bcl = blk / R_, r = blk % R_;
  int bc = bc0 + bcl;
  __shared__ float xr[48];
  int tid = threadIdx.x;
  if (tid < 48) xr[tid] = xc[(size_t)bc*SEQ_ + r*48 + tid];
  __syncthreads();
  int e = pred[bc*R_ + r];
  int p    = (e==0) ? 8 : (e==1) ? 16 : (e==2) ? 24 : 48;
  int base = (e==0) ? 0 : (e==1) ? 4096 : (e==2) ? 12288 : 24576;
  int num = 48 / p, rep = 7 - num;
  const float* Wt = wt + base;
  int d0 = tid, d1 = tid + 256;
  float acc0[6], acc1[6];
  #pragma unroll
  for (int u = 0; u < 6; u++){ acc0[u] = 0.f; acc1[u] = 0.f; }
  #pragma unroll
  for (int u = 0; u < 6; u++){
    if (u < num){
      float s0 = 0.f, s1 = 0.f;
      const float* xu = xr + u*p;
      for (int q = 0; q < p; q++){
        float xv = xu[q];
        const float* wrow = Wt + q*512;
        s0 = fmaf(xv, wrow[d0], s0);
        s1 = fmaf(xv, wrow[d1], s1);
      }
      acc0[u] = s0; acc1[u] = s1;
    }
  }
  #pragma unroll
  for (int u = 0; u < 6; u++){
    if (u < num){
      #pragma unroll
      for (int t = 0; t < 6; t++){
        int ut = t / rep; if (ut > num-1) ut = num-1;
        if (ut == u){
          int n = r*T_ + t;
          size_t off = ((size_t)bcl*N_ + n)*D_;
          zb[off + d0] = f2b(acc0[u] + pe[n*D_ + d0]);
          zb[off + d1] = f2b(acc1[u] + pe[n*D_ + d1]);
        }
      }
    }
  }
}

// ---------------- bf16 MFMA GEMM: C[M,N] = act(A[M,K] * B[N,K]^T + bias) ------
// 128x128 tile, BK=32, 256 thr (4 waves, 2x2), 4x4 16x16x32 frags per wave.
// Double-buffered LDS with COUNTED vmcnt(4): next-tile loads stay in flight
// across the barrier. Second bare barrier = WAR protection.
// M % 128 == 0, N % 128 == 0, K % 32 == 0, K >= 64.
template<bool GELU, bool OBF16>
__global__ __launch_bounds__(256) void k_mm(const unsigned short* __restrict__ A,
      const unsigned short* __restrict__ Bw, const float* __restrict__ bias,
      void* __restrict__ Cp, int M, int N, int K){
  __shared__ unsigned short As[2][128*32];
  __shared__ unsigned short Bs[2][128*32];
  int tid = threadIdx.x;
  int lane = tid & 63;
  int wave = tid >> 6;
  int wr = wave >> 1, wc = wave & 1;
  // bijective XCD swizzle (m204): contiguous wgid chunk per XCD
  int nx = N >> 7;
  int nwg = gridDim.x;
  int orig = blockIdx.x;
  int q = nwg >> 3, r8 = nwg & 7;
  int xcd = orig & 7, idx = orig >> 3;
  int wgid = (xcd < r8 ? xcd*(q+1) : r8*(q+1) + (xcd - r8)*q) + idx;
  int m0 = (wgid / nx) << 7;
  int n0 = (wgid % nx) << 7;
  int eb0 = (tid & 192);                   // wave-uniform chunk base, group 0
  int e0 = eb0 + lane, e1 = eb0 + 256 + lane;
  int row0 = e0 >> 2, kc0 = (e0 & 3) << 3;
  int row1 = e1 >> 2, kc1 = (e1 & 3) << 3;
  const unsigned short* a0 = A  + (size_t)(m0+row0)*K + kc0;
  const unsigned short* a1 = A  + (size_t)(m0+row1)*K + kc1;
  const unsigned short* b0 = Bw + (size_t)(n0+row0)*K + kc0;
  const unsigned short* b1 = Bw + (size_t)(n0+row1)*K + kc1;
  f32x4 acc[4][4];
  #pragma unroll
  for (int m = 0; m < 4; m++)
    #pragma unroll
    for (int n = 0; n < 4; n++) acc[m][n] = (f32x4){0.f,0.f,0.f,0.f};

  stage16(a0, &As[0][eb0*8]);
  stage16(a1, &As[0][(eb0+256)*8]);
  stage16(b0, &Bs[0][eb0*8]);
  stage16(b1, &Bs[0][(eb0+256)*8]);
  int cur = 0;
  for (int k0 = 0; k0 < K - 32; k0 += 32){
    int nb = cur ^ 1, ko = k0 + 32;
    stage16(a0 + ko, &As[nb][eb0*8]);
    stage16(a1 + ko, &As[nb][(eb0+256)*8]);
    stage16(b0 + ko, &Bs[nb][eb0*8]);
    stage16(b1 + ko, &Bs[nb][(eb0+256)*8]);
    asm volatile("s_waitcnt vmcnt(4)" ::: "memory");
    __builtin_amdgcn_s_barrier();
    __builtin_amdgcn_sched_barrier(0);
    bh8 fa[4], fb[4];
    #pragma unroll
    for (int m = 0; m < 4; m++)
      fa[m] = *(const bh8*)&As[cur][(wr*64 + m*16 + (lane & 15))*32 + (lane >> 4)*8];
    #pragma unroll
    for (int n = 0; n < 4; n++)
      fb[n] = *(const bh8*)&Bs[cur][(wc*64 + n*16 + (lane & 15))*32 + (lane >> 4)*8];
    #pragma unroll
    for (int m = 0; m < 4; m++)
      #pragma unroll
      for (int n = 0; n < 4; n++)
        acc[m][n] = __builtin_amdgcn_mfma_f32_16x16x32_bf16(fa[m], fb[n], acc[m][n], 0, 0, 0);
    __builtin_amdgcn_sched_barrier(0);
    __builtin_amdgcn_s_barrier();          // WAR: all reads of buf[cur] done
    cur ^= 1;
  }
  asm volatile("s_waitcnt vmcnt(0)" ::: "memory");
  __builtin_amdgcn_s_barrier();
  __builtin_amdgcn_sched_barrier(0);
  {
    bh8 fa[4], fb[4];
    #pragma unroll
    for (int m = 0; m < 4; m++)
      fa[m] = *(const bh8*)&As[cur][(wr*64 + m*16 + (lane & 15))*32 + (lane >> 4)*8];
    #pragma unroll
    for (int n = 0; n < 4; n++)
      fb[n] = *(const bh8*)&Bs[cur][(wc*64 + n*16 + (lane & 15))*32 + (lane >> 4)*8];
    #pragma unroll
    for (int m = 0; m < 4; m++)
      #pragma unroll
      for (int n = 0; n < 4; n++)
        acc[m][n] = __builtin_amdgcn_mfma_f32_16x16x32_bf16(fa[m], fb[n], acc[m][n], 0, 0, 0);
  }
  int rbase = m0 + wr*64 + (lane >> 4)*4;
  int cbase = n0 + wc*64 + (lane & 15);
  #pragma unroll
  for (int n = 0; n < 4; n++){
    int col = cbase + n*16;
    float bs = bias[col];
    #pragma unroll
    for (int m = 0; m < 4; m++){
      int row = rbase + m*16;
      #pragma unroll
      for (int j = 0; j < 4; j++){
        float cv = acc[m][n][j] + bs;
        if (GELU) cv = 0.5f*cv*(1.f + erff(cv*0.70710678118654752f));
        if (OBF16) ((unsigned short*)Cp)[(size_t)(row+j)*N + col] = f2b(cv);
        else       ((float*)Cp)[(size_t)(row+j)*N + col] = cv;
      }
    }
  }
}

// ---------------- head GEMM, split-K partials (rows/cols clamped) -------------
__global__ __launch_bounds__(256) void k_mm_part(const unsigned short* __restrict__ A,
      const unsigned short* __restrict__ Bw, float* __restrict__ part, int kchunk){
  __shared__ unsigned short As[2][128*32];
  __shared__ unsigned short Bs[2][128*32];
  int tid = threadIdx.x;
  int lane = tid & 63, wave = tid >> 6;
  int wr = wave >> 1, wc = wave & 1;
  int m0 = blockIdx.y*128, n0 = blockIdx.x*128;
  int kb0 = blockIdx.z*kchunk;
  int eb0 = (tid & 192);
  int e0 = eb0 + lane, e1 = eb0 + 256 + lane;
  int row0 = e0 >> 2, kc0 = (e0 & 3) << 3;
  int row1 = e1 >> 2, kc1 = (e1 & 3) << 3;
  int ar0 = m0 + row0; if (ar0 >= BC_)  ar0 = BC_ - 1;
  int ar1 = m0 + row1; if (ar1 >= BC_)  ar1 = BC_ - 1;
  int br0 = n0 + row0; if (br0 >= PRED_) br0 = PRED_ - 1;
  int br1 = n0 + row1; if (br1 >= PRED_) br1 = PRED_ - 1;
  const unsigned short* a0 = A  + (size_t)ar0*KHEAD_ + kb0 + kc0;
  const unsigned short* a1 = A  + (size_t)ar1*KHEAD_ + kb0 + kc1;
  const unsigned short* b0 = Bw + (size_t)br0*KHEAD_ + kb0 + kc0;
  const unsigned short* b1 = Bw + (size_t)br1*KHEAD_ + kb0 + kc1;
  f32x4 acc[4][4];
  #pragma unroll
  for (int m = 0; m < 4; m++)
    #pragma unroll
    for (int n = 0; n < 4; n++) acc[m][n] = (f32x4){0.f,0.f,0.f,0.f};

  stage16(a0, &As[0][eb0*8]);
  stage16(a1, &As[0][(eb0+256)*8]);
  stage16(b0, &Bs[0][eb0*8]);
  stage16(b1, &Bs[0][(eb0+256)*8]);
  int cur = 0;
  for (int ko = 0; ko < kchunk - 32; ko += 32){
    int nb = cur ^ 1, kk = ko + 32;
    stage16(a0 + kk, &As[nb][eb0*8]);
    stage16(a1 + kk, &As[nb][(eb0+256)*8]);
    stage16(b0 + kk, &Bs[nb][eb0*8]);
    stage16(b1 + kk, &Bs[nb][(eb0+256)*8]);
    asm volatile("s_waitcnt vmcnt(4)" ::: "memory");
    __builtin_amdgcn_s_barrier();
    __builtin_amdgcn_sched_barrier(0);
    bh8 fa[4], fb[4];
    #pragma unroll
    for (int m = 0; m < 4; m++)
      fa[m] = *(const bh8*)&As[cur][(wr*64 + m*16 + (lane & 15))*32 + (lane >> 4)*8];
    #pragma unroll
    for (int n = 0; n < 4; n++)
      fb[n] = *(const bh8*)&Bs[cur][(wc*64 + n*16 + (lane & 15))*32 + (lane >> 4)*8];
    #pragma unroll
    for (int m = 0; m < 4; m++)
      #pragma unroll
      for (int n = 0; n < 4; n++)
        acc[m][n] = __builtin_amdgcn_mfma_f32_16x16x32_bf16(fa[m], fb[n], acc[m][n], 0, 0, 0);
    __builtin_amdgcn_sched_barrier(0);
    __builtin_amdgcn_s_barrier();
    cur ^= 1;
  }
  asm volatile("s_waitcnt vmcnt(0)" ::: "memory");
  __builtin_amdgcn_s_barrier();
  __builtin_amdgcn_sched_barrier(0);
  {
    bh8 fa[4], fb[4];
    #pragma unroll
    for (int m = 0; m < 4; m++)
      fa[m] = *(const bh8*)&As[cur][(wr*64 + m*16 + (lane & 15))*32 + (lane >> 4)*8];
    #pragma unroll
    for (int n = 0; n < 4; n++)
      fb[n] = *(const bh8*)&Bs[cur][(wc*64 + n*16 + (lane & 15))*32 + (lane >> 4)*8];
    #pragma unroll
    for (int m = 0; m < 4; m++)
      #pragma unroll
      for (int n = 0; n < 4; n++)
        acc[m][n] = __builtin_amdgcn_mfma_f32_16x16x32_bf16(fa[m], fb[n], acc[m][n], 0, 0, 0);
  }
  float* po = part + (size_t)blockIdx.z*PM_*PN_;
  int rbase = m0 + wr*64 + (lane >> 4)*4;
  int cbase = n0 + wc*64 + (lane & 15);
  #pragma unroll
  for (int n = 0; n < 4; n++){
    int col = cbase + n*16;
    #pragma unroll
    for (int m = 0; m < 4; m++){
      int row = rbase + m*16;
      #pragma unroll
      for (int j = 0; j < 4; j++)
        po[(size_t)(row+j)*PN_ + col] = acc[m][n][j];
    }
  }
}

// ---------------- head reduce + bias ----------------
__global__ void k_headred(const float* __restrict__ part, const float* __restrict__ bias2,
                          float* __restrict__ dec){
  int i = blockIdx.x*256 + threadIdx.x;
  if (i >= BC_*PRED_) return;
  int bc = i / PRED_, pr = i % PRED_;
  float s = bias2[pr];
  #pragma unroll
  for (int sk = 0; sk < SK_; sk++)
    s += part[(size_t)sk*PM_*PN_ + (size_t)bc*PN_ + pr];
  dec[i] = s;
}

// -------- MFMA fused attention: block = (bc-local, head), 6 waves -------------
__global__ __launch_bounds__(384) void k_attn(const unsigned short* __restrict__ qkv,
                                              unsigned short* __restrict__ o){
  __shared__ unsigned short Qb[96][72];       // stride 144B: 2-way alias (free)
  __shared__ unsigned short Kb[96][72];
  __shared__ unsigned short Vt[64][104];      // V transposed; stride 208B
  __shared__ unsigned short Pb[6][16][104];
  int bh = blockIdx.x; int bcl = bh >> 3, h = bh & 7;
  int tid = threadIdx.x, lane = tid & 63, wv = tid >> 6;   // wv = row-tile 0..5
  size_t qb = (size_t)bcl*N_*QKVN_ + h*64;
  for (int g = tid; g < 1536; g += 384){
    int n = g >> 4, d4 = (g & 15) << 2;
    ushort4 qv = make_ushort4(0,0,0,0), kv = make_ushort4(0,0,0,0);
    if (n < N_){
      qv = *(const ushort4*)(qkv + qb + (size_t)n*QKVN_ + d4);
      kv = *(const ushort4*)(qkv + qb + 512 + (size_t)n*QKVN_ + d4);
    }
    *(ushort4*)&Qb[n][d4] = qv;
    *(ushort4*)&Kb[n][d4] = kv;
  }
  for (int g = tid; g < N_*16; g += 384){
    int n = g >> 4, d4 = (g & 15) << 2;
    ushort4 vv = *(const ushort4*)(qkv + qb + 1024 + (size_t)n*QKVN_ + d4);
    Vt[d4+0][n] = vv.x; Vt[d4+1][n] = vv.y; Vt[d4+2][n] = vv.z; Vt[d4+3][n] = vv.w;
  }
  for (int g = tid; g < 64*12; g += 384) Vt[g/12][N_ + g%12] = 0;
  __syncthreads();
  f32x4 acc[6];
  #pragma unroll
  for (int t = 0; t < 6; t++) acc[t] = (f32x4){0.f,0.f,0.f,0.f};
  #pragma unroll
  for (int ks = 0; ks < 2; ks++){
    bh8 qa = *(const bh8*)&Qb[wv*16 + (lane & 15)][ks*32 + (lane >> 4)*8];
    #pragma unroll
    for (int t = 0; t < 6; t++){
      bh8 kf = *(const bh8*)&Kb[t*16 + (lane & 15)][ks*32 + (lane >> 4)*8];
      acc[t] = __builtin_amdgcn_mfma_f32_16x16x32_bf16(qa, kf, acc[t], 0, 0, 0);
    }
  }
  bool v5 = (lane & 15) < 4;
  #pragma unroll
  for (int j = 0; j < 4; j++){
    float m = -1e30f;
    #pragma unroll
    for (int t = 0; t < 6; t++){
      float s = acc[t][j] * 0.125f;
      if (t == 5 && !v5) s = -1e30f;
      acc[t][j] = s;
      m = fmaxf(m, s);
    }
    #pragma unroll
    for (int off = 1; off < 16; off <<= 1) m = fmaxf(m, __shfl_xor(m, off, 64));
    float sum = 0.f;
    #pragma unroll
    for (int t = 0; t < 6; t++){
      float p = __expf(acc[t][j] - m);
      acc[t][j] = p;
      sum += p;
    }
    #pragma unroll
    for (int off = 1; off < 16; off <<= 1) sum += __shfl_xor(sum, off, 64);
    float inv = 1.f / sum;
    int lr = (lane >> 4)*4 + j;
    #pragma unroll
    for (int t = 0; t < 6; t++)
      Pb[wv][lr][t*16 + (lane & 15)] = f2b(acc[t][j] * inv);
  }
  f32x4 accO[4];
  #pragma unroll
  for (int dt = 0; dt < 4; dt++) accO[dt] = (f32x4){0.f,0.f,0.f,0.f};
  #pragma unroll
  for (int ks = 0; ks < 3; ks++){
    bh8 pa = *(const bh8*)&Pb[wv][lane & 15][ks*32 + (lane >> 4)*8];
    #pragma unroll
    for (int dt = 0; dt < 4; dt++){
      bh8 vf = *(const bh8*)&Vt[dt*16 + (lane & 15)][ks*32 + (lane >> 4)*8];
      accO[dt] = __builtin_amdgcn_mfma_f32_16x16x32_bf16(pa, vf, accO[dt], 0, 0, 0);
    }
  }
  size_t ob = (size_t)bcl*N_*D_ + h*64;
  #pragma unroll
  for (int dt = 0; dt < 4; dt++)
    #pragma unroll
    for (int j = 0; j < 4; j++){
      int r = wv*16 + (lane >> 4)*4 + j;
      if (r < N_) o[ob + (size_t)r*D_ + dt*16 + (lane & 15)] = f2b(accO[dt][j]);
    }
}

// ---------- fused residual-add + LayerNorm, bf16 residual master --------------
__global__ __launch_bounds__(256) void k_addln(const unsigned short* zin,
                        const unsigned short* __restrict__ delta,
                        const float* __restrict__ g, const float* __restrict__ b,
                        unsigned short* zout, int ntok){
  int w = threadIdx.x >> 6, lane = threadIdx.x & 63;
  int tok = blockIdx.x*4 + w;
  if (tok >= ntok) return;
  const ushort4* zp = (const ushort4*)(zin + (size_t)tok*D_);
  const ushort4* dp = (const ushort4*)(delta + (size_t)tok*D_);
  ushort4 z0 = zp[lane], z1 = zp[64+lane];
  ushort4 u0 = dp[lane], u1 = dp[64+lane];
  float4 a0, a1;
  a0.x = b2f(z0.x) + b2f(u0.x); a0.y = b2f(z0.y) + b2f(u0.y);
  a0.z = b2f(z0.z) + b2f(u0.z); a0.w = b2f(z0.w) + b2f(u0.w);
  a1.x = b2f(z1.x) + b2f(u1.x); a1.y = b2f(z1.y) + b2f(u1.y);
  a1.z = b2f(z1.z) + b2f(u1.z); a1.w = b2f(z1.w) + b2f(u1.w);
  float s  = a0.x+a0.y+a0.z+a0.w + a1.x+a1.y+a1.z+a1.w;
  float sq = a0.x*a0.x+a0.y*a0.y+a0.z*a0.z+a0.w*a0.w
           + a1.x*a1.x+a1.y*a1.y+a1.z*a1.z+a1.w*a1.w;
  s = wred_add(s); sq = wred_add(sq);
  float mean = s * (1.f/D_);
  float var  = sq * (1.f/D_) - mean*mean;
  float rstd = rsqrtf(var + 1e-5f);
  const float4* g4 = (const float4*)g; const float4* b4 = (const float4*)b;
  float4 G0 = g4[lane], G1 = g4[64+lane], B0 = b4[lane], B1 = b4[64+lane];
  unsigned short* zo = zout + (size_t)tok*D_;
  *(ushort4*)(zo + 4*lane) = make_ushort4(
      f2b((a0.x-mean)*rstd*G0.x + B0.x), f2b((a0.y-mean)*rstd*G0.y + B0.y),
      f2b((a0.z-mean)*rstd*G0.z + B0.z), f2b((a0.w-mean)*rstd*G0.w + B0.w));
  *(ushort4*)(zo + 256 + 4*lane) = make_ushort4(
      f2b((a1.x-mean)*rstd*G1.x + B1.x), f2b((a1.y-mean)*rstd*G1.y + B1.y),
      f2b((a1.z-mean)*rstd*G1.z + B1.z), f2b((a1.w-mean)*rstd*G1.w + B1.w));
}

// ------ head_w transpose -> bf16 with BN-gamma fold: hwt[pr][n*512+d] ---------
__global__ void k_transw(const float* __restrict__ hw, const float* __restrict__ bng,
                         unsigned short* __restrict__ hwt){
  int dc = blockIdx.x, pr = blockIdx.y;
  int d0 = dc*64;
  __shared__ float tl[64*N_];
  const float* src = hw + (size_t)pr*KHEAD_ + (size_t)d0*N_;
  for (int i = threadIdx.x; i < 64*N_; i += 256) tl[i] = src[i];
  __syncthreads();
  const float sc = 0.9999950000374997f;   // 1/sqrt(1+1e-5)
  unsigned short* dst = hwt + (size_t)pr*KHEAD_;
  for (int i = threadIdx.x; i < 64*N_; i += 256){
    int n = i >> 6, dd = i & 63;
    dst[(size_t)n*D_ + d0 + dd] = f2b(tl[dd*N_ + n] * sc * bng[d0+dd]);
  }
}

// ------ bias2[pr] = head_b[pr] + sum_{d,n} bn_b[d]*head_w[pr][d*84+n] ---------
__global__ void k_bias2(const float* __restrict__ hw, const float* __restrict__ bnb,
                        const float* __restrict__ hb, float* __restrict__ bias2){
  int pr = blockIdx.x, tid = threadIdx.x;
  const float* src = hw + (size_t)pr*KHEAD_;
  float s = 0.f;
  for (int i = tid; i < KHEAD_; i += 256) s += src[i] * bnb[i / N_];
  __shared__ float rs[4];
  s = wred_add(s);
  int w = tid >> 6;
  if ((tid & 63) == 0) rs[w] = s;
  __syncthreads();
  if (tid == 0) bias2[pr] = hb[pr] + rs[0] + rs[1] + rs[2] + rs[3];
}

// ---------------- de-normalize + final transpose ----------------
__global__ void k_out(const float* __restrict__ dec, const float* __restrict__ stats,
                      float* __restrict__ out){
  int i = blockIdx.x*256 + threadIdx.x;
  if (i >= B_*PRED_*CVAR_) return;
  int c = i % CVAR_; int t = (i / CVAR_) % PRED_; int b = i / (CVAR_*PRED_);
  int bc = b*CVAR_ + c;
  out[i] = dec[(size_t)bc*PRED_ + t] * stats[BC_ + bc] + stats[bc];
}

extern "C" void kernel_launch(void* const* d_in, const int* in_sizes, int n_in,
                              void* d_out, int out_size, void* d_ws, size_t ws_size,
                              hipStream_t stream){
  const float* x_enc  = (const float*)d_in[0];
  const float* cls_w1 = (const float*)d_in[4];
  const float* cls_b1 = (const float*)d_in[5];
  const float* cls_w2 = (const float*)d_in[6];
  const float* cls_b2 = (const float*)d_in[7];
  const float* ew0 = (const float*)d_in[8];
  const float* ew1 = (const float*)d_in[9];
  const float* ew2 = (const float*)d_in[10];
  const float* ew3 = (const float*)d_in[11];
  const float* wq = (const float*)d_in[12]; const float* bq = (const float*)d_in[13];
  const float* wk = (const float*)d_in[14]; const float* bk = (const float*)d_in[15];
  const float* wv = (const float*)d_in[16]; const float* bv = (const float*)d_in[17];
  const float* wo = (const float*)d_in[18]; const float* bo = (const float*)d_in[19];
  const float* ln1_g = (const float*)d_in[20]; const float* ln1_b = (const float*)d_in[21];
  const float* ln2_g = (const float*)d_in[22]; const float* ln2_b = (const float*)d_in[23];
  const float* ff1_w = (const float*)d_in[24]; const float* ff1_b = (const float*)d_in[25];
  const float* ff2_w = (const float*)d_in[26]; const float* ff2_b = (const float*)d_in[27];
  const float* bn_g = (const float*)d_in[28]; const float* bn_b = (const float*)d_in[29];
  const float* head_w = (const float*)d_in[30]; const float* head_b = (const float*)d_in[31];
  float* out = (float*)d_out;

  // ---- workspace layout (256B-aligned regions) ----
  char* cur = (char*)d_ws;
  auto alloc = [&](size_t bytes)->char*{
    char* p = cur; cur += (bytes + 255) & ~(size_t)255; return p;
  };
  float* xc    = (float*)alloc(451584*4);
  float* stats = (float*)alloc(1344*4);
  int*   pred  = (int*)  alloc(9408*4);
  float* pe    = (float*)alloc(43008*4);
  float* ewt   = (float*)alloc(49152*4);
  unsigned short* wqkv_b = (unsigned short*)alloc((size_t)NL_*QKVN_*D_*2);
  float* bqkv  = (float*)alloc((size_t)NL_*QKVN_*4);
  unsigned short* wo_b  = (unsigned short*)alloc((size_t)NL_*D_*D_*2);
  unsigned short* ff1b  = (unsigned short*)alloc((size_t)NL_*DFF_*D_*2);
  unsigned short* ff2b  = (unsigned short*)alloc((size_t)NL_*D_*DFF_*2);
  unsigned short* hwt   = (unsigned short*)alloc((size_t)PRED_*KHEAD_*2);
  float* bias2 = (float*)alloc(PRED_*4);
  unsigned short* zfinal = (unsigned short*)alloc((size_t)M_*D_*2);
  char* E = cur;
  size_t E_avail = (ws_size > (size_t)(E - (char*)d_ws)) ? ws_size - (size_t)(E - (char*)d_ws) : 0;

  // chunk size: Cb in {672,224,96,32}; per-token scratch = 6144 B (bf16 master)
  static const int cands[4] = {672, 224, 96, 32};
  int Cb = 32;
  for (int i = 0; i < 4; i++){
    size_t need = (size_t)6144 * cands[i] * N_;
    if (need <= E_avail){ Cb = cands[i]; break; }
  }
  const int nchunk = BC_ / Cb;
  const int Tc = Cb * N_;
  unsigned short* zb_c = (unsigned short*)E;                           // [Tc][512] bf16
  unsigned short* r1   = (unsigned short*)(E + (size_t)1024*Tc);       // qkv [Tc][1536] / y1 [Tc][2048]
  unsigned short* abuf = (unsigned short*)(E + (size_t)4096*Tc);       // attn out [Tc][512]
  unsigned short* r2   = (unsigned short*)(E + (size_t)5120*Tc);       // delta [Tc][512] bf16
  // head-phase scratch (after encoder done)
  float* part = (float*)E;
  float* dec  = (float*)(E + (size_t)SK_*PM_*PN_*4);

  // ---- prologue ----
  k_instnorm<<<BC_, 256, 0, stream>>>(x_enc, xc, stats);
  k_router<<<(BC_*R_ + 255)/256, 256, 0, stream>>>(xc, cls_w1, cls_b1, cls_w2, cls_b2, pred);
  k_pe<<<(N_*D_ + 255)/256, 256, 0, stream>>>(pe);
  k_transe<<<192, 256, 0, stream>>>(ew0, ew1, ew2, ew3, ewt);
  int nqkvg = NL_*QKVN_*D_/4, nw4 = NL_*D_*D_/4, nff4 = NL_*DFF_*D_/4;
  k_cvtqkv<<<(nqkvg+255)/256, 256, 0, stream>>>(wq, wk, wv, wqkv_b);
  k_catbias<<<(NL_*QKVN_+255)/256, 256, 0, stream>>>(bq, bk, bv, bqkv);
  k_cvt<<<(nw4+255)/256, 256, 0, stream>>>(wo, wo_b, nw4);
  k_cvt<<<(nff4+255)/256, 256, 0, stream>>>(ff1_w, ff1b, nff4);
  k_cvt<<<(nff4+255)/256, 256, 0, stream>>>(ff2_w, ff2b, nff4);
  k_transw<<<dim3(8, PRED_), 256, 0, stream>>>(head_w, bn_g, hwt);
  k_bias2<<<PRED_, 256, 0, stream>>>(head_w, bn_b, head_b, bias2);

  // ---- encoder (chunked over bc; chunks fully independent) ----
  for (int ch = 0; ch < nchunk; ch++){
    int bc0 = ch*Cb;
    k_embed<<<Cb*R_, 256, 0, stream>>>(xc, pred, ewt, pe, zb_c, bc0);
    for (int l = 0; l < NL_; l++){
      k_mm<false,true><<<(QKVN_/128)*(Tc/128), 256, 0, stream>>>(
          zb_c, wqkv_b + (size_t)l*QKVN_*D_, bqkv + l*QKVN_, r1, Tc, QKVN_, D_);
      k_attn<<<Cb*H_, 384, 0, stream>>>(r1, abuf);
      k_mm<false,true><<<(D_/128)*(Tc/128), 256, 0, stream>>>(
          abuf, wo_b + (size_t)l*D_*D_, bo + l*D_, r2, Tc, D_, D_);
      k_addln<<<Tc/4, 256, 0, stream>>>(zb_c, r2, ln1_g+l*D_, ln1_b+l*D_, zb_c, Tc);
      size_t foff = (size_t)l*DFF_*D_;
      k_mm<true,true><<<(DFF_/128)*(Tc/128), 256, 0, stream>>>(
          zb_c, ff1b+foff, ff1_b+l*DFF_, r1, Tc, DFF_, D_);
      k_mm<false,true><<<(D_/128)*(Tc/128), 256, 0, stream>>>(
          r1, ff2b+foff, ff2_b+l*D_, r2, Tc, D_, DFF_);
      unsigned short* zb_out = (l == NL_-1) ? (zfinal + (size_t)bc0*N_*D_) : zb_c;
      k_addln<<<Tc/4, 256, 0, stream>>>(zb_c, r2, ln2_g+l*D_, ln2_b+l*D_, zb_out, Tc);
    }
  }

  // ---- head: dec = zfinal @ hwt^T (split-K) + bias2, then de-normalize ----
  k_mm_part<<<dim3(PN_/128, PM_/128, SK_), 256, 0, stream>>>(zfinal, hwt, part, KHEAD_/SK_);
  k_headred<<<(BC_*PRED_ + 255)/256, 256, 0, stream>>>(part, bias2, dec);
  k_out<<<(B_*PRED_*CVAR_ + 255)/256, 256, 0, stream>>>(dec, stats, out);
}

// Round 12
// 1662.547 us; speedup vs baseline: 1.1701x; 1.0643x over previous
//
#include <hip/hip_runtime.h>
#include <hip/hip_bf16.h>
#include <math.h>

#define B_    32
#define SEQ_  672
#define CVAR_ 21
#define PRED_ 336
#define D_    512
#define H_    8
#define DFF_  2048
#define NL_   2
#define R_    14
#define T_    6
#define N_    84
#define BC_   672           // B_*CVAR_
#define M_    (BC_*N_)      // 56448 tokens
#define KHEAD_ (D_*N_)      // 43008
#define SK_   16            // head split-K
#define PM_   768           // head M padded to 6*128
#define PN_   384           // head N padded to 3*128
#define QKVN_ 1536          // fused qkv width

typedef __attribute__((ext_vector_type(8))) short bh8;
typedef __attribute__((ext_vector_type(4))) float f32x4;

__device__ __forceinline__ unsigned short f2b(float x){
  union { float f; unsigned int u; } v; v.f = x;
  unsigned int r = v.u + 0x7FFFu + ((v.u >> 16) & 1u);   // RNE
  return (unsigned short)(r >> 16);
}
__device__ __forceinline__ float b2f(unsigned short h){
  union { unsigned int u; float f; } v; v.u = ((unsigned int)h) << 16;
  return v.f;
}
__device__ __forceinline__ float wred_add(float v){
  #pragma unroll
  for (int o = 32; o; o >>= 1) v += __shfl_xor(v, o, 64);
  return v;
}
// async global->LDS, 16B per lane; lds base must be wave-uniform
__device__ __forceinline__ void stage16(const unsigned short* g, unsigned short* l){
  __builtin_amdgcn_global_load_lds(
      (const __attribute__((address_space(1))) unsigned int*)(const void*)g,
      (__attribute__((address_space(3))) unsigned int*)(void*)l, 16, 0, 0);
}

// ---------------- instance norm over time ----------------
__global__ void k_instnorm(const float* __restrict__ x, float* __restrict__ xc,
                           float* __restrict__ stats){
  int bc = blockIdx.x; int b = bc / CVAR_, c = bc % CVAR_;
  const float* xp = x + (size_t)b*SEQ_*CVAR_ + c;
  int tid = threadIdx.x;
  float s = 0.f, sq = 0.f;
  for (int l = tid; l < SEQ_; l += 256){ float v = xp[(size_t)l*CVAR_]; s += v; sq += v*v; }
  __shared__ float rs[4], rq[4];
  s = wred_add(s); sq = wred_add(sq);
  int w = tid >> 6, lane = tid & 63;
  if (lane == 0){ rs[w] = s; rq[w] = sq; }
  __syncthreads();
  if (tid == 0){
    float S = rs[0]+rs[1]+rs[2]+rs[3], Q = rq[0]+rq[1]+rq[2]+rq[3];
    float mean = S * (1.f/SEQ_);
    float var  = Q * (1.f/SEQ_) - mean*mean;
    float stdev = sqrtf(var + 1e-5f);
    stats[bc] = mean; stats[BC_ + bc] = stdev;
    rs[0] = mean; rq[0] = stdev;
  }
  __syncthreads();
  float mean = rs[0], inv = 1.f / rq[0];
  for (int l = tid; l < SEQ_; l += 256)
    xc[(size_t)bc*SEQ_ + l] = (xp[(size_t)l*CVAR_] - mean) * inv;
}

// ---------------- region router ----------------
__global__ void k_router(const float* __restrict__ xc,
                         const float* __restrict__ w1, const float* __restrict__ b1,
                         const float* __restrict__ w2, const float* __restrict__ b2,
                         int* __restrict__ pred){
  int t = blockIdx.x*256 + threadIdx.x;
  if (t >= BC_*R_) return;
  int bc = t / R_, r = t % R_;
  const float* xr = xc + (size_t)bc*SEQ_ + r*48;
  float xs[48];
  #pragma unroll
  for (int i = 0; i < 48; i++) xs[i] = xr[i];
  float hdn[64];
  #pragma unroll 4
  for (int h = 0; h < 64; h++){
    float a = b1[h];
    const float* wr = w1 + h*48;
    #pragma unroll
    for (int i = 0; i < 48; i++) a = fmaf(xs[i], wr[i], a);
    hdn[h] = fmaxf(a, 0.f);
  }
  float best = -1e30f; int be = 0;
  for (int e = 0; e < 4; e++){
    float lg = b2[e];
    const float* wr = w2 + e*64;
    #pragma unroll 8
    for (int h = 0; h < 64; h++) lg = fmaf(hdn[h], wr[h], lg);
    if (lg > best){ best = lg; be = e; }   // first max wins (strict >)
  }
  pred[t] = be;
}

// ---------------- positional encoding ----------------
__global__ void k_pe(float* __restrict__ pe){
  int i = blockIdx.x*256 + threadIdx.x;
  if (i >= N_*D_) return;
  int n = i / D_, d = i % D_;
  int ii = d >> 1;
  float freq = expf((float)(2*ii) * (-9.210340371976184f / (float)D_)); // -ln(10000)/D
  float a = (float)n * freq;
  pe[i] = (d & 1) ? cosf(a) : sinf(a);
}

// ---------------- fp32 -> bf16 convert (n4 = elems/4) ----------------
__global__ void k_cvt(const float* __restrict__ in, unsigned short* __restrict__ out, int n4){
  int i = blockIdx.x*256 + threadIdx.x;
  if (i >= n4) return;
  float4 v = ((const float4*)in)[i];
  ((ushort4*)out)[i] = make_ushort4(f2b(v.x), f2b(v.y), f2b(v.z), f2b(v.w));
}

// ---------------- fused qkv weight convert (concat rows) ----------------
__global__ void k_cvtqkv(const float* __restrict__ wq, const float* __restrict__ wk,
                         const float* __restrict__ wv, unsigned short* __restrict__ o){
  int i = blockIdx.x*256 + threadIdx.x;          // one per 4 elems
  const int per_l = QKVN_*D_/4;                  // 196608
  const int per_s = D_*D_/4;                     // 65536
  if (i >= NL_*per_l) return;
  int l = i / per_l;
  int rem = i - l*per_l;
  int sec = rem / per_s;
  int off = rem - sec*per_s;
  const float* src = (sec==0 ? wq : sec==1 ? wk : wv) + (size_t)l*D_*D_ + (size_t)off*4;
  float4 v = *(const float4*)src;
  ((ushort4*)o)[i] = make_ushort4(f2b(v.x), f2b(v.y), f2b(v.z), f2b(v.w));
}

// ---------------- qkv bias concat ----------------
__global__ void k_catbias(const float* __restrict__ bq, const float* __restrict__ bk,
                          const float* __restrict__ bv, float* __restrict__ bqkv){
  int i = blockIdx.x*256 + threadIdx.x;
  if (i >= NL_*QKVN_) return;
  int l = i / QKVN_, r = i % QKVN_;
  float v = (r < 512) ? bq[l*512 + r] : (r < 1024) ? bk[l*512 + r - 512] : bv[l*512 + r - 1024];
  bqkv[i] = v;
}

// ------ expert weight transpose: W_e[d][q] -> wt[base_e + q*512 + d] ----------
__global__ void k_transe(const float* __restrict__ w0, const float* __restrict__ w1,
                         const float* __restrict__ w2, const float* __restrict__ w3,
                         float* __restrict__ wt){
  int i = blockIdx.x*256 + threadIdx.x;
  if (i >= 49152) return;
  int e, base, p;
  if (i < 4096){ e = 0; base = 0; p = 8; }
  else if (i < 12288){ e = 1; base = 4096; p = 16; }
  else if (i < 24576){ e = 2; base = 12288; p = 24; }
  else { e = 3; base = 24576; p = 48; }
  int local = i - base;
  int q = local >> 9, d = local & 511;
  const float* W = (e==0) ? w0 : (e==1) ? w1 : (e==2) ? w2 : w3;
  wt[base + q*512 + d] = W[(size_t)d*p + q];
}

// ---------------- patch embedding + PE (coalesced transposed weights) ---------
__global__ void k_embed(const float* __restrict__ xc, const int* __restrict__ pred,
                        const float* __restrict__ wt, const float* __restrict__ pe,
                        unsigned short* __restrict__ zb, int bc0){
  int blk = blockIdx.x; int bcl = blk / R_, r = blk % R_;
  int bc = bc0 + bcl;
  __shared__ float xr[48];
  int tid = threadIdx.x;
  if (tid < 48) xr[tid] = xc[(size_t)bc*SEQ_ + r*48 + tid];
  __syncthreads();
  int e = pred[bc*R_ + r];
  int p    = (e==0) ? 8 : (e==1) ? 16 : (e==2) ? 24 : 48;
  int base = (e==0) ? 0 : (e==1) ? 4096 : (e==2) ? 12288 : 24576;
  int num = 48 / p, rep = 7 - num;
  const float* Wt = wt + base;
  int d0 = tid, d1 = tid + 256;
  float acc0[6], acc1[6];
  #pragma unroll
  for (int u = 0; u < 6; u++){ acc0[u] = 0.f; acc1[u] = 0.f; }
  #pragma unroll
  for (int u = 0; u < 6; u++){
    if (u < num){
      float s0 = 0.f, s1 = 0.f;
      const float* xu = xr + u*p;
      for (int q = 0; q < p; q++){
        float xv = xu[q];
        const float* wrow = Wt + q*512;
        s0 = fmaf(xv, wrow[d0], s0);
        s1 = fmaf(xv, wrow[d1], s1);
      }
      acc0[u] = s0; acc1[u] = s1;
    }
  }
  #pragma unroll
  for (int u = 0; u < 6; u++){
    if (u < num){
      #pragma unroll
      for (int t = 0; t < 6; t++){
        int ut = t / rep; if (ut > num-1) ut = num-1;
        if (ut == u){
          int n = r*T_ + t;
          size_t off = ((size_t)bcl*N_ + n)*D_;
          zb[off + d0] = f2b(acc0[u] + pe[n*D_ + d0]);
          zb[off + d1] = f2b(acc1[u] + pe[n*D_ + d1]);
        }
      }
    }
  }
}

// ---------------- bf16 MFMA GEMM: C[M,N] = act(A[M,K] * B[N,K]^T + bias) ------
// 128x128 tile, BK=32, 512 thr (8 waves, 2 row-groups x 4 col-groups).
// Per wave: 64x32 output (acc[4][2] = 32 AGPRs) -> ~82 unified regs ->
// 6 waves/SIMD (24 waves/CU) vs 4 with the 4-wave/acc[4][4] layout.
// Double-buffered LDS with COUNTED vmcnt(2): next-tile loads stay in flight
// across the barrier. Second bare barrier = WAR protection.
// M % 128 == 0, N % 128 == 0, K % 32 == 0, K >= 64.
template<bool GELU, bool OBF16>
__global__ __launch_bounds__(512, 6) void k_mm(const unsigned short* __restrict__ A,
      const unsigned short* __restrict__ Bw, const float* __restrict__ bias,
      void* __restrict__ Cp, int M, int N, int K){
  __shared__ unsigned short As[2][128*32];
  __shared__ unsigned short Bs[2][128*32];
  int tid = threadIdx.x;
  int lane = tid & 63;
  int wave = tid >> 6;                     // 0..7
  int wr0 = (wave >> 2) * 64;              // 0 / 64
  int wc0 = (wave & 3) * 32;               // 0 / 32 / 64 / 96
  // bijective XCD swizzle (m204): contiguous wgid chunk per XCD
  int nx = N >> 7;
  int nwg = gridDim.x;
  int orig = blockIdx.x;
  int q = nwg >> 3, r8 = nwg & 7;
  int xcd = orig & 7, idx = orig >> 3;
  int wgid = (xcd < r8 ? xcd*(q+1) : r8*(q+1) + (xcd - r8)*q) + idx;
  int m0 = (wgid / nx) << 7;
  int n0 = (wgid % nx) << 7;
  // staging geometry: 512 16B-chunks each for A and B; wave w stages chunk
  // group w of A and group w of B (64 chunks each, lane-contiguous).
  int ec = wave*64 + lane;                 // chunk id 0..511
  int rowc = ec >> 2, kcc = (ec & 3) << 3;
  const unsigned short* ap = A  + (size_t)(m0+rowc)*K + kcc;
  const unsigned short* bp = Bw + (size_t)(n0+rowc)*K + kcc;
  unsigned short* lda0 = &As[0][wave*512]; // wave-uniform LDS bases
  unsigned short* lda1 = &As[1][wave*512];
  unsigned short* ldb0 = &Bs[0][wave*512];
  unsigned short* ldb1 = &Bs[1][wave*512];
  f32x4 acc[4][2];
  #pragma unroll
  for (int m = 0; m < 4; m++)
    #pragma unroll
    for (int n = 0; n < 2; n++) acc[m][n] = (f32x4){0.f,0.f,0.f,0.f};

  stage16(ap, lda0);
  stage16(bp, ldb0);
  int cur = 0;
  for (int k0 = 0; k0 < K - 32; k0 += 32){
    int ko = k0 + 32;
    stage16(ap + ko, cur ? lda0 : lda1);
    stage16(bp + ko, cur ? ldb0 : ldb1);
    // wait own buf[cur] loads (<=2 newest outstanding = next tile), then sync
    asm volatile("s_waitcnt vmcnt(2)" ::: "memory");
    __builtin_amdgcn_s_barrier();
    __builtin_amdgcn_sched_barrier(0);
    bh8 fa[4], fb[2];
    #pragma unroll
    for (int m = 0; m < 4; m++)
      fa[m] = *(const bh8*)&As[cur][(wr0 + m*16 + (lane & 15))*32 + (lane >> 4)*8];
    #pragma unroll
    for (int n = 0; n < 2; n++)
      fb[n] = *(const bh8*)&Bs[cur][(wc0 + n*16 + (lane & 15))*32 + (lane >> 4)*8];
    #pragma unroll
    for (int m = 0; m < 4; m++)
      #pragma unroll
      for (int n = 0; n < 2; n++)
        acc[m][n] = __builtin_amdgcn_mfma_f32_16x16x32_bf16(fa[m], fb[n], acc[m][n], 0, 0, 0);
    __builtin_amdgcn_sched_barrier(0);
    __builtin_amdgcn_s_barrier();          // WAR: all reads of buf[cur] done
    cur ^= 1;
  }
  asm volatile("s_waitcnt vmcnt(0)" ::: "memory");
  __builtin_amdgcn_s_barrier();
  __builtin_amdgcn_sched_barrier(0);
  {
    bh8 fa[4], fb[2];
    #pragma unroll
    for (int m = 0; m < 4; m++)
      fa[m] = *(const bh8*)&As[cur][(wr0 + m*16 + (lane & 15))*32 + (lane >> 4)*8];
    #pragma unroll
    for (int n = 0; n < 2; n++)
      fb[n] = *(const bh8*)&Bs[cur][(wc0 + n*16 + (lane & 15))*32 + (lane >> 4)*8];
    #pragma unroll
    for (int m = 0; m < 4; m++)
      #pragma unroll
      for (int n = 0; n < 2; n++)
        acc[m][n] = __builtin_amdgcn_mfma_f32_16x16x32_bf16(fa[m], fb[n], acc[m][n], 0, 0, 0);
  }
  int rbase = m0 + wr0 + (lane >> 4)*4;
  int cbase = n0 + wc0 + (lane & 15);
  #pragma unroll
  for (int n = 0; n < 2; n++){
    int col = cbase + n*16;
    float bs = bias[col];
    #pragma unroll
    for (int m = 0; m < 4; m++){
      int row = rbase + m*16;
      #pragma unroll
      for (int j = 0; j < 4; j++){
        float cv = acc[m][n][j] + bs;
        if (GELU) cv = 0.5f*cv*(1.f + erff(cv*0.70710678118654752f));
        if (OBF16) ((unsigned short*)Cp)[(size_t)(row+j)*N + col] = f2b(cv);
        else       ((float*)Cp)[(size_t)(row+j)*N + col] = cv;
      }
    }
  }
}

// ---------------- head GEMM, split-K partials (rows/cols clamped) -------------
__global__ __launch_bounds__(256) void k_mm_part(const unsigned short* __restrict__ A,
      const unsigned short* __restrict__ Bw, float* __restrict__ part, int kchunk){
  __shared__ unsigned short As[2][128*32];
  __shared__ unsigned short Bs[2][128*32];
  int tid = threadIdx.x;
  int lane = tid & 63, wave = tid >> 6;
  int wr = wave >> 1, wc = wave & 1;
  int m0 = blockIdx.y*128, n0 = blockIdx.x*128;
  int kb0 = blockIdx.z*kchunk;
  int eb0 = (tid & 192);
  int e0 = eb0 + lane, e1 = eb0 + 256 + lane;
  int row0 = e0 >> 2, kc0 = (e0 & 3) << 3;
  int row1 = e1 >> 2, kc1 = (e1 & 3) << 3;
  int ar0 = m0 + row0; if (ar0 >= BC_)  ar0 = BC_ - 1;
  int ar1 = m0 + row1; if (ar1 >= BC_)  ar1 = BC_ - 1;
  int br0 = n0 + row0; if (br0 >= PRED_) br0 = PRED_ - 1;
  int br1 = n0 + row1; if (br1 >= PRED_) br1 = PRED_ - 1;
  const unsigned short* a0 = A  + (size_t)ar0*KHEAD_ + kb0 + kc0;
  const unsigned short* a1 = A  + (size_t)ar1*KHEAD_ + kb0 + kc1;
  const unsigned short* b0 = Bw + (size_t)br0*KHEAD_ + kb0 + kc0;
  const unsigned short* b1 = Bw + (size_t)br1*KHEAD_ + kb0 + kc1;
  f32x4 acc[4][4];
  #pragma unroll
  for (int m = 0; m < 4; m++)
    #pragma unroll
    for (int n = 0; n < 4; n++) acc[m][n] = (f32x4){0.f,0.f,0.f,0.f};

  stage16(a0, &As[0][eb0*8]);
  stage16(a1, &As[0][(eb0+256)*8]);
  stage16(b0, &Bs[0][eb0*8]);
  stage16(b1, &Bs[0][(eb0+256)*8]);
  int cur = 0;
  for (int ko = 0; ko < kchunk - 32; ko += 32){
    int nb = cur ^ 1, kk = ko + 32;
    stage16(a0 + kk, &As[nb][eb0*8]);
    stage16(a1 + kk, &As[nb][(eb0+256)*8]);
    stage16(b0 + kk, &Bs[nb][eb0*8]);
    stage16(b1 + kk, &Bs[nb][(eb0+256)*8]);
    asm volatile("s_waitcnt vmcnt(4)" ::: "memory");
    __builtin_amdgcn_s_barrier();
    __builtin_amdgcn_sched_barrier(0);
    bh8 fa[4], fb[4];
    #pragma unroll
    for (int m = 0; m < 4; m++)
      fa[m] = *(const bh8*)&As[cur][(wr*64 + m*16 + (lane & 15))*32 + (lane >> 4)*8];
    #pragma unroll
    for (int n = 0; n < 4; n++)
      fb[n] = *(const bh8*)&Bs[cur][(wc*64 + n*16 + (lane & 15))*32 + (lane >> 4)*8];
    #pragma unroll
    for (int m = 0; m < 4; m++)
      #pragma unroll
      for (int n = 0; n < 4; n++)
        acc[m][n] = __builtin_amdgcn_mfma_f32_16x16x32_bf16(fa[m], fb[n], acc[m][n], 0, 0, 0);
    __builtin_amdgcn_sched_barrier(0);
    __builtin_amdgcn_s_barrier();
    cur ^= 1;
  }
  asm volatile("s_waitcnt vmcnt(0)" ::: "memory");
  __builtin_amdgcn_s_barrier();
  __builtin_amdgcn_sched_barrier(0);
  {
    bh8 fa[4], fb[4];
    #pragma unroll
    for (int m = 0; m < 4; m++)
      fa[m] = *(const bh8*)&As[cur][(wr*64 + m*16 + (lane & 15))*32 + (lane >> 4)*8];
    #pragma unroll
    for (int n = 0; n < 4; n++)
      fb[n] = *(const bh8*)&Bs[cur][(wc*64 + n*16 + (lane & 15))*32 + (lane >> 4)*8];
    #pragma unroll
    for (int m = 0; m < 4; m++)
      #pragma unroll
      for (int n = 0; n < 4; n++)
        acc[m][n] = __builtin_amdgcn_mfma_f32_16x16x32_bf16(fa[m], fb[n], acc[m][n], 0, 0, 0);
  }
  float* po = part + (size_t)blockIdx.z*PM_*PN_;
  int rbase = m0 + wr*64 + (lane >> 4)*4;
  int cbase = n0 + wc*64 + (lane & 15);
  #pragma unroll
  for (int n = 0; n < 4; n++){
    int col = cbase + n*16;
    #pragma unroll
    for (int m = 0; m < 4; m++){
      int row = rbase + m*16;
      #pragma unroll
      for (int j = 0; j < 4; j++)
        po[(size_t)(row+j)*PN_ + col] = acc[m][n][j];
    }
  }
}

// ---------------- head reduce + bias ----------------
__global__ void k_headred(const float* __restrict__ part, const float* __restrict__ bias2,
                          float* __restrict__ dec){
  int i = blockIdx.x*256 + threadIdx.x;
  if (i >= BC_*PRED_) return;
  int bc = i / PRED_, pr = i % PRED_;
  float s = bias2[pr];
  #pragma unroll
  for (int sk = 0; sk < SK_; sk++)
    s += part[(size_t)sk*PM_*PN_ + (size_t)bc*PN_ + pr];
  dec[i] = s;
}

// -------- MFMA fused attention: block = (bc-local, head), 6 waves -------------
__global__ __launch_bounds__(384) void k_attn(const unsigned short* __restrict__ qkv,
                                              unsigned short* __restrict__ o){
  __shared__ unsigned short Qb[96][72];       // stride 144B: 2-way alias (free)
  __shared__ unsigned short Kb[96][72];
  __shared__ unsigned short Vt[64][104];      // V transposed; stride 208B
  __shared__ unsigned short Pb[6][16][104];
  int bh = blockIdx.x; int bcl = bh >> 3, h = bh & 7;
  int tid = threadIdx.x, lane = tid & 63, wv = tid >> 6;   // wv = row-tile 0..5
  size_t qb = (size_t)bcl*N_*QKVN_ + h*64;
  for (int g = tid; g < 1536; g += 384){
    int n = g >> 4, d4 = (g & 15) << 2;
    ushort4 qv = make_ushort4(0,0,0,0), kv = make_ushort4(0,0,0,0);
    if (n < N_){
      qv = *(const ushort4*)(qkv + qb + (size_t)n*QKVN_ + d4);
      kv = *(const ushort4*)(qkv + qb + 512 + (size_t)n*QKVN_ + d4);
    }
    *(ushort4*)&Qb[n][d4] = qv;
    *(ushort4*)&Kb[n][d4] = kv;
  }
  for (int g = tid; g < N_*16; g += 384){
    int n = g >> 4, d4 = (g & 15) << 2;
    ushort4 vv = *(const ushort4*)(qkv + qb + 1024 + (size_t)n*QKVN_ + d4);
    Vt[d4+0][n] = vv.x; Vt[d4+1][n] = vv.y; Vt[d4+2][n] = vv.z; Vt[d4+3][n] = vv.w;
  }
  for (int g = tid; g < 64*12; g += 384) Vt[g/12][N_ + g%12] = 0;
  __syncthreads();
  f32x4 acc[6];
  #pragma unroll
  for (int t = 0; t < 6; t++) acc[t] = (f32x4){0.f,0.f,0.f,0.f};
  #pragma unroll
  for (int ks = 0; ks < 2; ks++){
    bh8 qa = *(const bh8*)&Qb[wv*16 + (lane & 15)][ks*32 + (lane >> 4)*8];
    #pragma unroll
    for (int t = 0; t < 6; t++){
      bh8 kf = *(const bh8*)&Kb[t*16 + (lane & 15)][ks*32 + (lane >> 4)*8];
      acc[t] = __builtin_amdgcn_mfma_f32_16x16x32_bf16(qa, kf, acc[t], 0, 0, 0);
    }
  }
  bool v5 = (lane & 15) < 4;
  #pragma unroll
  for (int j = 0; j < 4; j++){
    float m = -1e30f;
    #pragma unroll
    for (int t = 0; t < 6; t++){
      float s = acc[t][j] * 0.125f;
      if (t == 5 && !v5) s = -1e30f;
      acc[t][j] = s;
      m = fmaxf(m, s);
    }
    #pragma unroll
    for (int off = 1; off < 16; off <<= 1) m = fmaxf(m, __shfl_xor(m, off, 64));
    float sum = 0.f;
    #pragma unroll
    for (int t = 0; t < 6; t++){
      float p = __expf(acc[t][j] - m);
      acc[t][j] = p;
      sum += p;
    }
    #pragma unroll
    for (int off = 1; off < 16; off <<= 1) sum += __shfl_xor(sum, off, 64);
    float inv = 1.f / sum;
    int lr = (lane >> 4)*4 + j;
    #pragma unroll
    for (int t = 0; t < 6; t++)
      Pb[wv][lr][t*16 + (lane & 15)] = f2b(acc[t][j] * inv);
  }
  f32x4 accO[4];
  #pragma unroll
  for (int dt = 0; dt < 4; dt++) accO[dt] = (f32x4){0.f,0.f,0.f,0.f};
  #pragma unroll
  for (int ks = 0; ks < 3; ks++){
    bh8 pa = *(const bh8*)&Pb[wv][lane & 15][ks*32 + (lane >> 4)*8];
    #pragma unroll
    for (int dt = 0; dt < 4; dt++){
      bh8 vf = *(const bh8*)&Vt[dt*16 + (lane & 15)][ks*32 + (lane >> 4)*8];
      accO[dt] = __builtin_amdgcn_mfma_f32_16x16x32_bf16(pa, vf, accO[dt], 0, 0, 0);
    }
  }
  size_t ob = (size_t)bcl*N_*D_ + h*64;
  #pragma unroll
  for (int dt = 0; dt < 4; dt++)
    #pragma unroll
    for (int j = 0; j < 4; j++){
      int r = wv*16 + (lane >> 4)*4 + j;
      if (r < N_) o[ob + (size_t)r*D_ + dt*16 + (lane & 15)] = f2b(accO[dt][j]);
    }
}

// ---------- fused residual-add + LayerNorm, bf16 residual master --------------
__global__ __launch_bounds__(256) void k_addln(const unsigned short* zin,
                        const unsigned short* __restrict__ delta,
                        const float* __restrict__ g, const float* __restrict__ b,
                        unsigned short* zout, int ntok){
  int w = threadIdx.x >> 6, lane = threadIdx.x & 63;
  int tok = blockIdx.x*4 + w;
  if (tok >= ntok) return;
  const ushort4* zp = (const ushort4*)(zin + (size_t)tok*D_);
  const ushort4* dp = (const ushort4*)(delta + (size_t)tok*D_);
  ushort4 z0 = zp[lane], z1 = zp[64+lane];
  ushort4 u0 = dp[lane], u1 = dp[64+lane];
  float4 a0, a1;
  a0.x = b2f(z0.x) + b2f(u0.x); a0.y = b2f(z0.y) + b2f(u0.y);
  a0.z = b2f(z0.z) + b2f(u0.z); a0.w = b2f(z0.w) + b2f(u0.w);
  a1.x = b2f(z1.x) + b2f(u1.x); a1.y = b2f(z1.y) + b2f(u1.y);
  a1.z = b2f(z1.z) + b2f(u1.z); a1.w = b2f(z1.w) + b2f(u1.w);
  float s  = a0.x+a0.y+a0.z+a0.w + a1.x+a1.y+a1.z+a1.w;
  float sq = a0.x*a0.x+a0.y*a0.y+a0.z*a0.z+a0.w*a0.w
           + a1.x*a1.x+a1.y*a1.y+a1.z*a1.z+a1.w*a1.w;
  s = wred_add(s); sq = wred_add(sq);
  float mean = s * (1.f/D_);
  float var  = sq * (1.f/D_) - mean*mean;
  float rstd = rsqrtf(var + 1e-5f);
  const float4* g4 = (const float4*)g; const float4* b4 = (const float4*)b;
  float4 G0 = g4[lane], G1 = g4[64+lane], B0 = b4[lane], B1 = b4[64+lane];
  unsigned short* zo = zout + (size_t)tok*D_;
  *(ushort4*)(zo + 4*lane) = make_ushort4(
      f2b((a0.x-mean)*rstd*G0.x + B0.x), f2b((a0.y-mean)*rstd*G0.y + B0.y),
      f2b((a0.z-mean)*rstd*G0.z + B0.z), f2b((a0.w-mean)*rstd*G0.w + B0.w));
  *(ushort4*)(zo + 256 + 4*lane) = make_ushort4(
      f2b((a1.x-mean)*rstd*G1.x + B1.x), f2b((a1.y-mean)*rstd*G1.y + B1.y),
      f2b((a1.z-mean)*rstd*G1.z + B1.z), f2b((a1.w-mean)*rstd*G1.w + B1.w));
}

// ------ head_w transpose -> bf16 with BN-gamma fold: hwt[pr][n*512+d] ---------
__global__ void k_transw(const float* __restrict__ hw, const float* __restrict__ bng,
                         unsigned short* __restrict__ hwt){
  int dc = blockIdx.x, pr = blockIdx.y;
  int d0 = dc*64;
  __shared__ float tl[64*N_];
  const float* src = hw + (size_t)pr*KHEAD_ + (size_t)d0*N_;
  for (int i = threadIdx.x; i < 64*N_; i += 256) tl[i] = src[i];
  __syncthreads();
  const float sc = 0.9999950000374997f;   // 1/sqrt(1+1e-5)
  unsigned short* dst = hwt + (size_t)pr*KHEAD_;
  for (int i = threadIdx.x; i < 64*N_; i += 256){
    int n = i >> 6, dd = i & 63;
    dst[(size_t)n*D_ + d0 + dd] = f2b(tl[dd*N_ + n] * sc * bng[d0+dd]);
  }
}

// ------ bias2[pr] = head_b[pr] + sum_{d,n} bn_b[d]*head_w[pr][d*84+n] ---------
__global__ void k_bias2(const float* __restrict__ hw, const float* __restrict__ bnb,
                        const float* __restrict__ hb, float* __restrict__ bias2){
  int pr = blockIdx.x, tid = threadIdx.x;
  const float* src = hw + (size_t)pr*KHEAD_;
  float s = 0.f;
  for (int i = tid; i < KHEAD_; i += 256) s += src[i] * bnb[i / N_];
  __shared__ float rs[4];
  s = wred_add(s);
  int w = tid >> 6;
  if ((tid & 63) == 0) rs[w] = s;
  __syncthreads();
  if (tid == 0) bias2[pr] = hb[pr] + rs[0] + rs[1] + rs[2] + rs[3];
}

// ---------------- de-normalize + final transpose ----------------
__global__ void k_out(const float* __restrict__ dec, const float* __restrict__ stats,
                      float* __restrict__ out){
  int i = blockIdx.x*256 + threadIdx.x;
  if (i >= B_*PRED_*CVAR_) return;
  int c = i % CVAR_; int t = (i / CVAR_) % PRED_; int b = i / (CVAR_*PRED_);
  int bc = b*CVAR_ + c;
  out[i] = dec[(size_t)bc*PRED_ + t] * stats[BC_ + bc] + stats[bc];
}

extern "C" void kernel_launch(void* const* d_in, const int* in_sizes, int n_in,
                              void* d_out, int out_size, void* d_ws, size_t ws_size,
                              hipStream_t stream){
  const float* x_enc  = (const float*)d_in[0];
  const float* cls_w1 = (const float*)d_in[4];
  const float* cls_b1 = (const float*)d_in[5];
  const float* cls_w2 = (const float*)d_in[6];
  const float* cls_b2 = (const float*)d_in[7];
  const float* ew0 = (const float*)d_in[8];
  const float* ew1 = (const float*)d_in[9];
  const float* ew2 = (const float*)d_in[10];
  const float* ew3 = (const float*)d_in[11];
  const float* wq = (const float*)d_in[12]; const float* bq = (const float*)d_in[13];
  const float* wk = (const float*)d_in[14]; const float* bk = (const float*)d_in[15];
  const float* wv = (const float*)d_in[16]; const float* bv = (const float*)d_in[17];
  const float* wo = (const float*)d_in[18]; const float* bo = (const float*)d_in[19];
  const float* ln1_g = (const float*)d_in[20]; const float* ln1_b = (const float*)d_in[21];
  const float* ln2_g = (const float*)d_in[22]; const float* ln2_b = (const float*)d_in[23];
  const float* ff1_w = (const float*)d_in[24]; const float* ff1_b = (const float*)d_in[25];
  const float* ff2_w = (const float*)d_in[26]; const float* ff2_b = (const float*)d_in[27];
  const float* bn_g = (const float*)d_in[28]; const float* bn_b = (const float*)d_in[29];
  const float* head_w = (const float*)d_in[30]; const float* head_b = (const float*)d_in[31];
  float* out = (float*)d_out;

  // ---- workspace layout (256B-aligned regions) ----
  char* cur = (char*)d_ws;
  auto alloc = [&](size_t bytes)->char*{
    char* p = cur; cur += (bytes + 255) & ~(size_t)255; return p;
  };
  float* xc    = (float*)alloc(451584*4);
  float* stats = (float*)alloc(1344*4);
  int*   pred  = (int*)  alloc(9408*4);
  float* pe    = (float*)alloc(43008*4);
  float* ewt   = (float*)alloc(49152*4);
  unsigned short* wqkv_b = (unsigned short*)alloc((size_t)NL_*QKVN_*D_*2);
  float* bqkv  = (float*)alloc((size_t)NL_*QKVN_*4);
  unsigned short* wo_b  = (unsigned short*)alloc((size_t)NL_*D_*D_*2);
  unsigned short* ff1b  = (unsigned short*)alloc((size_t)NL_*DFF_*D_*2);
  unsigned short* ff2b  = (unsigned short*)alloc((size_t)NL_*D_*DFF_*2);
  unsigned short* hwt   = (unsigned short*)alloc((size_t)PRED_*KHEAD_*2);
  float* bias2 = (float*)alloc(PRED_*4);
  unsigned short* zfinal = (unsigned short*)alloc((size_t)M_*D_*2);
  char* E = cur;
  size_t E_avail = (ws_size > (size_t)(E - (char*)d_ws)) ? ws_size - (size_t)(E - (char*)d_ws) : 0;

  // chunk size: Cb in {672,224,96,32}; per-token scratch = 6144 B (bf16 master)
  static const int cands[4] = {672, 224, 96, 32};
  int Cb = 32;
  for (int i = 0; i < 4; i++){
    size_t need = (size_t)6144 * cands[i] * N_;
    if (need <= E_avail){ Cb = cands[i]; break; }
  }
  const int nchunk = BC_ / Cb;
  const int Tc = Cb * N_;
  unsigned short* zb_c = (unsigned short*)E;                           // [Tc][512] bf16
  unsigned short* r1   = (unsigned short*)(E + (size_t)1024*Tc);       // qkv [Tc][1536] / y1 [Tc][2048]
  unsigned short* abuf = (unsigned short*)(E + (size_t)4096*Tc);       // attn out [Tc][512]
  unsigned short* r2   = (unsigned short*)(E + (size_t)5120*Tc);       // delta [Tc][512] bf16
  // head-phase scratch (after encoder done)
  float* part = (float*)E;
  float* dec  = (float*)(E + (size_t)SK_*PM_*PN_*4);

  // ---- prologue ----
  k_instnorm<<<BC_, 256, 0, stream>>>(x_enc, xc, stats);
  k_router<<<(BC_*R_ + 255)/256, 256, 0, stream>>>(xc, cls_w1, cls_b1, cls_w2, cls_b2, pred);
  k_pe<<<(N_*D_ + 255)/256, 256, 0, stream>>>(pe);
  k_transe<<<192, 256, 0, stream>>>(ew0, ew1, ew2, ew3, ewt);
  int nqkvg = NL_*QKVN_*D_/4, nw4 = NL_*D_*D_/4, nff4 = NL_*DFF_*D_/4;
  k_cvtqkv<<<(nqkvg+255)/256, 256, 0, stream>>>(wq, wk, wv, wqkv_b);
  k_catbias<<<(NL_*QKVN_+255)/256, 256, 0, stream>>>(bq, bk, bv, bqkv);
  k_cvt<<<(nw4+255)/256, 256, 0, stream>>>(wo, wo_b, nw4);
  k_cvt<<<(nff4+255)/256, 256, 0, stream>>>(ff1_w, ff1b, nff4);
  k_cvt<<<(nff4+255)/256, 256, 0, stream>>>(ff2_w, ff2b, nff4);
  k_transw<<<dim3(8, PRED_), 256, 0, stream>>>(head_w, bn_g, hwt);
  k_bias2<<<PRED_, 256, 0, stream>>>(head_w, bn_b, head_b, bias2);

  // ---- encoder (chunked over bc; chunks fully independent) ----
  for (int ch = 0; ch < nchunk; ch++){
    int bc0 = ch*Cb;
    k_embed<<<Cb*R_, 256, 0, stream>>>(xc, pred, ewt, pe, zb_c, bc0);
    for (int l = 0; l < NL_; l++){
      k_mm<false,true><<<(QKVN_/128)*(Tc/128), 512, 0, stream>>>(
          zb_c, wqkv_b + (size_t)l*QKVN_*D_, bqkv + l*QKVN_, r1, Tc, QKVN_, D_);
      k_attn<<<Cb*H_, 384, 0, stream>>>(r1, abuf);
      k_mm<false,true><<<(D_/128)*(Tc/128), 512, 0, stream>>>(
          abuf, wo_b + (size_t)l*D_*D_, bo + l*D_, r2, Tc, D_, D_);
      k_addln<<<Tc/4, 256, 0, stream>>>(zb_c, r2, ln1_g+l*D_, ln1_b+l*D_, zb_c, Tc);
      size_t foff = (size_t)l*DFF_*D_;
      k_mm<true,true><<<(DFF_/128)*(Tc/128), 512, 0, stream>>>(
          zb_c, ff1b+foff, ff1_b+l*DFF_, r1, Tc, DFF_, D_);
      k_mm<false,true><<<(D_/128)*(Tc/128), 512, 0, stream>>>(
          r1, ff2b+foff, ff2_b+l*D_, r2, Tc, D_, DFF_);
      unsigned short* zb_out = (l == NL_-1) ? (zfinal + (size_t)bc0*N_*D_) : zb_c;
      k_addln<<<Tc/4, 256, 0, stream>>>(zb_c, r2, ln2_g+l*D_, ln2_b+l*D_, zb_out, Tc);
    }
  }

  // ---- head: dec = zfinal @ hwt^T (split-K) + bias2, then de-normalize ----
  k_mm_part<<<dim3(PN_/128, PM_/128, SK_), 256, 0, stream>>>(zfinal, hwt, part, KHEAD_/SK_);
  k_headred<<<(BC_*PRED_ + 255)/256, 256, 0, stream>>>(part, bias2, dec);
  k_out<<<(B_*PRED_*CVAR_ + 255)/256, 256, 0, stream>>>(dec, stats, out);
}

// Round 13
// 1640.366 us; speedup vs baseline: 1.1860x; 1.0135x over previous
//
#include <hip/hip_runtime.h>
#include <hip/hip_bf16.h>
#include <math.h>

#define B_    32
#define SEQ_  672
#define CVAR_ 21
#define PRED_ 336
#define D_    512
#define H_    8
#define DFF_  2048
#define NL_   2
#define R_    14
#define T_    6
#define N_    84
#define BC_   672           // B_*CVAR_
#define M_    (BC_*N_)      // 56448 tokens
#define KHEAD_ (D_*N_)      // 43008
#define PM_   768           // head M padded to 6*128
#define PN_   384           // head N padded to 3*128
#define QKVN_ 1536          // fused qkv width

typedef __attribute__((ext_vector_type(8))) short bh8;
typedef __attribute__((ext_vector_type(4))) float f32x4;

__device__ __forceinline__ unsigned short f2b(float x){
  union { float f; unsigned int u; } v; v.f = x;
  unsigned int r = v.u + 0x7FFFu + ((v.u >> 16) & 1u);   // RNE
  return (unsigned short)(r >> 16);
}
__device__ __forceinline__ float b2f(unsigned short h){
  union { unsigned int u; float f; } v; v.u = ((unsigned int)h) << 16;
  return v.f;
}
__device__ __forceinline__ float wred_add(float v){
  #pragma unroll
  for (int o = 32; o; o >>= 1) v += __shfl_xor(v, o, 64);
  return v;
}
// async global->LDS, 16B per lane; lds base must be wave-uniform
__device__ __forceinline__ void stage16(const unsigned short* g, unsigned short* l){
  __builtin_amdgcn_global_load_lds(
      (const __attribute__((address_space(1))) unsigned int*)(const void*)g,
      (__attribute__((address_space(3))) unsigned int*)(void*)l, 16, 0, 0);
}

// ---------------- instance norm over time ----------------
__global__ void k_instnorm(const float* __restrict__ x, float* __restrict__ xc,
                           float* __restrict__ stats){
  int bc = blockIdx.x; int b = bc / CVAR_, c = bc % CVAR_;
  const float* xp = x + (size_t)b*SEQ_*CVAR_ + c;
  int tid = threadIdx.x;
  float s = 0.f, sq = 0.f;
  for (int l = tid; l < SEQ_; l += 256){ float v = xp[(size_t)l*CVAR_]; s += v; sq += v*v; }
  __shared__ float rs[4], rq[4];
  s = wred_add(s); sq = wred_add(sq);
  int w = tid >> 6, lane = tid & 63;
  if (lane == 0){ rs[w] = s; rq[w] = sq; }
  __syncthreads();
  if (tid == 0){
    float S = rs[0]+rs[1]+rs[2]+rs[3], Q = rq[0]+rq[1]+rq[2]+rq[3];
    float mean = S * (1.f/SEQ_);
    float var  = Q * (1.f/SEQ_) - mean*mean;
    float stdev = sqrtf(var + 1e-5f);
    stats[bc] = mean; stats[BC_ + bc] = stdev;
    rs[0] = mean; rq[0] = stdev;
  }
  __syncthreads();
  float mean = rs[0], inv = 1.f / rq[0];
  for (int l = tid; l < SEQ_; l += 256)
    xc[(size_t)bc*SEQ_ + l] = (xp[(size_t)l*CVAR_] - mean) * inv;
}

// ---------------- region router ----------------
__global__ void k_router(const float* __restrict__ xc,
                         const float* __restrict__ w1, const float* __restrict__ b1,
                         const float* __restrict__ w2, const float* __restrict__ b2,
                         int* __restrict__ pred){
  int t = blockIdx.x*256 + threadIdx.x;
  if (t >= BC_*R_) return;
  int bc = t / R_, r = t % R_;
  const float* xr = xc + (size_t)bc*SEQ_ + r*48;
  float xs[48];
  #pragma unroll
  for (int i = 0; i < 48; i++) xs[i] = xr[i];
  float hdn[64];
  #pragma unroll 4
  for (int h = 0; h < 64; h++){
    float a = b1[h];
    const float* wr = w1 + h*48;
    #pragma unroll
    for (int i = 0; i < 48; i++) a = fmaf(xs[i], wr[i], a);
    hdn[h] = fmaxf(a, 0.f);
  }
  float best = -1e30f; int be = 0;
  for (int e = 0; e < 4; e++){
    float lg = b2[e];
    const float* wr = w2 + e*64;
    #pragma unroll 8
    for (int h = 0; h < 64; h++) lg = fmaf(hdn[h], wr[h], lg);
    if (lg > best){ best = lg; be = e; }   // first max wins (strict >)
  }
  pred[t] = be;
}

// ---------------- positional encoding ----------------
__global__ void k_pe(float* __restrict__ pe){
  int i = blockIdx.x*256 + threadIdx.x;
  if (i >= N_*D_) return;
  int n = i / D_, d = i % D_;
  int ii = d >> 1;
  float freq = expf((float)(2*ii) * (-9.210340371976184f / (float)D_)); // -ln(10000)/D
  float a = (float)n * freq;
  pe[i] = (d & 1) ? cosf(a) : sinf(a);
}

// ---------------- fp32 -> bf16 convert (n4 = elems/4) ----------------
__global__ void k_cvt(const float* __restrict__ in, unsigned short* __restrict__ out, int n4){
  int i = blockIdx.x*256 + threadIdx.x;
  if (i >= n4) return;
  float4 v = ((const float4*)in)[i];
  ((ushort4*)out)[i] = make_ushort4(f2b(v.x), f2b(v.y), f2b(v.z), f2b(v.w));
}

// ---------------- fused qkv weight convert (concat rows) ----------------
__global__ void k_cvtqkv(const float* __restrict__ wq, const float* __restrict__ wk,
                         const float* __restrict__ wv, unsigned short* __restrict__ o){
  int i = blockIdx.x*256 + threadIdx.x;          // one per 4 elems
  const int per_l = QKVN_*D_/4;                  // 196608
  const int per_s = D_*D_/4;                     // 65536
  if (i >= NL_*per_l) return;
  int l = i / per_l;
  int rem = i - l*per_l;
  int sec = rem / per_s;
  int off = rem - sec*per_s;
  const float* src = (sec==0 ? wq : sec==1 ? wk : wv) + (size_t)l*D_*D_ + (size_t)off*4;
  float4 v = *(const float4*)src;
  ((ushort4*)o)[i] = make_ushort4(f2b(v.x), f2b(v.y), f2b(v.z), f2b(v.w));
}

// ---------------- qkv bias concat ----------------
__global__ void k_catbias(const float* __restrict__ bq, const float* __restrict__ bk,
                          const float* __restrict__ bv, float* __restrict__ bqkv){
  int i = blockIdx.x*256 + threadIdx.x;
  if (i >= NL_*QKVN_) return;
  int l = i / QKVN_, r = i % QKVN_;
  float v = (r < 512) ? bq[l*512 + r] : (r < 1024) ? bk[l*512 + r - 512] : bv[l*512 + r - 1024];
  bqkv[i] = v;
}

// ------ expert weight transpose: W_e[d][q] -> wt[base_e + q*512 + d] ----------
__global__ void k_transe(const float* __restrict__ w0, const float* __restrict__ w1,
                         const float* __restrict__ w2, const float* __restrict__ w3,
                         float* __restrict__ wt){
  int i = blockIdx.x*256 + threadIdx.x;
  if (i >= 49152) return;
  int e, base, p;
  if (i < 4096){ e = 0; base = 0; p = 8; }
  else if (i < 12288){ e = 1; base = 4096; p = 16; }
  else if (i < 24576){ e = 2; base = 12288; p = 24; }
  else { e = 3; base = 24576; p = 48; }
  int local = i - base;
  int q = local >> 9, d = local & 511;
  const float* W = (e==0) ? w0 : (e==1) ? w1 : (e==2) ? w2 : w3;
  wt[base + q*512 + d] = W[(size_t)d*p + q];
}

// ---------------- patch embedding + PE (coalesced transposed weights) ---------
__global__ void k_embed(const float* __restrict__ xc, const int* __restrict__ pred,
                        const float* __restrict__ wt, const float* __restrict__ pe,
                        unsigned short* __restrict__ zb, int bc0){
  int blk = blockIdx.x; int bcl = blk / R_, r = blk % R_;
  int bc = bc0 + bcl;
  __shared__ float xr[48];
  int tid = threadIdx.x;
  if (tid < 48) xr[tid] = xc[(size_t)bc*SEQ_ + r*48 + tid];
  __syncthreads();
  int e = pred[bc*R_ + r];
  int p    = (e==0) ? 8 : (e==1) ? 16 : (e==2) ? 24 : 48;
  int base = (e==0) ? 0 : (e==1) ? 4096 : (e==2) ? 12288 : 24576;
  int num = 48 / p, rep = 7 - num;
  const float* Wt = wt + base;
  int d0 = tid, d1 = tid + 256;
  float acc0[6], acc1[6];
  #pragma unroll
  for (int u = 0; u < 6; u++){ acc0[u] = 0.f; acc1[u] = 0.f; }
  #pragma unroll
  for (int u = 0; u < 6; u++){
    if (u < num){
      float s0 = 0.f, s1 = 0.f;
      const float* xu = xr + u*p;
      for (int q = 0; q < p; q++){
        float xv = xu[q];
        const float* wrow = Wt + q*512;
        s0 = fmaf(xv, wrow[d0], s0);
        s1 = fmaf(xv, wrow[d1], s1);
      }
      acc0[u] = s0; acc1[u] = s1;
    }
  }
  #pragma unroll
  for (int u = 0; u < 6; u++){
    if (u < num){
      #pragma unroll
      for (int t = 0; t < 6; t++){
        int ut = t / rep; if (ut > num-1) ut = num-1;
        if (ut == u){
          int n = r*T_ + t;
          size_t off = ((size_t)bcl*N_ + n)*D_;
          zb[off + d0] = f2b(acc0[u] + pe[n*D_ + d0]);
          zb[off + d1] = f2b(acc1[u] + pe[n*D_ + d1]);
        }
      }
    }
  }
}

// ---------------- bf16 MFMA GEMM: C[M,N] = act(A[M,K] * B[N,K]^T + bias) ------
// 128x128 tile, BK=32, 512 thr (8 waves, 2 row-groups x 4 col-groups).
// Per wave: 64x32 output (acc[4][2] = 32 AGPRs) -> ~82 unified regs ->
// 6 waves/SIMD. Double-buffered LDS with COUNTED vmcnt(2).
template<bool GELU, bool OBF16>
__global__ __launch_bounds__(512, 6) void k_mm(const unsigned short* __restrict__ A,
      const unsigned short* __restrict__ Bw, const float* __restrict__ bias,
      void* __restrict__ Cp, int M, int N, int K){
  __shared__ unsigned short As[2][128*32];
  __shared__ unsigned short Bs[2][128*32];
  int tid = threadIdx.x;
  int lane = tid & 63;
  int wave = tid >> 6;                     // 0..7
  int wr0 = (wave >> 2) * 64;              // 0 / 64
  int wc0 = (wave & 3) * 32;               // 0 / 32 / 64 / 96
  // bijective XCD swizzle (m204): contiguous wgid chunk per XCD
  int nx = N >> 7;
  int nwg = gridDim.x;
  int orig = blockIdx.x;
  int q = nwg >> 3, r8 = nwg & 7;
  int xcd = orig & 7, idx = orig >> 3;
  int wgid = (xcd < r8 ? xcd*(q+1) : r8*(q+1) + (xcd - r8)*q) + idx;
  int m0 = (wgid / nx) << 7;
  int n0 = (wgid % nx) << 7;
  int ec = wave*64 + lane;                 // chunk id 0..511
  int rowc = ec >> 2, kcc = (ec & 3) << 3;
  const unsigned short* ap = A  + (size_t)(m0+rowc)*K + kcc;
  const unsigned short* bp = Bw + (size_t)(n0+rowc)*K + kcc;
  unsigned short* lda0 = &As[0][wave*512]; // wave-uniform LDS bases
  unsigned short* lda1 = &As[1][wave*512];
  unsigned short* ldb0 = &Bs[0][wave*512];
  unsigned short* ldb1 = &Bs[1][wave*512];
  f32x4 acc[4][2];
  #pragma unroll
  for (int m = 0; m < 4; m++)
    #pragma unroll
    for (int n = 0; n < 2; n++) acc[m][n] = (f32x4){0.f,0.f,0.f,0.f};

  stage16(ap, lda0);
  stage16(bp, ldb0);
  int cur = 0;
  for (int k0 = 0; k0 < K - 32; k0 += 32){
    int ko = k0 + 32;
    stage16(ap + ko, cur ? lda0 : lda1);
    stage16(bp + ko, cur ? ldb0 : ldb1);
    asm volatile("s_waitcnt vmcnt(2)" ::: "memory");
    __builtin_amdgcn_s_barrier();
    __builtin_amdgcn_sched_barrier(0);
    bh8 fa[4], fb[2];
    #pragma unroll
    for (int m = 0; m < 4; m++)
      fa[m] = *(const bh8*)&As[cur][(wr0 + m*16 + (lane & 15))*32 + (lane >> 4)*8];
    #pragma unroll
    for (int n = 0; n < 2; n++)
      fb[n] = *(const bh8*)&Bs[cur][(wc0 + n*16 + (lane & 15))*32 + (lane >> 4)*8];
    #pragma unroll
    for (int m = 0; m < 4; m++)
      #pragma unroll
      for (int n = 0; n < 2; n++)
        acc[m][n] = __builtin_amdgcn_mfma_f32_16x16x32_bf16(fa[m], fb[n], acc[m][n], 0, 0, 0);
    __builtin_amdgcn_sched_barrier(0);
    __builtin_amdgcn_s_barrier();          // WAR: all reads of buf[cur] done
    cur ^= 1;
  }
  asm volatile("s_waitcnt vmcnt(0)" ::: "memory");
  __builtin_amdgcn_s_barrier();
  __builtin_amdgcn_sched_barrier(0);
  {
    bh8 fa[4], fb[2];
    #pragma unroll
    for (int m = 0; m < 4; m++)
      fa[m] = *(const bh8*)&As[cur][(wr0 + m*16 + (lane & 15))*32 + (lane >> 4)*8];
    #pragma unroll
    for (int n = 0; n < 2; n++)
      fb[n] = *(const bh8*)&Bs[cur][(wc0 + n*16 + (lane & 15))*32 + (lane >> 4)*8];
    #pragma unroll
    for (int m = 0; m < 4; m++)
      #pragma unroll
      for (int n = 0; n < 2; n++)
        acc[m][n] = __builtin_amdgcn_mfma_f32_16x16x32_bf16(fa[m], fb[n], acc[m][n], 0, 0, 0);
  }
  int rbase = m0 + wr0 + (lane >> 4)*4;
  int cbase = n0 + wc0 + (lane & 15);
  #pragma unroll
  for (int n = 0; n < 2; n++){
    int col = cbase + n*16;
    float bs = bias[col];
    #pragma unroll
    for (int m = 0; m < 4; m++){
      int row = rbase + m*16;
      #pragma unroll
      for (int j = 0; j < 4; j++){
        float cv = acc[m][n][j] + bs;
        if (GELU) cv = 0.5f*cv*(1.f + erff(cv*0.70710678118654752f));
        if (OBF16) ((unsigned short*)Cp)[(size_t)(row+j)*N + col] = f2b(cv);
        else       ((float*)Cp)[(size_t)(row+j)*N + col] = cv;
      }
    }
  }
}

// ------- head GEMM, split-K partials: 8-wave, 1-D XCD-swizzled grid ----------
// grid = SK*6*3 blocks; wgid -> (sk, mb, nb) with nb fastest so the 3 n-blocks
// sharing an A-slice are wgid-adjacent -> same XCD -> A fetched ~once per XCD.
__global__ __launch_bounds__(512, 6) void k_mm_part(const unsigned short* __restrict__ A,
      const unsigned short* __restrict__ Bw, float* __restrict__ part, int kchunk){
  __shared__ unsigned short As[2][128*32];
  __shared__ unsigned short Bs[2][128*32];
  int tid = threadIdx.x;
  int lane = tid & 63;
  int wave = tid >> 6;
  int wr0 = (wave >> 2) * 64;
  int wc0 = (wave & 3) * 32;
  int nwg = gridDim.x;
  int orig = blockIdx.x;
  int q = nwg >> 3, r8 = nwg & 7;
  int xcd = orig & 7, idx = orig >> 3;
  int wgid = (xcd < r8 ? xcd*(q+1) : r8*(q+1) + (xcd - r8)*q) + idx;
  int sk = wgid / 18;
  int rem = wgid - sk*18;
  int m0 = (rem / 3) << 7;
  int n0 = (rem % 3) << 7;
  int kb0 = sk*kchunk;
  int ec = wave*64 + lane;
  int rowc = ec >> 2, kcc = (ec & 3) << 3;
  int ar = m0 + rowc; if (ar >= BC_)  ar = BC_ - 1;
  int br = n0 + rowc; if (br >= PRED_) br = PRED_ - 1;
  const unsigned short* ap = A  + (size_t)ar*KHEAD_ + kb0 + kcc;
  const unsigned short* bp = Bw + (size_t)br*KHEAD_ + kb0 + kcc;
  unsigned short* lda0 = &As[0][wave*512];
  unsigned short* lda1 = &As[1][wave*512];
  unsigned short* ldb0 = &Bs[0][wave*512];
  unsigned short* ldb1 = &Bs[1][wave*512];
  f32x4 acc[4][2];
  #pragma unroll
  for (int m = 0; m < 4; m++)
    #pragma unroll
    for (int n = 0; n < 2; n++) acc[m][n] = (f32x4){0.f,0.f,0.f,0.f};

  stage16(ap, lda0);
  stage16(bp, ldb0);
  int cur = 0;
  for (int ko = 0; ko < kchunk - 32; ko += 32){
    int kk = ko + 32;
    stage16(ap + kk, cur ? lda0 : lda1);
    stage16(bp + kk, cur ? ldb0 : ldb1);
    asm volatile("s_waitcnt vmcnt(2)" ::: "memory");
    __builtin_amdgcn_s_barrier();
    __builtin_amdgcn_sched_barrier(0);
    bh8 fa[4], fb[2];
    #pragma unroll
    for (int m = 0; m < 4; m++)
      fa[m] = *(const bh8*)&As[cur][(wr0 + m*16 + (lane & 15))*32 + (lane >> 4)*8];
    #pragma unroll
    for (int n = 0; n < 2; n++)
      fb[n] = *(const bh8*)&Bs[cur][(wc0 + n*16 + (lane & 15))*32 + (lane >> 4)*8];
    #pragma unroll
    for (int m = 0; m < 4; m++)
      #pragma unroll
      for (int n = 0; n < 2; n++)
        acc[m][n] = __builtin_amdgcn_mfma_f32_16x16x32_bf16(fa[m], fb[n], acc[m][n], 0, 0, 0);
    __builtin_amdgcn_sched_barrier(0);
    __builtin_amdgcn_s_barrier();
    cur ^= 1;
  }
  asm volatile("s_waitcnt vmcnt(0)" ::: "memory");
  __builtin_amdgcn_s_barrier();
  __builtin_amdgcn_sched_barrier(0);
  {
    bh8 fa[4], fb[2];
    #pragma unroll
    for (int m = 0; m < 4; m++)
      fa[m] = *(const bh8*)&As[cur][(wr0 + m*16 + (lane & 15))*32 + (lane >> 4)*8];
    #pragma unroll
    for (int n = 0; n < 2; n++)
      fb[n] = *(const bh8*)&Bs[cur][(wc0 + n*16 + (lane & 15))*32 + (lane >> 4)*8];
    #pragma unroll
    for (int m = 0; m < 4; m++)
      #pragma unroll
      for (int n = 0; n < 2; n++)
        acc[m][n] = __builtin_amdgcn_mfma_f32_16x16x32_bf16(fa[m], fb[n], acc[m][n], 0, 0, 0);
  }
  float* po = part + (size_t)sk*PM_*PN_;
  int rbase = m0 + wr0 + (lane >> 4)*4;
  int cbase = n0 + wc0 + (lane & 15);
  #pragma unroll
  for (int n = 0; n < 2; n++){
    int col = cbase + n*16;
    #pragma unroll
    for (int m = 0; m < 4; m++){
      int row = rbase + m*16;
      #pragma unroll
      for (int j = 0; j < 4; j++)
        po[(size_t)(row+j)*PN_ + col] = acc[m][n][j];
    }
  }
}

// ---------------- head reduce + bias ----------------
__global__ void k_headred(const float* __restrict__ part, const float* __restrict__ bias2,
                          float* __restrict__ dec, int nsk){
  int i = blockIdx.x*256 + threadIdx.x;
  if (i >= BC_*PRED_) return;
  int bc = i / PRED_, pr = i % PRED_;
  float s = bias2[pr];
  for (int sk = 0; sk < nsk; sk++)
    s += part[(size_t)sk*PM_*PN_ + (size_t)bc*PN_ + pr];
  dec[i] = s;
}

// -------- MFMA fused attention: block = (bc-local, head), 6 waves -------------
__global__ __launch_bounds__(384) void k_attn(const unsigned short* __restrict__ qkv,
                                              unsigned short* __restrict__ o){
  __shared__ unsigned short Qb[96][72];       // stride 144B: 2-way alias (free)
  __shared__ unsigned short Kb[96][72];
  __shared__ unsigned short Vt[64][104];      // V transposed; stride 208B
  __shared__ unsigned short Pb[6][16][104];
  int bh = blockIdx.x; int bcl = bh >> 3, h = bh & 7;
  int tid = threadIdx.x, lane = tid & 63, wv = tid >> 6;   // wv = row-tile 0..5
  size_t qb = (size_t)bcl*N_*QKVN_ + h*64;
  for (int g = tid; g < 1536; g += 384){
    int n = g >> 4, d4 = (g & 15) << 2;
    ushort4 qv = make_ushort4(0,0,0,0), kv = make_ushort4(0,0,0,0);
    if (n < N_){
      qv = *(const ushort4*)(qkv + qb + (size_t)n*QKVN_ + d4);
      kv = *(const ushort4*)(qkv + qb + 512 + (size_t)n*QKVN_ + d4);
    }
    *(ushort4*)&Qb[n][d4] = qv;
    *(ushort4*)&Kb[n][d4] = kv;
  }
  for (int g = tid; g < N_*16; g += 384){
    int n = g >> 4, d4 = (g & 15) << 2;
    ushort4 vv = *(const ushort4*)(qkv + qb + 1024 + (size_t)n*QKVN_ + d4);
    Vt[d4+0][n] = vv.x; Vt[d4+1][n] = vv.y; Vt[d4+2][n] = vv.z; Vt[d4+3][n] = vv.w;
  }
  for (int g = tid; g < 64*12; g += 384) Vt[g/12][N_ + g%12] = 0;
  __syncthreads();
  f32x4 acc[6];
  #pragma unroll
  for (int t = 0; t < 6; t++) acc[t] = (f32x4){0.f,0.f,0.f,0.f};
  #pragma unroll
  for (int ks = 0; ks < 2; ks++){
    bh8 qa = *(const bh8*)&Qb[wv*16 + (lane & 15)][ks*32 + (lane >> 4)*8];
    #pragma unroll
    for (int t = 0; t < 6; t++){
      bh8 kf = *(const bh8*)&Kb[t*16 + (lane & 15)][ks*32 + (lane >> 4)*8];
      acc[t] = __builtin_amdgcn_mfma_f32_16x16x32_bf16(qa, kf, acc[t], 0, 0, 0);
    }
  }
  bool v5 = (lane & 15) < 4;
  #pragma unroll
  for (int j = 0; j < 4; j++){
    float m = -1e30f;
    #pragma unroll
    for (int t = 0; t < 6; t++){
      float s = acc[t][j] * 0.125f;
      if (t == 5 && !v5) s = -1e30f;
      acc[t][j] = s;
      m = fmaxf(m, s);
    }
    #pragma unroll
    for (int off = 1; off < 16; off <<= 1) m = fmaxf(m, __shfl_xor(m, off, 64));
    float sum = 0.f;
    #pragma unroll
    for (int t = 0; t < 6; t++){
      float p = __expf(acc[t][j] - m);
      acc[t][j] = p;
      sum += p;
    }
    #pragma unroll
    for (int off = 1; off < 16; off <<= 1) sum += __shfl_xor(sum, off, 64);
    float inv = 1.f / sum;
    int lr = (lane >> 4)*4 + j;
    #pragma unroll
    for (int t = 0; t < 6; t++)
      Pb[wv][lr][t*16 + (lane & 15)] = f2b(acc[t][j] * inv);
  }
  f32x4 accO[4];
  #pragma unroll
  for (int dt = 0; dt < 4; dt++) accO[dt] = (f32x4){0.f,0.f,0.f,0.f};
  #pragma unroll
  for (int ks = 0; ks < 3; ks++){
    bh8 pa = *(const bh8*)&Pb[wv][lane & 15][ks*32 + (lane >> 4)*8];
    #pragma unroll
    for (int dt = 0; dt < 4; dt++){
      bh8 vf = *(const bh8*)&Vt[dt*16 + (lane & 15)][ks*32 + (lane >> 4)*8];
      accO[dt] = __builtin_amdgcn_mfma_f32_16x16x32_bf16(pa, vf, accO[dt], 0, 0, 0);
    }
  }
  size_t ob = (size_t)bcl*N_*D_ + h*64;
  #pragma unroll
  for (int dt = 0; dt < 4; dt++)
    #pragma unroll
    for (int j = 0; j < 4; j++){
      int r = wv*16 + (lane >> 4)*4 + j;
      if (r < N_) o[ob + (size_t)r*D_ + dt*16 + (lane & 15)] = f2b(accO[dt][j]);
    }
}

// ---------- fused residual-add + LayerNorm, bf16 residual master --------------
__global__ __launch_bounds__(256) void k_addln(const unsigned short* zin,
                        const unsigned short* __restrict__ delta,
                        const float* __restrict__ g, const float* __restrict__ b,
                        unsigned short* zout, int ntok){
  int w = threadIdx.x >> 6, lane = threadIdx.x & 63;
  int tok = blockIdx.x*4 + w;
  if (tok >= ntok) return;
  const ushort4* zp = (const ushort4*)(zin + (size_t)tok*D_);
  const ushort4* dp = (const ushort4*)(delta + (size_t)tok*D_);
  ushort4 z0 = zp[lane], z1 = zp[64+lane];
  ushort4 u0 = dp[lane], u1 = dp[64+lane];
  float4 a0, a1;
  a0.x = b2f(z0.x) + b2f(u0.x); a0.y = b2f(z0.y) + b2f(u0.y);
  a0.z = b2f(z0.z) + b2f(u0.z); a0.w = b2f(z0.w) + b2f(u0.w);
  a1.x = b2f(z1.x) + b2f(u1.x); a1.y = b2f(z1.y) + b2f(u1.y);
  a1.z = b2f(z1.z) + b2f(u1.z); a1.w = b2f(z1.w) + b2f(u1.w);
  float s  = a0.x+a0.y+a0.z+a0.w + a1.x+a1.y+a1.z+a1.w;
  float sq = a0.x*a0.x+a0.y*a0.y+a0.z*a0.z+a0.w*a0.w
           + a1.x*a1.x+a1.y*a1.y+a1.z*a1.z+a1.w*a1.w;
  s = wred_add(s); sq = wred_add(sq);
  float mean = s * (1.f/D_);
  float var  = sq * (1.f/D_) - mean*mean;
  float rstd = rsqrtf(var + 1e-5f);
  const float4* g4 = (const float4*)g; const float4* b4 = (const float4*)b;
  float4 G0 = g4[lane], G1 = g4[64+lane], B0 = b4[lane], B1 = b4[64+lane];
  unsigned short* zo = zout + (size_t)tok*D_;
  *(ushort4*)(zo + 4*lane) = make_ushort4(
      f2b((a0.x-mean)*rstd*G0.x + B0.x), f2b((a0.y-mean)*rstd*G0.y + B0.y),
      f2b((a0.z-mean)*rstd*G0.z + B0.z), f2b((a0.w-mean)*rstd*G0.w + B0.w));
  *(ushort4*)(zo + 256 + 4*lane) = make_ushort4(
      f2b((a1.x-mean)*rstd*G1.x + B1.x), f2b((a1.y-mean)*rstd*G1.y + B1.y),
      f2b((a1.z-mean)*rstd*G1.z + B1.z), f2b((a1.w-mean)*rstd*G1.w + B1.w));
}

// ------ head_w transpose -> bf16 with BN-gamma fold: hwt[pr][n*512+d] ---------
__global__ void k_transw(const float* __restrict__ hw, const float* __restrict__ bng,
                         unsigned short* __restrict__ hwt){
  int dc = blockIdx.x, pr = blockIdx.y;
  int d0 = dc*64;
  __shared__ float tl[64*N_];
  const float* src = hw + (size_t)pr*KHEAD_ + (size_t)d0*N_;
  for (int i = threadIdx.x; i < 64*N_; i += 256) tl[i] = src[i];
  __syncthreads();
  const float sc = 0.9999950000374997f;   // 1/sqrt(1+1e-5)
  unsigned short* dst = hwt + (size_t)pr*KHEAD_;
  for (int i = threadIdx.x; i < 64*N_; i += 256){
    int n = i >> 6, dd = i & 63;
    dst[(size_t)n*D_ + d0 + dd] = f2b(tl[dd*N_ + n] * sc * bng[d0+dd]);
  }
}

// ------ bias2[pr] = head_b[pr] + sum_{d,n} bn_b[d]*head_w[pr][d*84+n] ---------
__global__ void k_bias2(const float* __restrict__ hw, const float* __restrict__ bnb,
                        const float* __restrict__ hb, float* __restrict__ bias2){
  int pr = blockIdx.x, tid = threadIdx.x;
  const float* src = hw + (size_t)pr*KHEAD_;
  float s = 0.f;
  for (int i = tid; i < KHEAD_; i += 256) s += src[i] * bnb[i / N_];
  __shared__ float rs[4];
  s = wred_add(s);
  int w = tid >> 6;
  if ((tid & 63) == 0) rs[w] = s;
  __syncthreads();
  if (tid == 0) bias2[pr] = hb[pr] + rs[0] + rs[1] + rs[2] + rs[3];
}

// ---------------- de-normalize + final transpose ----------------
__global__ void k_out(const float* __restrict__ dec, const float* __restrict__ stats,
                      float* __restrict__ out){
  int i = blockIdx.x*256 + threadIdx.x;
  if (i >= B_*PRED_*CVAR_) return;
  int c = i % CVAR_; int t = (i / CVAR_) % PRED_; int b = i / (CVAR_*PRED_);
  int bc = b*CVAR_ + c;
  out[i] = dec[(size_t)bc*PRED_ + t] * stats[BC_ + bc] + stats[bc];
}

extern "C" void kernel_launch(void* const* d_in, const int* in_sizes, int n_in,
                              void* d_out, int out_size, void* d_ws, size_t ws_size,
                              hipStream_t stream){
  const float* x_enc  = (const float*)d_in[0];
  const float* cls_w1 = (const float*)d_in[4];
  const float* cls_b1 = (const float*)d_in[5];
  const float* cls_w2 = (const float*)d_in[6];
  const float* cls_b2 = (const float*)d_in[7];
  const float* ew0 = (const float*)d_in[8];
  const float* ew1 = (const float*)d_in[9];
  const float* ew2 = (const float*)d_in[10];
  const float* ew3 = (const float*)d_in[11];
  const float* wq = (const float*)d_in[12]; const float* bq = (const float*)d_in[13];
  const float* wk = (const float*)d_in[14]; const float* bk = (const float*)d_in[15];
  const float* wv = (const float*)d_in[16]; const float* bv = (const float*)d_in[17];
  const float* wo = (const float*)d_in[18]; const float* bo = (const float*)d_in[19];
  const float* ln1_g = (const float*)d_in[20]; const float* ln1_b = (const float*)d_in[21];
  const float* ln2_g = (const float*)d_in[22]; const float* ln2_b = (const float*)d_in[23];
  const float* ff1_w = (const float*)d_in[24]; const float* ff1_b = (const float*)d_in[25];
  const float* ff2_w = (const float*)d_in[26]; const float* ff2_b = (const float*)d_in[27];
  const float* bn_g = (const float*)d_in[28]; const float* bn_b = (const float*)d_in[29];
  const float* head_w = (const float*)d_in[30]; const float* head_b = (const float*)d_in[31];
  float* out = (float*)d_out;

  // ---- workspace layout (256B-aligned regions) ----
  char* cur = (char*)d_ws;
  auto alloc = [&](size_t bytes)->char*{
    char* p = cur; cur += (bytes + 255) & ~(size_t)255; return p;
  };
  float* xc    = (float*)alloc(451584*4);
  float* stats = (float*)alloc(1344*4);
  int*   pred  = (int*)  alloc(9408*4);
  float* pe    = (float*)alloc(43008*4);
  float* ewt   = (float*)alloc(49152*4);
  unsigned short* wqkv_b = (unsigned short*)alloc((size_t)NL_*QKVN_*D_*2);
  float* bqkv  = (float*)alloc((size_t)NL_*QKVN_*4);
  unsigned short* wo_b  = (unsigned short*)alloc((size_t)NL_*D_*D_*2);
  unsigned short* ff1b  = (unsigned short*)alloc((size_t)NL_*DFF_*D_*2);
  unsigned short* ff2b  = (unsigned short*)alloc((size_t)NL_*D_*DFF_*2);
  unsigned short* hwt   = (unsigned short*)alloc((size_t)PRED_*KHEAD_*2);
  float* bias2 = (float*)alloc(PRED_*4);
  unsigned short* zfinal = (unsigned short*)alloc((size_t)M_*D_*2);
  char* E = cur;
  size_t E_avail = (ws_size > (size_t)(E - (char*)d_ws)) ? ws_size - (size_t)(E - (char*)d_ws) : 0;

  // chunk size: Cb in {672,224,96,32}; per-token scratch = 6144 B (bf16 master)
  static const int cands[4] = {672, 224, 96, 32};
  int Cb = 32;
  for (int i = 0; i < 4; i++){
    size_t need = (size_t)6144 * cands[i] * N_;
    if (need <= E_avail){ Cb = cands[i]; break; }
  }
  const int nchunk = BC_ / Cb;
  const int Tc = Cb * N_;
  unsigned short* zb_c = (unsigned short*)E;                           // [Tc][512] bf16
  unsigned short* r1   = (unsigned short*)(E + (size_t)1024*Tc);       // qkv [Tc][1536] / y1 [Tc][2048]
  unsigned short* abuf = (unsigned short*)(E + (size_t)4096*Tc);       // attn out [Tc][512]
  unsigned short* r2   = (unsigned short*)(E + (size_t)5120*Tc);       // delta [Tc][512] bf16
  // head-phase scratch (after encoder done): pick largest SK that fits
  int SK = 8;
  {
    size_t dec_b = (size_t)BC_*PRED_*4 + 256;
    if ((size_t)32*PM_*PN_*4 + dec_b <= E_avail) SK = 32;
    else if ((size_t)16*PM_*PN_*4 + dec_b <= E_avail) SK = 16;
  }
  float* part = (float*)E;
  float* dec  = (float*)(E + (size_t)SK*PM_*PN_*4);

  // ---- prologue ----
  k_instnorm<<<BC_, 256, 0, stream>>>(x_enc, xc, stats);
  k_router<<<(BC_*R_ + 255)/256, 256, 0, stream>>>(xc, cls_w1, cls_b1, cls_w2, cls_b2, pred);
  k_pe<<<(N_*D_ + 255)/256, 256, 0, stream>>>(pe);
  k_transe<<<192, 256, 0, stream>>>(ew0, ew1, ew2, ew3, ewt);
  int nqkvg = NL_*QKVN_*D_/4, nw4 = NL_*D_*D_/4, nff4 = NL_*DFF_*D_/4;
  k_cvtqkv<<<(nqkvg+255)/256, 256, 0, stream>>>(wq, wk, wv, wqkv_b);
  k_catbias<<<(NL_*QKVN_+255)/256, 256, 0, stream>>>(bq, bk, bv, bqkv);
  k_cvt<<<(nw4+255)/256, 256, 0, stream>>>(wo, wo_b, nw4);
  k_cvt<<<(nff4+255)/256, 256, 0, stream>>>(ff1_w, ff1b, nff4);
  k_cvt<<<(nff4+255)/256, 256, 0, stream>>>(ff2_w, ff2b, nff4);
  k_transw<<<dim3(8, PRED_), 256, 0, stream>>>(head_w, bn_g, hwt);
  k_bias2<<<PRED_, 256, 0, stream>>>(head_w, bn_b, head_b, bias2);

  // ---- encoder (chunked over bc; chunks fully independent) ----
  for (int ch = 0; ch < nchunk; ch++){
    int bc0 = ch*Cb;
    k_embed<<<Cb*R_, 256, 0, stream>>>(xc, pred, ewt, pe, zb_c, bc0);
    for (int l = 0; l < NL_; l++){
      k_mm<false,true><<<(QKVN_/128)*(Tc/128), 512, 0, stream>>>(
          zb_c, wqkv_b + (size_t)l*QKVN_*D_, bqkv + l*QKVN_, r1, Tc, QKVN_, D_);
      k_attn<<<Cb*H_, 384, 0, stream>>>(r1, abuf);
      k_mm<false,true><<<(D_/128)*(Tc/128), 512, 0, stream>>>(
          abuf, wo_b + (size_t)l*D_*D_, bo + l*D_, r2, Tc, D_, D_);
      k_addln<<<Tc/4, 256, 0, stream>>>(zb_c, r2, ln1_g+l*D_, ln1_b+l*D_, zb_c, Tc);
      size_t foff = (size_t)l*DFF_*D_;
      k_mm<true,true><<<(DFF_/128)*(Tc/128), 512, 0, stream>>>(
          zb_c, ff1b+foff, ff1_b+l*DFF_, r1, Tc, DFF_, D_);
      k_mm<false,true><<<(D_/128)*(Tc/128), 512, 0, stream>>>(
          r1, ff2b+foff, ff2_b+l*D_, r2, Tc, D_, DFF_);
      unsigned short* zb_out = (l == NL_-1) ? (zfinal + (size_t)bc0*N_*D_) : zb_c;
      k_addln<<<Tc/4, 256, 0, stream>>>(zb_c, r2, ln2_g+l*D_, ln2_b+l*D_, zb_out, Tc);
    }
  }

  // ---- head: dec = zfinal @ hwt^T (split-K) + bias2, then de-normalize ----
  k_mm_part<<<SK*18, 512, 0, stream>>>(zfinal, hwt, part, KHEAD_/SK);
  k_headred<<<(BC_*PRED_ + 255)/256, 256, 0, stream>>>(part, bias2, dec, SK);
  k_out<<<(B_*PRED_*CVAR_ + 255)/256, 256, 0, stream>>>(dec, stats, out);
}

// Round 14
// 1598.543 us; speedup vs baseline: 1.2170x; 1.0262x over previous
//
#include <hip/hip_runtime.h>
#include <hip/hip_bf16.h>
#include <math.h>

#define B_    32
#define SEQ_  672
#define CVAR_ 21
#define PRED_ 336
#define D_    512
#define H_    8
#define DFF_  2048
#define NL_   2
#define R_    14
#define T_    6
#define N_    84
#define BC_   672           // B_*CVAR_
#define M_    (BC_*N_)      // 56448 tokens
#define KHEAD_ (D_*N_)      // 43008
#define PM_   768           // head M padded to 6*128
#define PN_   384           // head N padded to 3*128
#define QKVN_ 1536          // fused qkv width

typedef __attribute__((ext_vector_type(8))) short bh8;
typedef __attribute__((ext_vector_type(4))) float f32x4;

__device__ __forceinline__ unsigned short f2b(float x){
  union { float f; unsigned int u; } v; v.f = x;
  unsigned int r = v.u + 0x7FFFu + ((v.u >> 16) & 1u);   // RNE
  return (unsigned short)(r >> 16);
}
__device__ __forceinline__ float b2f(unsigned short h){
  union { unsigned int u; float f; } v; v.u = ((unsigned int)h) << 16;
  return v.f;
}
__device__ __forceinline__ float wred_add(float v){
  #pragma unroll
  for (int o = 32; o; o >>= 1) v += __shfl_xor(v, o, 64);
  return v;
}
// async global->LDS, 16B per lane; lds base must be wave-uniform
__device__ __forceinline__ void stage16(const unsigned short* g, unsigned short* l){
  __builtin_amdgcn_global_load_lds(
      (const __attribute__((address_space(1))) unsigned int*)(const void*)g,
      (__attribute__((address_space(3))) unsigned int*)(void*)l, 16, 0, 0);
}

// ---------------- instance norm over time ----------------
__global__ void k_instnorm(const float* __restrict__ x, float* __restrict__ xc,
                           float* __restrict__ stats){
  int bc = blockIdx.x; int b = bc / CVAR_, c = bc % CVAR_;
  const float* xp = x + (size_t)b*SEQ_*CVAR_ + c;
  int tid = threadIdx.x;
  float s = 0.f, sq = 0.f;
  for (int l = tid; l < SEQ_; l += 256){ float v = xp[(size_t)l*CVAR_]; s += v; sq += v*v; }
  __shared__ float rs[4], rq[4];
  s = wred_add(s); sq = wred_add(sq);
  int w = tid >> 6, lane = tid & 63;
  if (lane == 0){ rs[w] = s; rq[w] = sq; }
  __syncthreads();
  if (tid == 0){
    float S = rs[0]+rs[1]+rs[2]+rs[3], Q = rq[0]+rq[1]+rq[2]+rq[3];
    float mean = S * (1.f/SEQ_);
    float var  = Q * (1.f/SEQ_) - mean*mean;
    float stdev = sqrtf(var + 1e-5f);
    stats[bc] = mean; stats[BC_ + bc] = stdev;
    rs[0] = mean; rq[0] = stdev;
  }
  __syncthreads();
  float mean = rs[0], inv = 1.f / rq[0];
  for (int l = tid; l < SEQ_; l += 256)
    xc[(size_t)bc*SEQ_ + l] = (xp[(size_t)l*CVAR_] - mean) * inv;
}

// ------------- region router: one wave per region, no spills ------------------
// grid = BC_*R_/4 blocks exactly (9408 regions, 4 waves/block).
__global__ __launch_bounds__(256) void k_router(const float* __restrict__ xc,
                         const float* __restrict__ w1, const float* __restrict__ b1,
                         const float* __restrict__ w2, const float* __restrict__ b2,
                         int* __restrict__ pred){
  __shared__ float xs[4][48];
  int tid = threadIdx.x, wv = tid >> 6, lane = tid & 63;
  int t = blockIdx.x*4 + wv;             // region id, always < BC_*R_
  int bc = t / R_, r = t % R_;
  if (lane < 48) xs[wv][lane] = xc[(size_t)bc*SEQ_ + r*48 + lane];
  __syncthreads();
  float h = b1[lane];
  const float* wr = w1 + lane*48;
  #pragma unroll 12
  for (int i = 0; i < 48; i++) h = fmaf(xs[wv][i], wr[i], h);
  h = fmaxf(h, 0.f);
  float best = 0.f; int be = 0;
  #pragma unroll
  for (int e = 0; e < 4; e++){
    float lg = b2[e] + wred_add(h * w2[e*64 + lane]);
    if (e == 0) best = lg;
    else if (lg > best){ best = lg; be = e; }   // first max wins (strict >)
  }
  if (lane == 0) pred[t] = be;
}

// ---------------- positional encoding ----------------
__global__ void k_pe(float* __restrict__ pe){
  int i = blockIdx.x*256 + threadIdx.x;
  if (i >= N_*D_) return;
  int n = i / D_, d = i % D_;
  int ii = d >> 1;
  float freq = expf((float)(2*ii) * (-9.210340371976184f / (float)D_)); // -ln(10000)/D
  float a = (float)n * freq;
  pe[i] = (d & 1) ? cosf(a) : sinf(a);
}

// ---------------- fp32 -> bf16 convert (n4 = elems/4) ----------------
__global__ void k_cvt(const float* __restrict__ in, unsigned short* __restrict__ out, int n4){
  int i = blockIdx.x*256 + threadIdx.x;
  if (i >= n4) return;
  float4 v = ((const float4*)in)[i];
  ((ushort4*)out)[i] = make_ushort4(f2b(v.x), f2b(v.y), f2b(v.z), f2b(v.w));
}

// ---------------- fused qkv weight convert (concat rows) ----------------
__global__ void k_cvtqkv(const float* __restrict__ wq, const float* __restrict__ wk,
                         const float* __restrict__ wv, unsigned short* __restrict__ o){
  int i = blockIdx.x*256 + threadIdx.x;          // one per 4 elems
  const int per_l = QKVN_*D_/4;                  // 196608
  const int per_s = D_*D_/4;                     // 65536
  if (i >= NL_*per_l) return;
  int l = i / per_l;
  int rem = i - l*per_l;
  int sec = rem / per_s;
  int off = rem - sec*per_s;
  const float* src = (sec==0 ? wq : sec==1 ? wk : wv) + (size_t)l*D_*D_ + (size_t)off*4;
  float4 v = *(const float4*)src;
  ((ushort4*)o)[i] = make_ushort4(f2b(v.x), f2b(v.y), f2b(v.z), f2b(v.w));
}

// ---------------- qkv bias concat ----------------
__global__ void k_catbias(const float* __restrict__ bq, const float* __restrict__ bk,
                          const float* __restrict__ bv, float* __restrict__ bqkv){
  int i = blockIdx.x*256 + threadIdx.x;
  if (i >= NL_*QKVN_) return;
  int l = i / QKVN_, r = i % QKVN_;
  float v = (r < 512) ? bq[l*512 + r] : (r < 1024) ? bk[l*512 + r - 512] : bv[l*512 + r - 1024];
  bqkv[i] = v;
}

// ------ expert weight transpose: W_e[d][q] -> wt[base_e + q*512 + d] ----------
__global__ void k_transe(const float* __restrict__ w0, const float* __restrict__ w1,
                         const float* __restrict__ w2, const float* __restrict__ w3,
                         float* __restrict__ wt){
  int i = blockIdx.x*256 + threadIdx.x;
  if (i >= 49152) return;
  int e, base, p;
  if (i < 4096){ e = 0; base = 0; p = 8; }
  else if (i < 12288){ e = 1; base = 4096; p = 16; }
  else if (i < 24576){ e = 2; base = 12288; p = 24; }
  else { e = 3; base = 24576; p = 48; }
  int local = i - base;
  int q = local >> 9, d = local & 511;
  const float* W = (e==0) ? w0 : (e==1) ? w1 : (e==2) ? w2 : w3;
  wt[base + q*512 + d] = W[(size_t)d*p + q];
}

// ---------------- patch embedding + PE (coalesced transposed weights) ---------
__global__ void k_embed(const float* __restrict__ xc, const int* __restrict__ pred,
                        const float* __restrict__ wt, const float* __restrict__ pe,
                        unsigned short* __restrict__ zb, int bc0){
  int blk = blockIdx.x; int bcl = blk / R_, r = blk % R_;
  int bc = bc0 + bcl;
  __shared__ float xr[48];
  int tid = threadIdx.x;
  if (tid < 48) xr[tid] = xc[(size_t)bc*SEQ_ + r*48 + tid];
  __syncthreads();
  int e = pred[bc*R_ + r];
  int p    = (e==0) ? 8 : (e==1) ? 16 : (e==2) ? 24 : 48;
  int base = (e==0) ? 0 : (e==1) ? 4096 : (e==2) ? 12288 : 24576;
  int num = 48 / p, rep = 7 - num;
  const float* Wt = wt + base;
  int d0 = tid, d1 = tid + 256;
  float acc0[6], acc1[6];
  #pragma unroll
  for (int u = 0; u < 6; u++){ acc0[u] = 0.f; acc1[u] = 0.f; }
  #pragma unroll
  for (int u = 0; u < 6; u++){
    if (u < num){
      float s0 = 0.f, s1 = 0.f;
      const float* xu = xr + u*p;
      for (int q = 0; q < p; q++){
        float xv = xu[q];
        const float* wrow = Wt + q*512;
        s0 = fmaf(xv, wrow[d0], s0);
        s1 = fmaf(xv, wrow[d1], s1);
      }
      acc0[u] = s0; acc1[u] = s1;
    }
  }
  #pragma unroll
  for (int u = 0; u < 6; u++){
    if (u < num){
      #pragma unroll
      for (int t = 0; t < 6; t++){
        int ut = t / rep; if (ut > num-1) ut = num-1;
        if (ut == u){
          int n = r*T_ + t;
          size_t off = ((size_t)bcl*N_ + n)*D_;
          zb[off + d0] = f2b(acc0[u] + pe[n*D_ + d0]);
          zb[off + d1] = f2b(acc1[u] + pe[n*D_ + d1]);
        }
      }
    }
  }
}

// ---------------- bf16 MFMA GEMM: C[M,N] = act(A[M,K] * B[N,K]^T + bias) ------
// 128x128 tile, BK=32, 512 thr (8 waves, 2 row-groups x 4 col-groups).
// Per wave: 64x32 output (acc[4][2] = 32 AGPRs) -> ~82 unified regs ->
// 6 waves/SIMD. Double-buffered LDS with COUNTED vmcnt(2).
template<bool GELU, bool OBF16>
__global__ __launch_bounds__(512, 6) void k_mm(const unsigned short* __restrict__ A,
      const unsigned short* __restrict__ Bw, const float* __restrict__ bias,
      void* __restrict__ Cp, int M, int N, int K){
  __shared__ unsigned short As[2][128*32];
  __shared__ unsigned short Bs[2][128*32];
  int tid = threadIdx.x;
  int lane = tid & 63;
  int wave = tid >> 6;                     // 0..7
  int wr0 = (wave >> 2) * 64;              // 0 / 64
  int wc0 = (wave & 3) * 32;               // 0 / 32 / 64 / 96
  // bijective XCD swizzle (m204): contiguous wgid chunk per XCD
  int nx = N >> 7;
  int nwg = gridDim.x;
  int orig = blockIdx.x;
  int q = nwg >> 3, r8 = nwg & 7;
  int xcd = orig & 7, idx = orig >> 3;
  int wgid = (xcd < r8 ? xcd*(q+1) : r8*(q+1) + (xcd - r8)*q) + idx;
  int m0 = (wgid / nx) << 7;
  int n0 = (wgid % nx) << 7;
  int ec = wave*64 + lane;                 // chunk id 0..511
  int rowc = ec >> 2, kcc = (ec & 3) << 3;
  const unsigned short* ap = A  + (size_t)(m0+rowc)*K + kcc;
  const unsigned short* bp = Bw + (size_t)(n0+rowc)*K + kcc;
  unsigned short* lda0 = &As[0][wave*512]; // wave-uniform LDS bases
  unsigned short* lda1 = &As[1][wave*512];
  unsigned short* ldb0 = &Bs[0][wave*512];
  unsigned short* ldb1 = &Bs[1][wave*512];
  f32x4 acc[4][2];
  #pragma unroll
  for (int m = 0; m < 4; m++)
    #pragma unroll
    for (int n = 0; n < 2; n++) acc[m][n] = (f32x4){0.f,0.f,0.f,0.f};

  stage16(ap, lda0);
  stage16(bp, ldb0);
  int cur = 0;
  for (int k0 = 0; k0 < K - 32; k0 += 32){
    int ko = k0 + 32;
    stage16(ap + ko, cur ? lda0 : lda1);
    stage16(bp + ko, cur ? ldb0 : ldb1);
    asm volatile("s_waitcnt vmcnt(2)" ::: "memory");
    __builtin_amdgcn_s_barrier();
    __builtin_amdgcn_sched_barrier(0);
    bh8 fa[4], fb[2];
    #pragma unroll
    for (int m = 0; m < 4; m++)
      fa[m] = *(const bh8*)&As[cur][(wr0 + m*16 + (lane & 15))*32 + (lane >> 4)*8];
    #pragma unroll
    for (int n = 0; n < 2; n++)
      fb[n] = *(const bh8*)&Bs[cur][(wc0 + n*16 + (lane & 15))*32 + (lane >> 4)*8];
    #pragma unroll
    for (int m = 0; m < 4; m++)
      #pragma unroll
      for (int n = 0; n < 2; n++)
        acc[m][n] = __builtin_amdgcn_mfma_f32_16x16x32_bf16(fa[m], fb[n], acc[m][n], 0, 0, 0);
    __builtin_amdgcn_sched_barrier(0);
    __builtin_amdgcn_s_barrier();          // WAR: all reads of buf[cur] done
    cur ^= 1;
  }
  asm volatile("s_waitcnt vmcnt(0)" ::: "memory");
  __builtin_amdgcn_s_barrier();
  __builtin_amdgcn_sched_barrier(0);
  {
    bh8 fa[4], fb[2];
    #pragma unroll
    for (int m = 0; m < 4; m++)
      fa[m] = *(const bh8*)&As[cur][(wr0 + m*16 + (lane & 15))*32 + (lane >> 4)*8];
    #pragma unroll
    for (int n = 0; n < 2; n++)
      fb[n] = *(const bh8*)&Bs[cur][(wc0 + n*16 + (lane & 15))*32 + (lane >> 4)*8];
    #pragma unroll
    for (int m = 0; m < 4; m++)
      #pragma unroll
      for (int n = 0; n < 2; n++)
        acc[m][n] = __builtin_amdgcn_mfma_f32_16x16x32_bf16(fa[m], fb[n], acc[m][n], 0, 0, 0);
  }
  int rbase = m0 + wr0 + (lane >> 4)*4;
  int cbase = n0 + wc0 + (lane & 15);
  #pragma unroll
  for (int n = 0; n < 2; n++){
    int col = cbase + n*16;
    float bs = bias[col];
    #pragma unroll
    for (int m = 0; m < 4; m++){
      int row = rbase + m*16;
      #pragma unroll
      for (int j = 0; j < 4; j++){
        float cv = acc[m][n][j] + bs;
        if (GELU) cv = 0.5f*cv*(1.f + erff(cv*0.70710678118654752f));
        if (OBF16) ((unsigned short*)Cp)[(size_t)(row+j)*N + col] = f2b(cv);
        else       ((float*)Cp)[(size_t)(row+j)*N + col] = cv;
      }
    }
  }
}

// ------- head GEMM, split-K partials: 8-wave, 1-D XCD-swizzled grid ----------
__global__ __launch_bounds__(512, 6) void k_mm_part(const unsigned short* __restrict__ A,
      const unsigned short* __restrict__ Bw, float* __restrict__ part, int kchunk){
  __shared__ unsigned short As[2][128*32];
  __shared__ unsigned short Bs[2][128*32];
  int tid = threadIdx.x;
  int lane = tid & 63;
  int wave = tid >> 6;
  int wr0 = (wave >> 2) * 64;
  int wc0 = (wave & 3) * 32;
  int nwg = gridDim.x;
  int orig = blockIdx.x;
  int q = nwg >> 3, r8 = nwg & 7;
  int xcd = orig & 7, idx = orig >> 3;
  int wgid = (xcd < r8 ? xcd*(q+1) : r8*(q+1) + (xcd - r8)*q) + idx;
  int sk = wgid / 18;
  int rem = wgid - sk*18;
  int m0 = (rem / 3) << 7;
  int n0 = (rem % 3) << 7;
  int kb0 = sk*kchunk;
  int ec = wave*64 + lane;
  int rowc = ec >> 2, kcc = (ec & 3) << 3;
  int ar = m0 + rowc; if (ar >= BC_)  ar = BC_ - 1;
  int br = n0 + rowc; if (br >= PRED_) br = PRED_ - 1;
  const unsigned short* ap = A  + (size_t)ar*KHEAD_ + kb0 + kcc;
  const unsigned short* bp = Bw + (size_t)br*KHEAD_ + kb0 + kcc;
  unsigned short* lda0 = &As[0][wave*512];
  unsigned short* lda1 = &As[1][wave*512];
  unsigned short* ldb0 = &Bs[0][wave*512];
  unsigned short* ldb1 = &Bs[1][wave*512];
  f32x4 acc[4][2];
  #pragma unroll
  for (int m = 0; m < 4; m++)
    #pragma unroll
    for (int n = 0; n < 2; n++) acc[m][n] = (f32x4){0.f,0.f,0.f,0.f};

  stage16(ap, lda0);
  stage16(bp, ldb0);
  int cur = 0;
  for (int ko = 0; ko < kchunk - 32; ko += 32){
    int kk = ko + 32;
    stage16(ap + kk, cur ? lda0 : lda1);
    stage16(bp + kk, cur ? ldb0 : ldb1);
    asm volatile("s_waitcnt vmcnt(2)" ::: "memory");
    __builtin_amdgcn_s_barrier();
    __builtin_amdgcn_sched_barrier(0);
    bh8 fa[4], fb[2];
    #pragma unroll
    for (int m = 0; m < 4; m++)
      fa[m] = *(const bh8*)&As[cur][(wr0 + m*16 + (lane & 15))*32 + (lane >> 4)*8];
    #pragma unroll
    for (int n = 0; n < 2; n++)
      fb[n] = *(const bh8*)&Bs[cur][(wc0 + n*16 + (lane & 15))*32 + (lane >> 4)*8];
    #pragma unroll
    for (int m = 0; m < 4; m++)
      #pragma unroll
      for (int n = 0; n < 2; n++)
        acc[m][n] = __builtin_amdgcn_mfma_f32_16x16x32_bf16(fa[m], fb[n], acc[m][n], 0, 0, 0);
    __builtin_amdgcn_sched_barrier(0);
    __builtin_amdgcn_s_barrier();
    cur ^= 1;
  }
  asm volatile("s_waitcnt vmcnt(0)" ::: "memory");
  __builtin_amdgcn_s_barrier();
  __builtin_amdgcn_sched_barrier(0);
  {
    bh8 fa[4], fb[2];
    #pragma unroll
    for (int m = 0; m < 4; m++)
      fa[m] = *(const bh8*)&As[cur][(wr0 + m*16 + (lane & 15))*32 + (lane >> 4)*8];
    #pragma unroll
    for (int n = 0; n < 2; n++)
      fb[n] = *(const bh8*)&Bs[cur][(wc0 + n*16 + (lane & 15))*32 + (lane >> 4)*8];
    #pragma unroll
    for (int m = 0; m < 4; m++)
      #pragma unroll
      for (int n = 0; n < 2; n++)
        acc[m][n] = __builtin_amdgcn_mfma_f32_16x16x32_bf16(fa[m], fb[n], acc[m][n], 0, 0, 0);
  }
  float* po = part + (size_t)sk*PM_*PN_;
  int rbase = m0 + wr0 + (lane >> 4)*4;
  int cbase = n0 + wc0 + (lane & 15);
  #pragma unroll
  for (int n = 0; n < 2; n++){
    int col = cbase + n*16;
    #pragma unroll
    for (int m = 0; m < 4; m++){
      int row = rbase + m*16;
      #pragma unroll
      for (int j = 0; j < 4; j++)
        po[(size_t)(row+j)*PN_ + col] = acc[m][n][j];
    }
  }
}

// ---------------- head reduce + bias ----------------
__global__ void k_headred(const float* __restrict__ part, const float* __restrict__ bias2,
                          float* __restrict__ dec, int nsk){
  int i = blockIdx.x*256 + threadIdx.x;
  if (i >= BC_*PRED_) return;
  int bc = i / PRED_, pr = i % PRED_;
  float s = bias2[pr];
  for (int sk = 0; sk < nsk; sk++)
    s += part[(size_t)sk*PM_*PN_ + (size_t)bc*PN_ + pr];
  dec[i] = s;
}

// -------- MFMA fused attention: block = (bc-local, head), 6 waves -------------
__global__ __launch_bounds__(384) void k_attn(const unsigned short* __restrict__ qkv,
                                              unsigned short* __restrict__ o){
  __shared__ unsigned short Qb[96][72];       // stride 144B: 2-way alias (free)
  __shared__ unsigned short Kb[96][72];
  __shared__ unsigned short Vt[64][104];      // V transposed; stride 208B
  __shared__ unsigned short Pb[6][16][104];
  int bh = blockIdx.x; int bcl = bh >> 3, h = bh & 7;
  int tid = threadIdx.x, lane = tid & 63, wv = tid >> 6;   // wv = row-tile 0..5
  size_t qb = (size_t)bcl*N_*QKVN_ + h*64;
  for (int g = tid; g < 1536; g += 384){
    int n = g >> 4, d4 = (g & 15) << 2;
    ushort4 qv = make_ushort4(0,0,0,0), kv = make_ushort4(0,0,0,0);
    if (n < N_){
      qv = *(const ushort4*)(qkv + qb + (size_t)n*QKVN_ + d4);
      kv = *(const ushort4*)(qkv + qb + 512 + (size_t)n*QKVN_ + d4);
    }
    *(ushort4*)&Qb[n][d4] = qv;
    *(ushort4*)&Kb[n][d4] = kv;
  }
  for (int g = tid; g < N_*16; g += 384){
    int n = g >> 4, d4 = (g & 15) << 2;
    ushort4 vv = *(const ushort4*)(qkv + qb + 1024 + (size_t)n*QKVN_ + d4);
    Vt[d4+0][n] = vv.x; Vt[d4+1][n] = vv.y; Vt[d4+2][n] = vv.z; Vt[d4+3][n] = vv.w;
  }
  for (int g = tid; g < 64*12; g += 384) Vt[g/12][N_ + g%12] = 0;
  __syncthreads();
  f32x4 acc[6];
  #pragma unroll
  for (int t = 0; t < 6; t++) acc[t] = (f32x4){0.f,0.f,0.f,0.f};
  #pragma unroll
  for (int ks = 0; ks < 2; ks++){
    bh8 qa = *(const bh8*)&Qb[wv*16 + (lane & 15)][ks*32 + (lane >> 4)*8];
    #pragma unroll
    for (int t = 0; t < 6; t++){
      bh8 kf = *(const bh8*)&Kb[t*16 + (lane & 15)][ks*32 + (lane >> 4)*8];
      acc[t] = __builtin_amdgcn_mfma_f32_16x16x32_bf16(qa, kf, acc[t], 0, 0, 0);
    }
  }
  bool v5 = (lane & 15) < 4;
  #pragma unroll
  for (int j = 0; j < 4; j++){
    float m = -1e30f;
    #pragma unroll
    for (int t = 0; t < 6; t++){
      float s = acc[t][j] * 0.125f;
      if (t == 5 && !v5) s = -1e30f;
      acc[t][j] = s;
      m = fmaxf(m, s);
    }
    #pragma unroll
    for (int off = 1; off < 16; off <<= 1) m = fmaxf(m, __shfl_xor(m, off, 64));
    float sum = 0.f;
    #pragma unroll
    for (int t = 0; t < 6; t++){
      float p = __expf(acc[t][j] - m);
      acc[t][j] = p;
      sum += p;
    }
    #pragma unroll
    for (int off = 1; off < 16; off <<= 1) sum += __shfl_xor(sum, off, 64);
    float inv = 1.f / sum;
    int lr = (lane >> 4)*4 + j;
    #pragma unroll
    for (int t = 0; t < 6; t++)
      Pb[wv][lr][t*16 + (lane & 15)] = f2b(acc[t][j] * inv);
  }
  f32x4 accO[4];
  #pragma unroll
  for (int dt = 0; dt < 4; dt++) accO[dt] = (f32x4){0.f,0.f,0.f,0.f};
  #pragma unroll
  for (int ks = 0; ks < 3; ks++){
    bh8 pa = *(const bh8*)&Pb[wv][lane & 15][ks*32 + (lane >> 4)*8];
    #pragma unroll
    for (int dt = 0; dt < 4; dt++){
      bh8 vf = *(const bh8*)&Vt[dt*16 + (lane & 15)][ks*32 + (lane >> 4)*8];
      accO[dt] = __builtin_amdgcn_mfma_f32_16x16x32_bf16(pa, vf, accO[dt], 0, 0, 0);
    }
  }
  size_t ob = (size_t)bcl*N_*D_ + h*64;
  #pragma unroll
  for (int dt = 0; dt < 4; dt++)
    #pragma unroll
    for (int j = 0; j < 4; j++){
      int r = wv*16 + (lane >> 4)*4 + j;
      if (r < N_) o[ob + (size_t)r*D_ + dt*16 + (lane & 15)] = f2b(accO[dt][j]);
    }
}

// ---------- fused residual-add + LayerNorm, bf16 residual master --------------
__global__ __launch_bounds__(256) void k_addln(const unsigned short* zin,
                        const unsigned short* __restrict__ delta,
                        const float* __restrict__ g, const float* __restrict__ b,
                        unsigned short* zout, int ntok){
  int w = threadIdx.x >> 6, lane = threadIdx.x & 63;
  int tok = blockIdx.x*4 + w;
  if (tok >= ntok) return;
  const ushort4* zp = (const ushort4*)(zin + (size_t)tok*D_);
  const ushort4* dp = (const ushort4*)(delta + (size_t)tok*D_);
  ushort4 z0 = zp[lane], z1 = zp[64+lane];
  ushort4 u0 = dp[lane], u1 = dp[64+lane];
  float4 a0, a1;
  a0.x = b2f(z0.x) + b2f(u0.x); a0.y = b2f(z0.y) + b2f(u0.y);
  a0.z = b2f(z0.z) + b2f(u0.z); a0.w = b2f(z0.w) + b2f(u0.w);
  a1.x = b2f(z1.x) + b2f(u1.x); a1.y = b2f(z1.y) + b2f(u1.y);
  a1.z = b2f(z1.z) + b2f(u1.z); a1.w = b2f(z1.w) + b2f(u1.w);
  float s  = a0.x+a0.y+a0.z+a0.w + a1.x+a1.y+a1.z+a1.w;
  float sq = a0.x*a0.x+a0.y*a0.y+a0.z*a0.z+a0.w*a0.w
           + a1.x*a1.x+a1.y*a1.y+a1.z*a1.z+a1.w*a1.w;
  s = wred_add(s); sq = wred_add(sq);
  float mean = s * (1.f/D_);
  float var  = sq * (1.f/D_) - mean*mean;
  float rstd = rsqrtf(var + 1e-5f);
  const float4* g4 = (const float4*)g; const float4* b4 = (const float4*)b;
  float4 G0 = g4[lane], G1 = g4[64+lane], B0 = b4[lane], B1 = b4[64+lane];
  unsigned short* zo = zout + (size_t)tok*D_;
  *(ushort4*)(zo + 4*lane) = make_ushort4(
      f2b((a0.x-mean)*rstd*G0.x + B0.x), f2b((a0.y-mean)*rstd*G0.y + B0.y),
      f2b((a0.z-mean)*rstd*G0.z + B0.z), f2b((a0.w-mean)*rstd*G0.w + B0.w));
  *(ushort4*)(zo + 256 + 4*lane) = make_ushort4(
      f2b((a1.x-mean)*rstd*G1.x + B1.x), f2b((a1.y-mean)*rstd*G1.y + B1.y),
      f2b((a1.z-mean)*rstd*G1.z + B1.z), f2b((a1.w-mean)*rstd*G1.w + B1.w));
}

// ------ head_w transpose -> bf16 with BN-gamma fold: hwt[pr][n*512+d] ---------
__global__ void k_transw(const float* __restrict__ hw, const float* __restrict__ bng,
                         unsigned short* __restrict__ hwt){
  int dc = blockIdx.x, pr = blockIdx.y;
  int d0 = dc*64;
  __shared__ float tl[64*N_];
  const float* src = hw + (size_t)pr*KHEAD_ + (size_t)d0*N_;
  for (int i = threadIdx.x; i < 64*N_; i += 256) tl[i] = src[i];
  __syncthreads();
  const float sc = 0.9999950000374997f;   // 1/sqrt(1+1e-5)
  unsigned short* dst = hwt + (size_t)pr*KHEAD_;
  for (int i = threadIdx.x; i < 64*N_; i += 256){
    int n = i >> 6, dd = i & 63;
    dst[(size_t)n*D_ + d0 + dd] = f2b(tl[dd*N_ + n] * sc * bng[d0+dd]);
  }
}

// ------ bias2[pr] = head_b[pr] + sum_{d,n} bn_b[d]*head_w[pr][d*84+n] ---------
__global__ void k_bias2(const float* __restrict__ hw, const float* __restrict__ bnb,
                        const float* __restrict__ hb, float* __restrict__ bias2){
  int pr = blockIdx.x, tid = threadIdx.x;
  const float* src = hw + (size_t)pr*KHEAD_;
  float s = 0.f;
  for (int i = tid; i < KHEAD_; i += 256) s += src[i] * bnb[i / N_];
  __shared__ float rs[4];
  s = wred_add(s);
  int w = tid >> 6;
  if ((tid & 63) == 0) rs[w] = s;
  __syncthreads();
  if (tid == 0) bias2[pr] = hb[pr] + rs[0] + rs[1] + rs[2] + rs[3];
}

// ---------------- de-normalize + final transpose ----------------
__global__ void k_out(const float* __restrict__ dec, const float* __restrict__ stats,
                      float* __restrict__ out){
  int i = blockIdx.x*256 + threadIdx.x;
  if (i >= B_*PRED_*CVAR_) return;
  int c = i % CVAR_; int t = (i / CVAR_) % PRED_; int b = i / (CVAR_*PRED_);
  int bc = b*CVAR_ + c;
  out[i] = dec[(size_t)bc*PRED_ + t] * stats[BC_ + bc] + stats[bc];
}

extern "C" void kernel_launch(void* const* d_in, const int* in_sizes, int n_in,
                              void* d_out, int out_size, void* d_ws, size_t ws_size,
                              hipStream_t stream){
  const float* x_enc  = (const float*)d_in[0];
  const float* cls_w1 = (const float*)d_in[4];
  const float* cls_b1 = (const float*)d_in[5];
  const float* cls_w2 = (const float*)d_in[6];
  const float* cls_b2 = (const float*)d_in[7];
  const float* ew0 = (const float*)d_in[8];
  const float* ew1 = (const float*)d_in[9];
  const float* ew2 = (const float*)d_in[10];
  const float* ew3 = (const float*)d_in[11];
  const float* wq = (const float*)d_in[12]; const float* bq = (const float*)d_in[13];
  const float* wk = (const float*)d_in[14]; const float* bk = (const float*)d_in[15];
  const float* wv = (const float*)d_in[16]; const float* bv = (const float*)d_in[17];
  const float* wo = (const float*)d_in[18]; const float* bo = (const float*)d_in[19];
  const float* ln1_g = (const float*)d_in[20]; const float* ln1_b = (const float*)d_in[21];
  const float* ln2_g = (const float*)d_in[22]; const float* ln2_b = (const float*)d_in[23];
  const float* ff1_w = (const float*)d_in[24]; const float* ff1_b = (const float*)d_in[25];
  const float* ff2_w = (const float*)d_in[26]; const float* ff2_b = (const float*)d_in[27];
  const float* bn_g = (const float*)d_in[28]; const float* bn_b = (const float*)d_in[29];
  const float* head_w = (const float*)d_in[30]; const float* head_b = (const float*)d_in[31];
  float* out = (float*)d_out;

  // ---- workspace layout (256B-aligned regions) ----
  char* cur = (char*)d_ws;
  auto alloc = [&](size_t bytes)->char*{
    char* p = cur; cur += (bytes + 255) & ~(size_t)255; return p;
  };
  float* xc    = (float*)alloc(451584*4);
  float* stats = (float*)alloc(1344*4);
  int*   pred  = (int*)  alloc(9408*4);
  float* pe    = (float*)alloc(43008*4);
  float* ewt   = (float*)alloc(49152*4);
  unsigned short* wqkv_b = (unsigned short*)alloc((size_t)NL_*QKVN_*D_*2);
  float* bqkv  = (float*)alloc((size_t)NL_*QKVN_*4);
  unsigned short* wo_b  = (unsigned short*)alloc((size_t)NL_*D_*D_*2);
  unsigned short* ff1b  = (unsigned short*)alloc((size_t)NL_*DFF_*D_*2);
  unsigned short* ff2b  = (unsigned short*)alloc((size_t)NL_*D_*DFF_*2);
  unsigned short* hwt   = (unsigned short*)alloc((size_t)PRED_*KHEAD_*2);
  float* bias2 = (float*)alloc(PRED_*4);
  unsigned short* zfinal = (unsigned short*)alloc((size_t)M_*D_*2);
  char* E = cur;
  size_t E_avail = (ws_size > (size_t)(E - (char*)d_ws)) ? ws_size - (size_t)(E - (char*)d_ws) : 0;

  // chunk size: Cb in {672,224,96,32}; per-token scratch = 6144 B (bf16 master)
  static const int cands[4] = {672, 224, 96, 32};
  int Cb = 32;
  for (int i = 0; i < 4; i++){
    size_t need = (size_t)6144 * cands[i] * N_;
    if (need <= E_avail){ Cb = cands[i]; break; }
  }
  const int nchunk = BC_ / Cb;
  const int Tc = Cb * N_;
  unsigned short* zb_c = (unsigned short*)E;                           // [Tc][512] bf16
  unsigned short* r1   = (unsigned short*)(E + (size_t)1024*Tc);       // qkv [Tc][1536] / y1 [Tc][2048]
  unsigned short* abuf = (unsigned short*)(E + (size_t)4096*Tc);       // attn out [Tc][512]
  unsigned short* r2   = (unsigned short*)(E + (size_t)5120*Tc);       // delta [Tc][512] bf16
  // head-phase scratch (after encoder done): pick largest SK that fits
  int SK = 8;
  {
    size_t dec_b = (size_t)BC_*PRED_*4 + 256;
    if ((size_t)32*PM_*PN_*4 + dec_b <= E_avail) SK = 32;
    else if ((size_t)16*PM_*PN_*4 + dec_b <= E_avail) SK = 16;
  }
  float* part = (float*)E;
  float* dec  = (float*)(E + (size_t)SK*PM_*PN_*4);

  // ---- prologue ----
  k_instnorm<<<BC_, 256, 0, stream>>>(x_enc, xc, stats);
  k_router<<<BC_*R_/4, 256, 0, stream>>>(xc, cls_w1, cls_b1, cls_w2, cls_b2, pred);
  k_pe<<<(N_*D_ + 255)/256, 256, 0, stream>>>(pe);
  k_transe<<<192, 256, 0, stream>>>(ew0, ew1, ew2, ew3, ewt);
  int nqkvg = NL_*QKVN_*D_/4, nw4 = NL_*D_*D_/4, nff4 = NL_*DFF_*D_/4;
  k_cvtqkv<<<(nqkvg+255)/256, 256, 0, stream>>>(wq, wk, wv, wqkv_b);
  k_catbias<<<(NL_*QKVN_+255)/256, 256, 0, stream>>>(bq, bk, bv, bqkv);
  k_cvt<<<(nw4+255)/256, 256, 0, stream>>>(wo, wo_b, nw4);
  k_cvt<<<(nff4+255)/256, 256, 0, stream>>>(ff1_w, ff1b, nff4);
  k_cvt<<<(nff4+255)/256, 256, 0, stream>>>(ff2_w, ff2b, nff4);
  k_transw<<<dim3(8, PRED_), 256, 0, stream>>>(head_w, bn_g, hwt);
  k_bias2<<<PRED_, 256, 0, stream>>>(head_w, bn_b, head_b, bias2);

  // ---- encoder (chunked over bc; chunks fully independent) ----
  for (int ch = 0; ch < nchunk; ch++){
    int bc0 = ch*Cb;
    k_embed<<<Cb*R_, 256, 0, stream>>>(xc, pred, ewt, pe, zb_c, bc0);
    for (int l = 0; l < NL_; l++){
      k_mm<false,true><<<(QKVN_/128)*(Tc/128), 512, 0, stream>>>(
          zb_c, wqkv_b + (size_t)l*QKVN_*D_, bqkv + l*QKVN_, r1, Tc, QKVN_, D_);
      k_attn<<<Cb*H_, 384, 0, stream>>>(r1, abuf);
      k_mm<false,true><<<(D_/128)*(Tc/128), 512, 0, stream>>>(
          abuf, wo_b + (size_t)l*D_*D_, bo + l*D_, r2, Tc, D_, D_);
      k_addln<<<Tc/4, 256, 0, stream>>>(zb_c, r2, ln1_g+l*D_, ln1_b+l*D_, zb_c, Tc);
      size_t foff = (size_t)l*DFF_*D_;
      k_mm<true,true><<<(DFF_/128)*(Tc/128), 512, 0, stream>>>(
          zb_c, ff1b+foff, ff1_b+l*DFF_, r1, Tc, DFF_, D_);
      k_mm<false,true><<<(D_/128)*(Tc/128), 512, 0, stream>>>(
          r1, ff2b+foff, ff2_b+l*D_, r2, Tc, D_, DFF_);
      unsigned short* zb_out = (l == NL_-1) ? (zfinal + (size_t)bc0*N_*D_) : zb_c;
      k_addln<<<Tc/4, 256, 0, stream>>>(zb_c, r2, ln2_g+l*D_, ln2_b+l*D_, zb_out, Tc);
    }
  }

  // ---- head: dec = zfinal @ hwt^T (split-K) + bias2, then de-normalize ----
  k_mm_part<<<SK*18, 512, 0, stream>>>(zfinal, hwt, part, KHEAD_/SK);
  k_headred<<<(BC_*PRED_ + 255)/256, 256, 0, stream>>>(part, bias2, dec, SK);
  k_out<<<(B_*PRED_*CVAR_ + 255)/256, 256, 0, stream>>>(dec, stats, out);
}

// Round 16
// 1595.656 us; speedup vs baseline: 1.2192x; 1.0018x over previous
//
#include <hip/hip_runtime.h>
#include <hip/hip_bf16.h>
#include <math.h>

#define B_    32
#define SEQ_  672
#define CVAR_ 21
#define PRED_ 336
#define D_    512
#define H_    8
#define DFF_  2048
#define NL_   2
#define R_    14
#define T_    6
#define N_    84
#define BC_   672           // B_*CVAR_
#define M_    (BC_*N_)      // 56448 tokens
#define KHEAD_ (D_*N_)      // 43008
#define PM_   768           // head M padded to 6*128
#define PN_   384           // head N padded to 3*128
#define QKVN_ 1536          // fused qkv width

typedef __attribute__((ext_vector_type(8))) short bh8;
typedef __attribute__((ext_vector_type(4))) float f32x4;

__device__ __forceinline__ unsigned short f2b(float x){
  union { float f; unsigned int u; } v; v.f = x;
  unsigned int r = v.u + 0x7FFFu + ((v.u >> 16) & 1u);   // RNE
  return (unsigned short)(r >> 16);
}
__device__ __forceinline__ float b2f(unsigned short h){
  union { unsigned int u; float f; } v; v.u = ((unsigned int)h) << 16;
  return v.f;
}
__device__ __forceinline__ float wred_add(float v){
  #pragma unroll
  for (int o = 32; o; o >>= 1) v += __shfl_xor(v, o, 64);
  return v;
}
// async global->LDS, 16B per lane; lds base must be wave-uniform
__device__ __forceinline__ void stage16(const unsigned short* g, unsigned short* l){
  __builtin_amdgcn_global_load_lds(
      (const __attribute__((address_space(1))) unsigned int*)(const void*)g,
      (__attribute__((address_space(3))) unsigned int*)(void*)l, 16, 0, 0);
}

// ---------------- instance norm over time ----------------
__global__ void k_instnorm(const float* __restrict__ x, float* __restrict__ xc,
                           float* __restrict__ stats){
  int bc = blockIdx.x; int b = bc / CVAR_, c = bc % CVAR_;
  const float* xp = x + (size_t)b*SEQ_*CVAR_ + c;
  int tid = threadIdx.x;
  float s = 0.f, sq = 0.f;
  for (int l = tid; l < SEQ_; l += 256){ float v = xp[(size_t)l*CVAR_]; s += v; sq += v*v; }
  __shared__ float rs[4], rq[4];
  s = wred_add(s); sq = wred_add(sq);
  int w = tid >> 6, lane = tid & 63;
  if (lane == 0){ rs[w] = s; rq[w] = sq; }
  __syncthreads();
  if (tid == 0){
    float S = rs[0]+rs[1]+rs[2]+rs[3], Q = rq[0]+rq[1]+rq[2]+rq[3];
    float mean = S * (1.f/SEQ_);
    float var  = Q * (1.f/SEQ_) - mean*mean;
    float stdev = sqrtf(var + 1e-5f);
    stats[bc] = mean; stats[BC_ + bc] = stdev;
    rs[0] = mean; rq[0] = stdev;
  }
  __syncthreads();
  float mean = rs[0], inv = 1.f / rq[0];
  for (int l = tid; l < SEQ_; l += 256)
    xc[(size_t)bc*SEQ_ + l] = (xp[(size_t)l*CVAR_] - mean) * inv;
}

// ------------- region router: one wave per region, no spills ------------------
__global__ __launch_bounds__(256) void k_router(const float* __restrict__ xc,
                         const float* __restrict__ w1, const float* __restrict__ b1,
                         const float* __restrict__ w2, const float* __restrict__ b2,
                         int* __restrict__ pred){
  __shared__ float xs[4][48];
  int tid = threadIdx.x, wv = tid >> 6, lane = tid & 63;
  int t = blockIdx.x*4 + wv;             // region id, always < BC_*R_
  int bc = t / R_, r = t % R_;
  if (lane < 48) xs[wv][lane] = xc[(size_t)bc*SEQ_ + r*48 + lane];
  __syncthreads();
  float h = b1[lane];
  const float* wr = w1 + lane*48;
  #pragma unroll 12
  for (int i = 0; i < 48; i++) h = fmaf(xs[wv][i], wr[i], h);
  h = fmaxf(h, 0.f);
  float best = 0.f; int be = 0;
  #pragma unroll
  for (int e = 0; e < 4; e++){
    float lg = b2[e] + wred_add(h * w2[e*64 + lane]);
    if (e == 0) best = lg;
    else if (lg > best){ best = lg; be = e; }   // first max wins (strict >)
  }
  if (lane == 0) pred[t] = be;
}

// ---------------- positional encoding ----------------
__global__ void k_pe(float* __restrict__ pe){
  int i = blockIdx.x*256 + threadIdx.x;
  if (i >= N_*D_) return;
  int n = i / D_, d = i % D_;
  int ii = d >> 1;
  float freq = expf((float)(2*ii) * (-9.210340371976184f / (float)D_)); // -ln(10000)/D
  float a = (float)n * freq;
  pe[i] = (d & 1) ? cosf(a) : sinf(a);
}

// ---------------- fp32 -> bf16 convert (n4 = elems/4) ----------------
__global__ void k_cvt(const float* __restrict__ in, unsigned short* __restrict__ out, int n4){
  int i = blockIdx.x*256 + threadIdx.x;
  if (i >= n4) return;
  float4 v = ((const float4*)in)[i];
  ((ushort4*)out)[i] = make_ushort4(f2b(v.x), f2b(v.y), f2b(v.z), f2b(v.w));
}

// ---------------- fused qkv weight convert (concat rows) ----------------
__global__ void k_cvtqkv(const float* __restrict__ wq, const float* __restrict__ wk,
                         const float* __restrict__ wv, unsigned short* __restrict__ o){
  int i = blockIdx.x*256 + threadIdx.x;          // one per 4 elems
  const int per_l = QKVN_*D_/4;                  // 196608
  const int per_s = D_*D_/4;                     // 65536
  if (i >= NL_*per_l) return;
  int l = i / per_l;
  int rem = i - l*per_l;
  int sec = rem / per_s;
  int off = rem - sec*per_s;
  const float* src = (sec==0 ? wq : sec==1 ? wk : wv) + (size_t)l*D_*D_ + (size_t)off*4;
  float4 v = *(const float4*)src;
  ((ushort4*)o)[i] = make_ushort4(f2b(v.x), f2b(v.y), f2b(v.z), f2b(v.w));
}

// ---------------- qkv bias concat ----------------
__global__ void k_catbias(const float* __restrict__ bq, const float* __restrict__ bk,
                          const float* __restrict__ bv, float* __restrict__ bqkv){
  int i = blockIdx.x*256 + threadIdx.x;
  if (i >= NL_*QKVN_) return;
  int l = i / QKVN_, r = i % QKVN_;
  float v = (r < 512) ? bq[l*512 + r] : (r < 1024) ? bk[l*512 + r - 512] : bv[l*512 + r - 1024];
  bqkv[i] = v;
}

// ------ expert weight transpose: W_e[d][q] -> wt[base_e + q*512 + d] ----------
__global__ void k_transe(const float* __restrict__ w0, const float* __restrict__ w1,
                         const float* __restrict__ w2, const float* __restrict__ w3,
                         float* __restrict__ wt){
  int i = blockIdx.x*256 + threadIdx.x;
  if (i >= 49152) return;
  int e, base, p;
  if (i < 4096){ e = 0; base = 0; p = 8; }
  else if (i < 12288){ e = 1; base = 4096; p = 16; }
  else if (i < 24576){ e = 2; base = 12288; p = 24; }
  else { e = 3; base = 24576; p = 48; }
  int local = i - base;
  int q = local >> 9, d = local & 511;
  const float* W = (e==0) ? w0 : (e==1) ? w1 : (e==2) ? w2 : w3;
  wt[base + q*512 + d] = W[(size_t)d*p + q];
}

// ---------------- patch embedding + PE (coalesced transposed weights) ---------
__global__ void k_embed(const float* __restrict__ xc, const int* __restrict__ pred,
                        const float* __restrict__ wt, const float* __restrict__ pe,
                        unsigned short* __restrict__ zb, int bc0){
  int blk = blockIdx.x; int bcl = blk / R_, r = blk % R_;
  int bc = bc0 + bcl;
  __shared__ float xr[48];
  int tid = threadIdx.x;
  if (tid < 48) xr[tid] = xc[(size_t)bc*SEQ_ + r*48 + tid];
  __syncthreads();
  int e = pred[bc*R_ + r];
  int p    = (e==0) ? 8 : (e==1) ? 16 : (e==2) ? 24 : 48;
  int base = (e==0) ? 0 : (e==1) ? 4096 : (e==2) ? 12288 : 24576;
  int num = 48 / p, rep = 7 - num;
  const float* Wt = wt + base;
  int d0 = tid, d1 = tid + 256;
  float acc0[6], acc1[6];
  #pragma unroll
  for (int u = 0; u < 6; u++){ acc0[u] = 0.f; acc1[u] = 0.f; }
  #pragma unroll
  for (int u = 0; u < 6; u++){
    if (u < num){
      float s0 = 0.f, s1 = 0.f;
      const float* xu = xr + u*p;
      for (int q = 0; q < p; q++){
        float xv = xu[q];
        const float* wrow = Wt + q*512;
        s0 = fmaf(xv, wrow[d0], s0);
        s1 = fmaf(xv, wrow[d1], s1);
      }
      acc0[u] = s0; acc1[u] = s1;
    }
  }
  #pragma unroll
  for (int u = 0; u < 6; u++){
    if (u < num){
      #pragma unroll
      for (int t = 0; t < 6; t++){
        int ut = t / rep; if (ut > num-1) ut = num-1;
        if (ut == u){
          int n = r*T_ + t;
          size_t off = ((size_t)bcl*N_ + n)*D_;
          zb[off + d0] = f2b(acc0[u] + pe[n*D_ + d0]);
          zb[off + d1] = f2b(acc1[u] + pe[n*D_ + d1]);
        }
      }
    }
  }
}

// ---------------- bf16 MFMA GEMM: C[M,N] = act(A[M,K] * B[N,K]^T + bias) ------
// 128x128 tile, BK=32, 512 thr (8 waves, 2 row-groups x 4 col-groups).
// LDS bank-conflict fix (rule #21 both-sides): LDS dest linear, global SOURCE
// chunk permuted s^((row>>1)&3), fragment reads apply the same XOR.
// ds_read_b128 now covers all 8 16B-slots 2-way (free) instead of 8-way.
// Double-buffered LDS with COUNTED vmcnt(2).
template<bool GELU, bool OBF16>
__global__ __launch_bounds__(512, 6) void k_mm(const unsigned short* __restrict__ A,
      const unsigned short* __restrict__ Bw, const float* __restrict__ bias,
      void* __restrict__ Cp, int M, int N, int K){
  __shared__ unsigned short As[2][128*32];
  __shared__ unsigned short Bs[2][128*32];
  int tid = threadIdx.x;
  int lane = tid & 63;
  int wave = tid >> 6;                     // 0..7
  int wr0 = (wave >> 2) * 64;              // 0 / 64
  int wc0 = (wave & 3) * 32;               // 0 / 32 / 64 / 96
  // bijective XCD swizzle (m204): contiguous wgid chunk per XCD
  int nx = N >> 7;
  int nwg = gridDim.x;
  int orig = blockIdx.x;
  int q = nwg >> 3, r8 = nwg & 7;
  int xcd = orig & 7, idx = orig >> 3;
  int wgid = (xcd < r8 ? xcd*(q+1) : r8*(q+1) + (xcd - r8)*q) + idx;
  int m0 = (wgid / nx) << 7;
  int n0 = (wgid % nx) << 7;
  int ec = wave*64 + lane;                 // chunk id 0..511
  int rowc = ec >> 2;
  int kcc = (((lane & 3) ^ ((lane >> 3) & 3)) << 3);   // source-permuted chunk
  const unsigned short* ap = A  + (size_t)(m0+rowc)*K + kcc;
  const unsigned short* bp = Bw + (size_t)(n0+rowc)*K + kcc;
  unsigned short* lda0 = &As[0][wave*512]; // wave-uniform LDS bases
  unsigned short* lda1 = &As[1][wave*512];
  unsigned short* ldb0 = &Bs[0][wave*512];
  unsigned short* ldb1 = &Bs[1][wave*512];
  // read-side swizzled chunk offset (per-lane constant)
  int cofs = (((lane >> 4) ^ (((lane & 15) >> 1) & 3)) << 3);
  f32x4 acc[4][2];
  #pragma unroll
  for (int m = 0; m < 4; m++)
    #pragma unroll
    for (int n = 0; n < 2; n++) acc[m][n] = (f32x4){0.f,0.f,0.f,0.f};

  stage16(ap, lda0);
  stage16(bp, ldb0);
  int cur = 0;
  for (int k0 = 0; k0 < K - 32; k0 += 32){
    int ko = k0 + 32;
    stage16(ap + ko, cur ? lda0 : lda1);
    stage16(bp + ko, cur ? ldb0 : ldb1);
    asm volatile("s_waitcnt vmcnt(2)" ::: "memory");
    __builtin_amdgcn_s_barrier();
    __builtin_amdgcn_sched_barrier(0);
    bh8 fa[4], fb[2];
    #pragma unroll
    for (int m = 0; m < 4; m++)
      fa[m] = *(const bh8*)&As[cur][(wr0 + m*16 + (lane & 15))*32 + cofs];
    #pragma unroll
    for (int n = 0; n < 2; n++)
      fb[n] = *(const bh8*)&Bs[cur][(wc0 + n*16 + (lane & 15))*32 + cofs];
    #pragma unroll
    for (int m = 0; m < 4; m++)
      #pragma unroll
      for (int n = 0; n < 2; n++)
        acc[m][n] = __builtin_amdgcn_mfma_f32_16x16x32_bf16(fa[m], fb[n], acc[m][n], 0, 0, 0);
    __builtin_amdgcn_sched_barrier(0);
    __builtin_amdgcn_s_barrier();          // WAR: all reads of buf[cur] done
    cur ^= 1;
  }
  asm volatile("s_waitcnt vmcnt(0)" ::: "memory");
  __builtin_amdgcn_s_barrier();
  __builtin_amdgcn_sched_barrier(0);
  {
    bh8 fa[4], fb[2];
    #pragma unroll
    for (int m = 0; m < 4; m++)
      fa[m] = *(const bh8*)&As[cur][(wr0 + m*16 + (lane & 15))*32 + cofs];
    #pragma unroll
    for (int n = 0; n < 2; n++)
      fb[n] = *(const bh8*)&Bs[cur][(wc0 + n*16 + (lane & 15))*32 + cofs];
    #pragma unroll
    for (int m = 0; m < 4; m++)
      #pragma unroll
      for (int n = 0; n < 2; n++)
        acc[m][n] = __builtin_amdgcn_mfma_f32_16x16x32_bf16(fa[m], fb[n], acc[m][n], 0, 0, 0);
  }
  int rbase = m0 + wr0 + (lane >> 4)*4;
  int cbase = n0 + wc0 + (lane & 15);
  #pragma unroll
  for (int n = 0; n < 2; n++){
    int col = cbase + n*16;
    float bs = bias[col];
    #pragma unroll
    for (int m = 0; m < 4; m++){
      int row = rbase + m*16;
      #pragma unroll
      for (int j = 0; j < 4; j++){
        float cv = acc[m][n][j] + bs;
        if (GELU) cv = 0.5f*cv*(1.f + erff(cv*0.70710678118654752f));
        if (OBF16) ((unsigned short*)Cp)[(size_t)(row+j)*N + col] = f2b(cv);
        else       ((float*)Cp)[(size_t)(row+j)*N + col] = cv;
      }
    }
  }
}

// ------- head GEMM, split-K partials: 8-wave, 1-D XCD-swizzled grid ----------
__global__ __launch_bounds__(512, 6) void k_mm_part(const unsigned short* __restrict__ A,
      const unsigned short* __restrict__ Bw, float* __restrict__ part, int kchunk){
  __shared__ unsigned short As[2][128*32];
  __shared__ unsigned short Bs[2][128*32];
  int tid = threadIdx.x;
  int lane = tid & 63;
  int wave = tid >> 6;
  int wr0 = (wave >> 2) * 64;
  int wc0 = (wave & 3) * 32;
  int nwg = gridDim.x;
  int orig = blockIdx.x;
  int q = nwg >> 3, r8 = nwg & 7;
  int xcd = orig & 7, idx = orig >> 3;
  int wgid = (xcd < r8 ? xcd*(q+1) : r8*(q+1) + (xcd - r8)*q) + idx;
  int sk = wgid / 18;
  int rem = wgid - sk*18;
  int m0 = (rem / 3) << 7;
  int n0 = (rem % 3) << 7;
  int kb0 = sk*kchunk;
  int ec = wave*64 + lane;
  int rowc = ec >> 2;
  int kcc = (((lane & 3) ^ ((lane >> 3) & 3)) << 3);
  int ar = m0 + rowc; if (ar >= BC_)  ar = BC_ - 1;
  int br = n0 + rowc; if (br >= PRED_) br = PRED_ - 1;
  const unsigned short* ap = A  + (size_t)ar*KHEAD_ + kb0 + kcc;
  const unsigned short* bp = Bw + (size_t)br*KHEAD_ + kb0 + kcc;
  unsigned short* lda0 = &As[0][wave*512];
  unsigned short* lda1 = &As[1][wave*512];
  unsigned short* ldb0 = &Bs[0][wave*512];
  unsigned short* ldb1 = &Bs[1][wave*512];
  int cofs = (((lane >> 4) ^ (((lane & 15) >> 1) & 3)) << 3);
  f32x4 acc[4][2];
  #pragma unroll
  for (int m = 0; m < 4; m++)
    #pragma unroll
    for (int n = 0; n < 2; n++) acc[m][n] = (f32x4){0.f,0.f,0.f,0.f};

  stage16(ap, lda0);
  stage16(bp, ldb0);
  int cur = 0;
  for (int ko = 0; ko < kchunk - 32; ko += 32){
    int kk = ko + 32;
    stage16(ap + kk, cur ? lda0 : lda1);
    stage16(bp + kk, cur ? ldb0 : ldb1);
    asm volatile("s_waitcnt vmcnt(2)" ::: "memory");
    __builtin_amdgcn_s_barrier();
    __builtin_amdgcn_sched_barrier(0);
    bh8 fa[4], fb[2];
    #pragma unroll
    for (int m = 0; m < 4; m++)
      fa[m] = *(const bh8*)&As[cur][(wr0 + m*16 + (lane & 15))*32 + cofs];
    #pragma unroll
    for (int n = 0; n < 2; n++)
      fb[n] = *(const bh8*)&Bs[cur][(wc0 + n*16 + (lane & 15))*32 + cofs];
    #pragma unroll
    for (int m = 0; m < 4; m++)
      #pragma unroll
      for (int n = 0; n < 2; n++)
        acc[m][n] = __builtin_amdgcn_mfma_f32_16x16x32_bf16(fa[m], fb[n], acc[m][n], 0, 0, 0);
    __builtin_amdgcn_sched_barrier(0);
    __builtin_amdgcn_s_barrier();
    cur ^= 1;
  }
  asm volatile("s_waitcnt vmcnt(0)" ::: "memory");
  __builtin_amdgcn_s_barrier();
  __builtin_amdgcn_sched_barrier(0);
  {
    bh8 fa[4], fb[2];
    #pragma unroll
    for (int m = 0; m < 4; m++)
      fa[m] = *(const bh8*)&As[cur][(wr0 + m*16 + (lane & 15))*32 + cofs];
    #pragma unroll
    for (int n = 0; n < 2; n++)
      fb[n] = *(const bh8*)&Bs[cur][(wc0 + n*16 + (lane & 15))*32 + cofs];
    #pragma unroll
    for (int m = 0; m < 4; m++)
      #pragma unroll
      for (int n = 0; n < 2; n++)
        acc[m][n] = __builtin_amdgcn_mfma_f32_16x16x32_bf16(fa[m], fb[n], acc[m][n], 0, 0, 0);
  }
  float* po = part + (size_t)sk*PM_*PN_;
  int rbase = m0 + wr0 + (lane >> 4)*4;
  int cbase = n0 + wc0 + (lane & 15);
  #pragma unroll
  for (int n = 0; n < 2; n++){
    int col = cbase + n*16;
    #pragma unroll
    for (int m = 0; m < 4; m++){
      int row = rbase + m*16;
      #pragma unroll
      for (int j = 0; j < 4; j++)
        po[(size_t)(row+j)*PN_ + col] = acc[m][n][j];
    }
  }
}

// ---------------- head reduce + bias ----------------
__global__ void k_headred(const float* __restrict__ part, const float* __restrict__ bias2,
                          float* __restrict__ dec, int nsk){
  int i = blockIdx.x*256 + threadIdx.x;
  if (i >= BC_*PRED_) return;
  int bc = i / PRED_, pr = i % PRED_;
  float s = bias2[pr];
  for (int sk = 0; sk < nsk; sk++)
    s += part[(size_t)sk*PM_*PN_ + (size_t)bc*PN_ + pr];
  dec[i] = s;
}

// -------- MFMA fused attention: block = (bc-local, head), 6 waves -------------
__global__ __launch_bounds__(384) void k_attn(const unsigned short* __restrict__ qkv,
                                              unsigned short* __restrict__ o){
  __shared__ unsigned short Qb[96][72];       // stride 144B: 2-way alias (free)
  __shared__ unsigned short Kb[96][72];
  __shared__ unsigned short Vt[64][104];      // V transposed; stride 208B
  __shared__ unsigned short Pb[6][16][104];
  int bh = blockIdx.x; int bcl = bh >> 3, h = bh & 7;
  int tid = threadIdx.x, lane = tid & 63, wv = tid >> 6;   // wv = row-tile 0..5
  size_t qb = (size_t)bcl*N_*QKVN_ + h*64;
  for (int g = tid; g < 1536; g += 384){
    int n = g >> 4, d4 = (g & 15) << 2;
    ushort4 qv = make_ushort4(0,0,0,0), kv = make_ushort4(0,0,0,0);
    if (n < N_){
      qv = *(const ushort4*)(qkv + qb + (size_t)n*QKVN_ + d4);
      kv = *(const ushort4*)(qkv + qb + 512 + (size_t)n*QKVN_ + d4);
    }
    *(ushort4*)&Qb[n][d4] = qv;
    *(ushort4*)&Kb[n][d4] = kv;
  }
  for (int g = tid; g < N_*16; g += 384){
    int n = g >> 4, d4 = (g & 15) << 2;
    ushort4 vv = *(const ushort4*)(qkv + qb + 1024 + (size_t)n*QKVN_ + d4);
    Vt[d4+0][n] = vv.x; Vt[d4+1][n] = vv.y; Vt[d4+2][n] = vv.z; Vt[d4+3][n] = vv.w;
  }
  for (int g = tid; g < 64*12; g += 384) Vt[g/12][N_ + g%12] = 0;
  __syncthreads();
  f32x4 acc[6];
  #pragma unroll
  for (int t = 0; t < 6; t++) acc[t] = (f32x4){0.f,0.f,0.f,0.f};
  #pragma unroll
  for (int ks = 0; ks < 2; ks++){
    bh8 qa = *(const bh8*)&Qb[wv*16 + (lane & 15)][ks*32 + (lane >> 4)*8];
    #pragma unroll
    for (int t = 0; t < 6; t++){
      bh8 kf = *(const bh8*)&Kb[t*16 + (lane & 15)][ks*32 + (lane >> 4)*8];
      acc[t] = __builtin_amdgcn_mfma_f32_16x16x32_bf16(qa, kf, acc[t], 0, 0, 0);
    }
  }
  bool v5 = (lane & 15) < 4;
  #pragma unroll
  for (int j = 0; j < 4; j++){
    float m = -1e30f;
    #pragma unroll
    for (int t = 0; t < 6; t++){
      float s = acc[t][j] * 0.125f;
      if (t == 5 && !v5) s = -1e30f;
      acc[t][j] = s;
      m = fmaxf(m, s);
    }
    #pragma unroll
    for (int off = 1; off < 16; off <<= 1) m = fmaxf(m, __shfl_xor(m, off, 64));
    float sum = 0.f;
    #pragma unroll
    for (int t = 0; t < 6; t++){
      float p = __expf(acc[t][j] - m);
      acc[t][j] = p;
      sum += p;
    }
    #pragma unroll
    for (int off = 1; off < 16; off <<= 1) sum += __shfl_xor(sum, off, 64);
    float inv = 1.f / sum;
    int lr = (lane >> 4)*4 + j;
    #pragma unroll
    for (int t = 0; t < 6; t++)
      Pb[wv][lr][t*16 + (lane & 15)] = f2b(acc[t][j] * inv);
  }
  f32x4 accO[4];
  #pragma unroll
  for (int dt = 0; dt < 4; dt++) accO[dt] = (f32x4){0.f,0.f,0.f,0.f};
  #pragma unroll
  for (int ks = 0; ks < 3; ks++){
    bh8 pa = *(const bh8*)&Pb[wv][lane & 15][ks*32 + (lane >> 4)*8];
    #pragma unroll
    for (int dt = 0; dt < 4; dt++){
      bh8 vf = *(const bh8*)&Vt[dt*16 + (lane & 15)][ks*32 + (lane >> 4)*8];
      accO[dt] = __builtin_amdgcn_mfma_f32_16x16x32_bf16(pa, vf, accO[dt], 0, 0, 0);
    }
  }
  size_t ob = (size_t)bcl*N_*D_ + h*64;
  #pragma unroll
  for (int dt = 0; dt < 4; dt++)
    #pragma unroll
    for (int j = 0; j < 4; j++){
      int r = wv*16 + (lane >> 4)*4 + j;
      if (r < N_) o[ob + (size_t)r*D_ + dt*16 + (lane & 15)] = f2b(accO[dt][j]);
    }
}

// ---------- fused residual-add + LayerNorm, bf16 residual master --------------
__global__ __launch_bounds__(256) void k_addln(const unsigned short* zin,
                        const unsigned short* __restrict__ delta,
                        const float* __restrict__ g, const float* __restrict__ b,
                        unsigned short* zout, int ntok){
  int w = threadIdx.x >> 6, lane = threadIdx.x & 63;
  int tok = blockIdx.x*4 + w;
  if (tok >= ntok) return;
  const ushort4* zp = (const ushort4*)(zin + (size_t)tok*D_);
  const ushort4* dp = (const ushort4*)(delta + (size_t)tok*D_);
  ushort4 z0 = zp[lane], z1 = zp[64+lane];
  ushort4 u0 = dp[lane], u1 = dp[64+lane];
  float4 a0, a1;
  a0.x = b2f(z0.x) + b2f(u0.x); a0.y = b2f(z0.y) + b2f(u0.y);
  a0.z = b2f(z0.z) + b2f(u0.z); a0.w = b2f(z0.w) + b2f(u0.w);
  a1.x = b2f(z1.x) + b2f(u1.x); a1.y = b2f(z1.y) + b2f(u1.y);
  a1.z = b2f(z1.z) + b2f(u1.z); a1.w = b2f(z1.w) + b2f(u1.w);
  float s  = a0.x+a0.y+a0.z+a0.w + a1.x+a1.y+a1.z+a1.w;
  float sq = a0.x*a0.x+a0.y*a0.y+a0.z*a0.z+a0.w*a0.w
           + a1.x*a1.x+a1.y*a1.y+a1.z*a1.z+a1.w*a1.w;
  s = wred_add(s); sq = wred_add(sq);
  float mean = s * (1.f/D_);
  float var  = sq * (1.f/D_) - mean*mean;
  float rstd = rsqrtf(var + 1e-5f);
  const float4* g4 = (const float4*)g; const float4* b4 = (const float4*)b;
  float4 G0 = g4[lane], G1 = g4[64+lane], B0 = b4[lane], B1 = b4[64+lane];
  unsigned short* zo = zout + (size_t)tok*D_;
  *(ushort4*)(zo + 4*lane) = make_ushort4(
      f2b((a0.x-mean)*rstd*G0.x + B0.x), f2b((a0.y-mean)*rstd*G0.y + B0.y),
      f2b((a0.z-mean)*rstd*G0.z + B0.z), f2b((a0.w-mean)*rstd*G0.w + B0.w));
  *(ushort4*)(zo + 256 + 4*lane) = make_ushort4(
      f2b((a1.x-mean)*rstd*G1.x + B1.x), f2b((a1.y-mean)*rstd*G1.y + B1.y),
      f2b((a1.z-mean)*rstd*G1.z + B1.z), f2b((a1.w-mean)*rstd*G1.w + B1.w));
}

// ------ head_w transpose -> bf16 with BN-gamma fold: hwt[pr][n*512+d] ---------
__global__ void k_transw(const float* __restrict__ hw, const float* __restrict__ bng,
                         unsigned short* __restrict__ hwt){
  int dc = blockIdx.x, pr = blockIdx.y;
  int d0 = dc*64;
  __shared__ float tl[64*N_];
  const float* src = hw + (size_t)pr*KHEAD_ + (size_t)d0*N_;
  for (int i = threadIdx.x; i < 64*N_; i += 256) tl[i] = src[i];
  __syncthreads();
  const float sc = 0.9999950000374997f;   // 1/sqrt(1+1e-5)
  unsigned short* dst = hwt + (size_t)pr*KHEAD_;
  for (int i = threadIdx.x; i < 64*N_; i += 256){
    int n = i >> 6, dd = i & 63;
    dst[(size_t)n*D_ + d0 + dd] = f2b(tl[dd*N_ + n] * sc * bng[d0+dd]);
  }
}

// ------ bias2[pr] = head_b[pr] + sum_{d,n} bn_b[d]*head_w[pr][d*84+n] ---------
__global__ void k_bias2(const float* __restrict__ hw, const float* __restrict__ bnb,
                        const float* __restrict__ hb, float* __restrict__ bias2){
  int pr = blockIdx.x, tid = threadIdx.x;
  const float* src = hw + (size_t)pr*KHEAD_;
  float s = 0.f;
  for (int i = tid; i < KHEAD_; i += 256) s += src[i] * bnb[i / N_];
  __shared__ float rs[4];
  s = wred_add(s);
  int w = tid >> 6;
  if ((tid & 63) == 0) rs[w] = s;
  __syncthreads();
  if (tid == 0) bias2[pr] = hb[pr] + rs[0] + rs[1] + rs[2] + rs[3];
}

// ---------------- de-normalize + final transpose ----------------
__global__ void k_out(const float* __restrict__ dec, const float* __restrict__ stats,
                      float* __restrict__ out){
  int i = blockIdx.x*256 + threadIdx.x;
  if (i >= B_*PRED_*CVAR_) return;
  int c = i % CVAR_; int t = (i / CVAR_) % PRED_; int b = i / (CVAR_*PRED_);
  int bc = b*CVAR_ + c;
  out[i] = dec[(size_t)bc*PRED_ + t] * stats[BC_ + bc] + stats[bc];
}

extern "C" void kernel_launch(void* const* d_in, const int* in_sizes, int n_in,
                              void* d_out, int out_size, void* d_ws, size_t ws_size,
                              hipStream_t stream){
  const float* x_enc  = (const float*)d_in[0];
  const float* cls_w1 = (const float*)d_in[4];
  const float* cls_b1 = (const float*)d_in[5];
  const float* cls_w2 = (const float*)d_in[6];
  const float* cls_b2 = (const float*)d_in[7];
  const float* ew0 = (const float*)d_in[8];
  const float* ew1 = (const float*)d_in[9];
  const float* ew2 = (const float*)d_in[10];
  const float* ew3 = (const float*)d_in[11];
  const float* wq = (const float*)d_in[12]; const float* bq = (const float*)d_in[13];
  const float* wk = (const float*)d_in[14]; const float* bk = (const float*)d_in[15];
  const float* wv = (const float*)d_in[16]; const float* bv = (const float*)d_in[17];
  const float* wo = (const float*)d_in[18]; const float* bo = (const float*)d_in[19];
  const float* ln1_g = (const float*)d_in[20]; const float* ln1_b = (const float*)d_in[21];
  const float* ln2_g = (const float*)d_in[22]; const float* ln2_b = (const float*)d_in[23];
  const float* ff1_w = (const float*)d_in[24]; const float* ff1_b = (const float*)d_in[25];
  const float* ff2_w = (const float*)d_in[26]; const float* ff2_b = (const float*)d_in[27];
  const float* bn_g = (const float*)d_in[28]; const float* bn_b = (const float*)d_in[29];
  const float* head_w = (const float*)d_in[30]; const float* head_b = (const float*)d_in[31];
  float* out = (float*)d_out;

  // ---- workspace layout (256B-aligned regions) ----
  char* cur = (char*)d_ws;
  auto alloc = [&](size_t bytes)->char*{
    char* p = cur; cur += (bytes + 255) & ~(size_t)255; return p;
  };
  float* xc    = (float*)alloc(451584*4);
  float* stats = (float*)alloc(1344*4);
  int*   pred  = (int*)  alloc(9408*4);
  float* pe    = (float*)alloc(43008*4);
  float* ewt   = (float*)alloc(49152*4);
  unsigned short* wqkv_b = (unsigned short*)alloc((size_t)NL_*QKVN_*D_*2);
  float* bqkv  = (float*)alloc((size_t)NL_*QKVN_*4);
  unsigned short* wo_b  = (unsigned short*)alloc((size_t)NL_*D_*D_*2);
  unsigned short* ff1b  = (unsigned short*)alloc((size_t)NL_*DFF_*D_*2);
  unsigned short* ff2b  = (unsigned short*)alloc((size_t)NL_*D_*DFF_*2);
  unsigned short* hwt   = (unsigned short*)alloc((size_t)PRED_*KHEAD_*2);
  float* bias2 = (float*)alloc(PRED_*4);
  unsigned short* zfinal = (unsigned short*)alloc((size_t)M_*D_*2);
  char* E = cur;
  size_t E_avail = (ws_size > (size_t)(E - (char*)d_ws)) ? ws_size - (size_t)(E - (char*)d_ws) : 0;

  // chunk size: Cb in {672,224,96,32}; per-token scratch = 6144 B (bf16 master)
  static const int cands[4] = {672, 224, 96, 32};
  int Cb = 32;
  for (int i = 0; i < 4; i++){
    size_t need = (size_t)6144 * cands[i] * N_;
    if (need <= E_avail){ Cb = cands[i]; break; }
  }
  const int nchunk = BC_ / Cb;
  const int Tc = Cb * N_;
  unsigned short* zb_c = (unsigned short*)E;                           // [Tc][512] bf16
  unsigned short* r1   = (unsigned short*)(E + (size_t)1024*Tc);       // qkv [Tc][1536] / y1 [Tc][2048]
  unsigned short* abuf = (unsigned short*)(E + (size_t)4096*Tc);       // attn out [Tc][512]
  unsigned short* r2   = (unsigned short*)(E + (size_t)5120*Tc);       // delta [Tc][512] bf16
  // head-phase scratch (after encoder done): pick largest SK that fits
  int SK = 8;
  {
    size_t dec_b = (size_t)BC_*PRED_*4 + 256;
    if ((size_t)32*PM_*PN_*4 + dec_b <= E_avail) SK = 32;
    else if ((size_t)16*PM_*PN_*4 + dec_b <= E_avail) SK = 16;
  }
  float* part = (float*)E;
  float* dec  = (float*)(E + (size_t)SK*PM_*PN_*4);

  // ---- prologue ----
  k_instnorm<<<BC_, 256, 0, stream>>>(x_enc, xc, stats);
  k_router<<<BC_*R_/4, 256, 0, stream>>>(xc, cls_w1, cls_b1, cls_w2, cls_b2, pred);
  k_pe<<<(N_*D_ + 255)/256, 256, 0, stream>>>(pe);
  k_transe<<<192, 256, 0, stream>>>(ew0, ew1, ew2, ew3, ewt);
  int nqkvg = NL_*QKVN_*D_/4, nw4 = NL_*D_*D_/4, nff4 = NL_*DFF_*D_/4;
  k_cvtqkv<<<(nqkvg+255)/256, 256, 0, stream>>>(wq, wk, wv, wqkv_b);
  k_catbias<<<(NL_*QKVN_+255)/256, 256, 0, stream>>>(bq, bk, bv, bqkv);
  k_cvt<<<(nw4+255)/256, 256, 0, stream>>>(wo, wo_b, nw4);
  k_cvt<<<(nff4+255)/256, 256, 0, stream>>>(ff1_w, ff1b, nff4);
  k_cvt<<<(nff4+255)/256, 256, 0, stream>>>(ff2_w, ff2b, nff4);
  k_transw<<<dim3(8, PRED_), 256, 0, stream>>>(head_w, bn_g, hwt);
  k_bias2<<<PRED_, 256, 0, stream>>>(head_w, bn_b, head_b, bias2);

  // ---- encoder (chunked over bc; chunks fully independent) ----
  for (int ch = 0; ch < nchunk; ch++){
    int bc0 = ch*Cb;
    k_embed<<<Cb*R_, 256, 0, stream>>>(xc, pred, ewt, pe, zb_c, bc0);
    for (int l = 0; l < NL_; l++){
      k_mm<false,true><<<(QKVN_/128)*(Tc/128), 512, 0, stream>>>(
          zb_c, wqkv_b + (size_t)l*QKVN_*D_, bqkv + l*QKVN_, r1, Tc, QKVN_, D_);
      k_attn<<<Cb*H_, 384, 0, stream>>>(r1, abuf);
      k_mm<false,true><<<(D_/128)*(Tc/128), 512, 0, stream>>>(
          abuf, wo_b + (size_t)l*D_*D_, bo + l*D_, r2, Tc, D_, D_);
      k_addln<<<Tc/4, 256, 0, stream>>>(zb_c, r2, ln1_g+l*D_, ln1_b+l*D_, zb_c, Tc);
      size_t foff = (size_t)l*DFF_*D_;
      k_mm<true,true><<<(DFF_/128)*(Tc/128), 512, 0, stream>>>(
          zb_c, ff1b+foff, ff1_b+l*DFF_, r1, Tc, DFF_, D_);
      k_mm<false,true><<<(D_/128)*(Tc/128), 512, 0, stream>>>(
          r1, ff2b+foff, ff2_b+l*D_, r2, Tc, D_, DFF_);
      unsigned short* zb_out = (l == NL_-1) ? (zfinal + (size_t)bc0*N_*D_) : zb_c;
      k_addln<<<Tc/4, 256, 0, stream>>>(zb_c, r2, ln2_g+l*D_, ln2_b+l*D_, zb_out, Tc);
    }
  }

  // ---- head: dec = zfinal @ hwt^T (split-K) + bias2, then de-normalize ----
  k_mm_part<<<SK*18, 512, 0, stream>>>(zfinal, hwt, part, KHEAD_/SK);
  k_headred<<<(BC_*PRED_ + 255)/256, 256, 0, stream>>>(part, bias2, dec, SK);
  k_out<<<(B_*PRED_*CVAR_ + 255)/256, 256, 0, stream>>>(dec, stats, out);
}